// Round 1
// baseline (4335.137 us; speedup 1.0000x reference)
//
#include <hip/hip_runtime.h>
#include <cstdint>

#define BB 4
#define SS 2048
#define DD 1024
#define HH 16
#define HDIM 64
#define MTOT (BB*SS)

using half_t = _Float16;
typedef _Float16 half2v __attribute__((ext_vector_type(2)));

// C[m,n] = cast<TC>( sum_k A[m,k]*W[n,k] + bias[n] )   (i.e. A @ W^T + b)
template<typename TA, typename TC>
__global__ __launch_bounds__(256) void gemm_bias(const TA* __restrict__ A,
    const float* __restrict__ W, const float* __restrict__ bias,
    TC* __restrict__ C, int Mdim, int Ndim, int Kdim)
{
    constexpr int BK = 16;
    __shared__ float As[BK][68];   // As[k][m], stride 68 keeps float4 reads 16B-aligned
    __shared__ float Ws[BK][68];   // Ws[k][n]
    const int tx = threadIdx.x, ty = threadIdx.y;   // 16x16
    const int tid = ty * 16 + tx;
    const int m0 = blockIdx.y * 64, n0 = blockIdx.x * 64;
    const int lrow = tid >> 2;          // 0..63
    const int lc4  = (tid & 3) * 4;     // 0,4,8,12

    float acc[4][4] = {};

    for (int kk = 0; kk < Kdim; kk += BK) {
        // stage A tile (64 rows x BK cols) and W tile (64 rows x BK cols)
        {
            const TA* ap = A + (size_t)(m0 + lrow) * Kdim + kk + lc4;
            float a0, a1, a2, a3;
            if constexpr (sizeof(TA) == 4) {
                float4 v = *reinterpret_cast<const float4*>(ap);
                a0 = v.x; a1 = v.y; a2 = v.z; a3 = v.w;
            } else {
                half2v v0 = *reinterpret_cast<const half2v*>(ap);
                half2v v1 = *reinterpret_cast<const half2v*>(ap + 2);
                a0 = (float)v0[0]; a1 = (float)v0[1];
                a2 = (float)v1[0]; a3 = (float)v1[1];
            }
            As[lc4 + 0][lrow] = a0; As[lc4 + 1][lrow] = a1;
            As[lc4 + 2][lrow] = a2; As[lc4 + 3][lrow] = a3;

            const float* wp = W + (size_t)(n0 + lrow) * Kdim + kk + lc4;
            float4 w = *reinterpret_cast<const float4*>(wp);
            Ws[lc4 + 0][lrow] = w.x; Ws[lc4 + 1][lrow] = w.y;
            Ws[lc4 + 2][lrow] = w.z; Ws[lc4 + 3][lrow] = w.w;
        }
        __syncthreads();
        #pragma unroll
        for (int k = 0; k < BK; ++k) {
            float4 av = *reinterpret_cast<const float4*>(&As[k][ty * 4]);
            float4 bv = *reinterpret_cast<const float4*>(&Ws[k][tx * 4]);
            float a[4] = {av.x, av.y, av.z, av.w};
            float b[4] = {bv.x, bv.y, bv.z, bv.w};
            #pragma unroll
            for (int i = 0; i < 4; ++i)
                #pragma unroll
                for (int j = 0; j < 4; ++j)
                    acc[i][j] = fmaf(a[i], b[j], acc[i][j]);
        }
        __syncthreads();
    }

    #pragma unroll
    for (int i = 0; i < 4; ++i) {
        const int m = m0 + ty * 4 + i;
        #pragma unroll
        for (int j = 0; j < 4; ++j) {
            const int n = n0 + tx * 4 + j;
            float v = acc[i][j] + bias[n];
            if constexpr (sizeof(TC) == 4)
                C[(size_t)m * Ndim + n] = v;
            else
                C[(size_t)m * Ndim + n] = (half_t)v;
        }
    }
}

// One block = one (b, h, 4 q-rows). Wave w owns q-row s0+w (lane = one of 64 dims/keys).
// Exact (non-online) softmax matching the reference's fp16 semantics:
//   e16 = f16(f32_dot(q16,k16)) * 0.125   (exact pow2 scale)
//   m   = max(e16);  p16 = f16(exp(e16 - m));  l = f32 sum(p16)
//   a16 = f16(p16 / l);  x16 = f16(f32_sum_k a16 * v16)
__global__ __launch_bounds__(256) void attn_kernel(const half_t* __restrict__ Q,
    const half_t* __restrict__ Kd, const half_t* __restrict__ V,
    half_t* __restrict__ X)
{
    __shared__ half_t KV[64 * 66];     // K or V tile, row stride 66 (bank-conflict-free)
    __shared__ half_t PE[4][SS];       // per-row scores -> p16 -> attn16
    __shared__ half_t QL[4][HDIM];

    const int tid  = threadIdx.x;
    const int wv   = tid >> 6;
    const int lane = tid & 63;
    const int b = blockIdx.z, h = blockIdx.y;
    const int s0 = blockIdx.x * 4;
    const size_t headoff = (size_t)(b * SS) * DD + h * HDIM;
    const int myrow = s0 + wv;

    QL[wv][lane] = Q[headoff + (size_t)myrow * DD + lane];

    float mrow = -1e30f;
    for (int t = 0; t < SS / 64; ++t) {
        __syncthreads();
        // stage K tile: 64 rows x 64 halves, as dword chunks
        #pragma unroll
        for (int j = 0; j < 8; ++j) {
            const int c = tid + j * 256;
            const int row = c >> 5, col2 = c & 31;
            const uint32_t val = *reinterpret_cast<const uint32_t*>(
                &Kd[headoff + (size_t)(t * 64 + row) * DD + col2 * 2]);
            *reinterpret_cast<uint32_t*>(&KV[row * 66 + col2 * 2]) = val;
        }
        __syncthreads();
        float s = 0.f;
        #pragma unroll
        for (int d2 = 0; d2 < 32; ++d2) {
            half2v qv = *reinterpret_cast<const half2v*>(&QL[wv][2 * d2]);
            half2v kv = *reinterpret_cast<const half2v*>(&KV[lane * 66 + 2 * d2]);
            s = fmaf((float)qv[0], (float)kv[0], s);   // v_fma_mix_f32
            s = fmaf((float)qv[1], (float)kv[1], s);
        }
        const half_t e16 = (half_t)s * (half_t)0.125f;  // exact pow2 scale
        PE[wv][t * 64 + lane] = e16;
        mrow = fmaxf(mrow, (float)e16);
    }

    // wave-reduce max over the 64 lanes
    #pragma unroll
    for (int off = 32; off; off >>= 1)
        mrow = fmaxf(mrow, __shfl_xor(mrow, off, 64));

    // p16 = f16(exp(e - m)); l = f32 sum of p16
    float lsum = 0.f;
    for (int t = 0; t < SS / 64; ++t) {
        const int k = t * 64 + lane;
        const float p = __expf((float)PE[wv][k] - mrow);
        const half_t p16 = (half_t)p;
        PE[wv][k] = p16;
        lsum += (float)p16;
    }
    #pragma unroll
    for (int off = 32; off; off >>= 1)
        lsum += __shfl_xor(lsum, off, 64);
    const float inv = 1.0f / lsum;
    for (int t = 0; t < SS / 64; ++t) {
        const int k = t * 64 + lane;
        PE[wv][k] = (half_t)((float)PE[wv][k] * inv);
    }

    // PV: lane owns output dim d = lane, f32 accumulate
    float acc = 0.f;
    for (int t = 0; t < SS / 64; ++t) {
        __syncthreads();
        #pragma unroll
        for (int j = 0; j < 8; ++j) {
            const int c = tid + j * 256;
            const int row = c >> 5, col2 = c & 31;
            const uint32_t val = *reinterpret_cast<const uint32_t*>(
                &V[headoff + (size_t)(t * 64 + row) * DD + col2 * 2]);
            *reinterpret_cast<uint32_t*>(&KV[row * 66 + col2 * 2]) = val;
        }
        __syncthreads();
        #pragma unroll
        for (int i = 0; i < 64; ++i) {
            const float a = (float)PE[wv][t * 64 + i];     // broadcast
            acc = fmaf(a, (float)KV[i * 66 + lane], acc);  // 2 lanes/bank: free
        }
    }
    X[headoff + (size_t)myrow * DD + lane] = (half_t)acc;
}

extern "C" void kernel_launch(void* const* d_in, const int* in_sizes, int n_in,
                              void* d_out, int out_size, void* d_ws, size_t ws_size,
                              hipStream_t stream) {
    const float* q   = (const float*)d_in[0];
    const float* k   = (const float*)d_in[1];
    const float* v   = (const float*)d_in[2];
    const float* Wq  = (const float*)d_in[3];
    const float* bq  = (const float*)d_in[4];
    const float* Wk  = (const float*)d_in[5];
    const float* bk  = (const float*)d_in[6];
    const float* Wv  = (const float*)d_in[7];
    const float* bv  = (const float*)d_in[8];
    const float* Wo  = (const float*)d_in[9];
    const float* bo  = (const float*)d_in[10];
    float* out = (float*)d_out;

    half_t* q16 = (half_t*)d_ws;
    half_t* k16 = q16 + (size_t)MTOT * DD;
    half_t* v16 = k16 + (size_t)MTOT * DD;
    half_t* x16 = v16 + (size_t)MTOT * DD;

    dim3 blk(16, 16);
    dim3 grd(DD / 64, MTOT / 64);
    hipLaunchKernelGGL((gemm_bias<float, half_t>), grd, blk, 0, stream,
                       q, Wq, bq, q16, MTOT, DD, DD);
    hipLaunchKernelGGL((gemm_bias<float, half_t>), grd, blk, 0, stream,
                       k, Wk, bk, k16, MTOT, DD, DD);
    hipLaunchKernelGGL((gemm_bias<float, half_t>), grd, blk, 0, stream,
                       v, Wv, bv, v16, MTOT, DD, DD);

    dim3 ablk(256);
    dim3 agrd(SS / 4, HH, BB);
    hipLaunchKernelGGL(attn_kernel, agrd, ablk, 0, stream, q16, k16, v16, x16);

    hipLaunchKernelGGL((gemm_bias<half_t, float>), grd, blk, 0, stream,
                       x16, Wo, bo, out, MTOT, DD, DD);
}

// Round 2
// 1203.779 us; speedup vs baseline: 3.6013x; 3.6013x over previous
//
#include <hip/hip_runtime.h>
#include <cstdint>

#define BB 4
#define SS 2048
#define DD 1024
#define HH 16
#define HDIM 64
#define MTOT (BB*SS)

using half_t = _Float16;
typedef _Float16 half2v __attribute__((ext_vector_type(2)));
typedef _Float16 half4v __attribute__((ext_vector_type(4)));
typedef float f32x4 __attribute__((ext_vector_type(4)));

// C[m,n] = cast<TC>( sum_k A[m,k]*W[n,k] + bias[n] )   (i.e. A @ W^T + b)
template<typename TA, typename TC>
__global__ __launch_bounds__(256) void gemm_bias(const TA* __restrict__ A,
    const float* __restrict__ W, const float* __restrict__ bias,
    TC* __restrict__ C, int Mdim, int Ndim, int Kdim)
{
    constexpr int BK = 16;
    __shared__ float As[BK][68];   // As[k][m]
    __shared__ float Ws[BK][68];   // Ws[k][n]
    const int tx = threadIdx.x, ty = threadIdx.y;   // 16x16
    const int tid = ty * 16 + tx;
    const int m0 = blockIdx.y * 64, n0 = blockIdx.x * 64;
    const int lrow = tid >> 2;          // 0..63
    const int lc4  = (tid & 3) * 4;     // 0,4,8,12

    float acc[4][4] = {};

    for (int kk = 0; kk < Kdim; kk += BK) {
        {
            const TA* ap = A + (size_t)(m0 + lrow) * Kdim + kk + lc4;
            float a0, a1, a2, a3;
            if constexpr (sizeof(TA) == 4) {
                float4 v = *reinterpret_cast<const float4*>(ap);
                a0 = v.x; a1 = v.y; a2 = v.z; a3 = v.w;
            } else {
                half2v v0 = *reinterpret_cast<const half2v*>(ap);
                half2v v1 = *reinterpret_cast<const half2v*>(ap + 2);
                a0 = (float)v0[0]; a1 = (float)v0[1];
                a2 = (float)v1[0]; a3 = (float)v1[1];
            }
            As[lc4 + 0][lrow] = a0; As[lc4 + 1][lrow] = a1;
            As[lc4 + 2][lrow] = a2; As[lc4 + 3][lrow] = a3;

            const float* wp = W + (size_t)(n0 + lrow) * Kdim + kk + lc4;
            float4 w = *reinterpret_cast<const float4*>(wp);
            Ws[lc4 + 0][lrow] = w.x; Ws[lc4 + 1][lrow] = w.y;
            Ws[lc4 + 2][lrow] = w.z; Ws[lc4 + 3][lrow] = w.w;
        }
        __syncthreads();
        #pragma unroll
        for (int k = 0; k < BK; ++k) {
            float4 av = *reinterpret_cast<const float4*>(&As[k][ty * 4]);
            float4 bv = *reinterpret_cast<const float4*>(&Ws[k][tx * 4]);
            float a[4] = {av.x, av.y, av.z, av.w};
            float b[4] = {bv.x, bv.y, bv.z, bv.w};
            #pragma unroll
            for (int i = 0; i < 4; ++i)
                #pragma unroll
                for (int j = 0; j < 4; ++j)
                    acc[i][j] = fmaf(a[i], b[j], acc[i][j]);
        }
        __syncthreads();
    }

    #pragma unroll
    for (int i = 0; i < 4; ++i) {
        const int m = m0 + ty * 4 + i;
        #pragma unroll
        for (int j = 0; j < 4; ++j) {
            const int n = n0 + tx * 4 + j;
            float v = acc[i][j] + bias[n];
            if constexpr (sizeof(TC) == 4)
                C[(size_t)m * Ndim + n] = v;
            else
                C[(size_t)m * Ndim + n] = (half_t)v;
        }
    }
}

// MFMA attention, swapped-operand QK^T, exact two-pass softmax (fp16 semantics).
// Block = 4 waves, 64 q-rows (16 per wave). Per K-tile of 64 keys:
//   T[k,q] = mfma(A=K_frag, B=Q_frag)  -> lane holds scores for q=lane&15 at
//   k = kb*16 + 4*(lane>>4) + j. e16 = f16(s)*0.125 (exact).
// Pass 1: running row max m + online f32 sum l.
// Pass 2: recompute scores, p16 = f16(exp(e16-m)), a16 = f16(p16/l),
//   x^T = mfma(A=Vt_frag, B=a16_frag) accumulated f32, rounded to f16.
__global__ __launch_bounds__(256) void attn_mfma(const half_t* __restrict__ Q,
    const half_t* __restrict__ K, const half_t* __restrict__ V,
    half_t* __restrict__ X)
{
    __shared__ half_t Ks[64][72];   // row stride 144B (16B-aligned, bank-spread)
    __shared__ half_t Vt[64][72];   // transposed V: Vt[d][k]

    const int tid = threadIdx.x;
    const int l   = tid & 63;
    const int w   = tid >> 6;
    const int lr  = l & 15;         // q-row within wave (and frag row)
    const int lg  = l >> 4;         // 4-lane group
    const int b = blockIdx.z, h = blockIdx.y;
    const int q0 = blockIdx.x * 64 + w * 16;
    const size_t hoff = (size_t)(b * SS) * DD + h * HDIM;

    // Q fragments: lane holds Q[q0+lr][hb*16 + 4*lg .. +3]
    half4v qf[4];
    {
        const half_t* qp = Q + hoff + (size_t)(q0 + lr) * DD;
        #pragma unroll
        for (int hb = 0; hb < 4; ++hb)
            qf[hb] = *reinterpret_cast<const half4v*>(qp + hb * 16 + 4 * lg);
    }

    float m = -1e30f, lsum = 0.f;

    // ---------------- pass 1: row max + sum ----------------
    for (int t = 0; t < SS / 64; ++t) {
        __syncthreads();
        {   // stage K tile: thread -> row tid>>2, 32B chunk (tid&3)*16
            const int r = tid >> 2, c0 = (tid & 3) * 16;
            const half_t* src = K + hoff + (size_t)(t * 64 + r) * DD + c0;
            *reinterpret_cast<int4*>(&Ks[r][c0])     = *reinterpret_cast<const int4*>(src);
            *reinterpret_cast<int4*>(&Ks[r][c0 + 8]) = *reinterpret_cast<const int4*>(src + 8);
        }
        __syncthreads();

        float ef[4][4];
        float tmax = -1e30f;
        #pragma unroll
        for (int kb = 0; kb < 4; ++kb) {
            f32x4 c = {0.f, 0.f, 0.f, 0.f};
            #pragma unroll
            for (int hb = 0; hb < 4; ++hb) {
                half4v kfr = *reinterpret_cast<const half4v*>(&Ks[kb * 16 + lr][hb * 16 + 4 * lg]);
                c = __builtin_amdgcn_mfma_f32_16x16x16f16(kfr, qf[hb], c, 0, 0, 0);
            }
            #pragma unroll
            for (int j = 0; j < 4; ++j) {
                half_t e = (half_t)c[j] * (half_t)0.125f;   // exact pow2 scale
                float fe = (float)e;
                ef[kb][j] = fe;
                tmax = fmaxf(tmax, fe);
            }
        }
        tmax = fmaxf(tmax, __shfl_xor(tmax, 16, 64));
        tmax = fmaxf(tmax, __shfl_xor(tmax, 32, 64));
        const float mnew = fmaxf(m, tmax);
        float ps = 0.f;
        #pragma unroll
        for (int kb = 0; kb < 4; ++kb)
            #pragma unroll
            for (int j = 0; j < 4; ++j)
                ps += __expf(ef[kb][j] - mnew);
        ps += __shfl_xor(ps, 16, 64);
        ps += __shfl_xor(ps, 32, 64);
        lsum = lsum * __expf(m - mnew) + ps;
        m = mnew;
    }

    const float invl = 1.0f / lsum;

    // ---------------- pass 2: recompute scores, PV ----------------
    f32x4 xacc[4] = {};
    for (int t = 0; t < SS / 64; ++t) {
        __syncthreads();
        {   // stage K tile
            const int r = tid >> 2, c0 = (tid & 3) * 16;
            const half_t* src = K + hoff + (size_t)(t * 64 + r) * DD + c0;
            *reinterpret_cast<int4*>(&Ks[r][c0])     = *reinterpret_cast<const int4*>(src);
            *reinterpret_cast<int4*>(&Ks[r][c0 + 8]) = *reinterpret_cast<const int4*>(src + 8);
        }
        {   // stage V transposed: thread handles k pair (2*k2, 2*k2+1), d = dq*8..+7
            const int k2 = tid & 31, dq = tid >> 5;
            const half_t* vsrc = V + hoff + (size_t)(t * 64 + 2 * k2) * DD + dq * 8;
            half_t va[8], vb[8];
            *reinterpret_cast<int4*>(va) = *reinterpret_cast<const int4*>(vsrc);
            *reinterpret_cast<int4*>(vb) = *reinterpret_cast<const int4*>(vsrc + DD);
            #pragma unroll
            for (int i = 0; i < 8; ++i) {
                half2v pk = {va[i], vb[i]};
                *reinterpret_cast<half2v*>(&Vt[dq * 8 + i][2 * k2]) = pk;
            }
        }
        __syncthreads();

        half4v af[4];
        #pragma unroll
        for (int kb = 0; kb < 4; ++kb) {
            f32x4 c = {0.f, 0.f, 0.f, 0.f};
            #pragma unroll
            for (int hb = 0; hb < 4; ++hb) {
                half4v kfr = *reinterpret_cast<const half4v*>(&Ks[kb * 16 + lr][hb * 16 + 4 * lg]);
                c = __builtin_amdgcn_mfma_f32_16x16x16f16(kfr, qf[hb], c, 0, 0, 0);
            }
            #pragma unroll
            for (int j = 0; j < 4; ++j) {
                half_t e = (half_t)c[j] * (half_t)0.125f;
                half_t p16 = (half_t)__expf((float)e - m);
                af[kb][j] = (half_t)((float)p16 * invl);
            }
        }
        #pragma unroll
        for (int db = 0; db < 4; ++db)
            #pragma unroll
            for (int kb = 0; kb < 4; ++kb) {
                half4v vf = *reinterpret_cast<const half4v*>(&Vt[db * 16 + lr][kb * 16 + 4 * lg]);
                xacc[db] = __builtin_amdgcn_mfma_f32_16x16x16f16(vf, af[kb], xacc[db], 0, 0, 0);
            }
    }

    // write x16: lane -> row q0+lr, d = db*16 + 4*lg .. +3
    {
        half_t* xp = X + hoff + (size_t)(q0 + lr) * DD;
        #pragma unroll
        for (int db = 0; db < 4; ++db) {
            half4v o;
            #pragma unroll
            for (int j = 0; j < 4; ++j) o[j] = (half_t)xacc[db][j];
            *reinterpret_cast<half4v*>(xp + db * 16 + 4 * lg) = o;
        }
    }
}

extern "C" void kernel_launch(void* const* d_in, const int* in_sizes, int n_in,
                              void* d_out, int out_size, void* d_ws, size_t ws_size,
                              hipStream_t stream) {
    const float* q   = (const float*)d_in[0];
    const float* k   = (const float*)d_in[1];
    const float* v   = (const float*)d_in[2];
    const float* Wq  = (const float*)d_in[3];
    const float* bq  = (const float*)d_in[4];
    const float* Wk  = (const float*)d_in[5];
    const float* bk  = (const float*)d_in[6];
    const float* Wv  = (const float*)d_in[7];
    const float* bv  = (const float*)d_in[8];
    const float* Wo  = (const float*)d_in[9];
    const float* bo  = (const float*)d_in[10];
    float* out = (float*)d_out;

    half_t* q16 = (half_t*)d_ws;
    half_t* k16 = q16 + (size_t)MTOT * DD;
    half_t* v16 = k16 + (size_t)MTOT * DD;
    half_t* x16 = v16 + (size_t)MTOT * DD;

    dim3 blk(16, 16);
    dim3 grd(DD / 64, MTOT / 64);
    hipLaunchKernelGGL((gemm_bias<float, half_t>), grd, blk, 0, stream,
                       q, Wq, bq, q16, MTOT, DD, DD);
    hipLaunchKernelGGL((gemm_bias<float, half_t>), grd, blk, 0, stream,
                       k, Wk, bk, k16, MTOT, DD, DD);
    hipLaunchKernelGGL((gemm_bias<float, half_t>), grd, blk, 0, stream,
                       v, Wv, bv, v16, MTOT, DD, DD);

    dim3 ablk(256);
    dim3 agrd(SS / 64, HH, BB);
    hipLaunchKernelGGL(attn_mfma, agrd, ablk, 0, stream, q16, k16, v16, x16);

    hipLaunchKernelGGL((gemm_bias<half_t, float>), grd, blk, 0, stream,
                       x16, Wo, bo, out, MTOT, DD, DD);
}

// Round 3
// 549.155 us; speedup vs baseline: 7.8942x; 2.1921x over previous
//
#include <hip/hip_runtime.h>
#include <cstdint>

#define BB 4
#define SS 2048
#define DD 1024
#define HH 16
#define HDIM 64
#define MTOT (BB*SS)

using half_t = _Float16;
typedef _Float16 half2v __attribute__((ext_vector_type(2)));
typedef _Float16 half4v __attribute__((ext_vector_type(4)));
typedef _Float16 half8v __attribute__((ext_vector_type(8)));
typedef float f32x4 __attribute__((ext_vector_type(4)));

// ---------------- fp32 -> (hi,lo) f16 split ----------------
__global__ __launch_bounds__(256) void split_hi_lo(const float* __restrict__ x,
    half_t* __restrict__ hi, half_t* __restrict__ lo, int n4)
{
    const int i = blockIdx.x * blockDim.x + threadIdx.x;
    if (i >= n4) return;
    float4 v = reinterpret_cast<const float4*>(x)[i];
    float vv[4] = {v.x, v.y, v.z, v.w};
    half4v h, l;
    #pragma unroll
    for (int j = 0; j < 4; ++j) {
        half_t hh = (half_t)vv[j];
        h[j] = hh;
        l[j] = (half_t)(vv[j] - (float)hh);
    }
    reinterpret_cast<half4v*>(hi)[i] = h;
    reinterpret_cast<half4v*>(lo)[i] = l;
}

// ---------------- MFMA split-f16 GEMM: C = A @ W^T + b ----------------
// MODE 0: A presplit (Ah, Al); 3 products.  MODE 1: A fp32, split in-kernel;
// 3 products.  MODE 2: A exact f16 (Ah); 2 products (Wh + Wl).
// Tile 128x128, BK=32, 4 waves of 64x64, mfma_f32_16x16x32_f16.
// LDS row stride 72 halves (144B): b128 stage-writes and frag-reads are
// bank-uniform (16B-slot class = (9*row + col16)%8 covers 0..7 evenly).
template<int MODE, typename TC>
__global__ __launch_bounds__(256) void gemm3s(
    const half_t* __restrict__ Ah, const half_t* __restrict__ Al,
    const float* __restrict__ Af,
    const half_t* __restrict__ Wh, const half_t* __restrict__ Wl,
    const float* __restrict__ bias, TC* __restrict__ C,
    int Kdim, int Ndim)
{
    constexpr int LDT = 72;   // hi: cols 0..31, lo: cols 40..71
    __shared__ __align__(16) half_t As[128 * LDT];
    __shared__ __align__(16) half_t Ws[128 * LDT];
    const int tid = threadIdx.x;
    const int l = tid & 63, w = tid >> 6;
    const int lr = l & 15, lg = l >> 4;
    const int wr = w >> 1, wc = w & 1;
    const int m0 = blockIdx.y * 128, n0 = blockIdx.x * 128;
    const int r = tid >> 1, t = tid & 1;   // staging: row 0..127, 16-col half

    f32x4 acc[4][4] = {};

    for (int kk = 0; kk < Kdim; kk += 32) {
        __syncthreads();
        // ---- stage A tile ----
        if constexpr (MODE == 1) {
            const float* ap = Af + (size_t)(m0 + r) * Kdim + kk + 16 * t;
            half_t hbuf[16], lbuf[16];
            #pragma unroll
            for (int u = 0; u < 4; ++u) {
                float4 v = *reinterpret_cast<const float4*>(ap + 4 * u);
                float vv[4] = {v.x, v.y, v.z, v.w};
                #pragma unroll
                for (int j = 0; j < 4; ++j) {
                    half_t hh = (half_t)vv[j];
                    hbuf[4 * u + j] = hh;
                    lbuf[4 * u + j] = (half_t)(vv[j] - (float)hh);
                }
            }
            *reinterpret_cast<int4*>(&As[r * LDT + 16 * t])          = *reinterpret_cast<int4*>(hbuf);
            *reinterpret_cast<int4*>(&As[r * LDT + 16 * t + 8])      = *reinterpret_cast<int4*>(hbuf + 8);
            *reinterpret_cast<int4*>(&As[r * LDT + 40 + 16 * t])     = *reinterpret_cast<int4*>(lbuf);
            *reinterpret_cast<int4*>(&As[r * LDT + 40 + 16 * t + 8]) = *reinterpret_cast<int4*>(lbuf + 8);
        } else {
            const half_t* ap = Ah + (size_t)(m0 + r) * Kdim + kk + 16 * t;
            *reinterpret_cast<int4*>(&As[r * LDT + 16 * t])     = *reinterpret_cast<const int4*>(ap);
            *reinterpret_cast<int4*>(&As[r * LDT + 16 * t + 8]) = *reinterpret_cast<const int4*>(ap + 8);
            if constexpr (MODE == 0) {
                const half_t* alp = Al + (size_t)(m0 + r) * Kdim + kk + 16 * t;
                *reinterpret_cast<int4*>(&As[r * LDT + 40 + 16 * t])     = *reinterpret_cast<const int4*>(alp);
                *reinterpret_cast<int4*>(&As[r * LDT + 40 + 16 * t + 8]) = *reinterpret_cast<const int4*>(alp + 8);
            }
        }
        // ---- stage W tile (always presplit) ----
        {
            const half_t* wp = Wh + (size_t)(n0 + r) * Kdim + kk + 16 * t;
            *reinterpret_cast<int4*>(&Ws[r * LDT + 16 * t])     = *reinterpret_cast<const int4*>(wp);
            *reinterpret_cast<int4*>(&Ws[r * LDT + 16 * t + 8]) = *reinterpret_cast<const int4*>(wp + 8);
            const half_t* wlp = Wl + (size_t)(n0 + r) * Kdim + kk + 16 * t;
            *reinterpret_cast<int4*>(&Ws[r * LDT + 40 + 16 * t])     = *reinterpret_cast<const int4*>(wlp);
            *reinterpret_cast<int4*>(&Ws[r * LDT + 40 + 16 * t + 8]) = *reinterpret_cast<const int4*>(wlp + 8);
        }
        __syncthreads();

        half8v af[4], alf[4];
        #pragma unroll
        for (int mt = 0; mt < 4; ++mt) {
            af[mt] = *reinterpret_cast<const half8v*>(&As[(wr * 64 + mt * 16 + lr) * LDT + 8 * lg]);
            if constexpr (MODE != 2)
                alf[mt] = *reinterpret_cast<const half8v*>(&As[(wr * 64 + mt * 16 + lr) * LDT + 40 + 8 * lg]);
        }
        #pragma unroll
        for (int nt = 0; nt < 4; ++nt) {
            half8v wf  = *reinterpret_cast<const half8v*>(&Ws[(wc * 64 + nt * 16 + lr) * LDT + 8 * lg]);
            half8v wlf = *reinterpret_cast<const half8v*>(&Ws[(wc * 64 + nt * 16 + lr) * LDT + 40 + 8 * lg]);
            #pragma unroll
            for (int mt = 0; mt < 4; ++mt) {
                acc[mt][nt] = __builtin_amdgcn_mfma_f32_16x16x32_f16(af[mt], wf, acc[mt][nt], 0, 0, 0);
                acc[mt][nt] = __builtin_amdgcn_mfma_f32_16x16x32_f16(af[mt], wlf, acc[mt][nt], 0, 0, 0);
                if constexpr (MODE != 2)
                    acc[mt][nt] = __builtin_amdgcn_mfma_f32_16x16x32_f16(alf[mt], wf, acc[mt][nt], 0, 0, 0);
            }
        }
    }

    #pragma unroll
    for (int nt = 0; nt < 4; ++nt) {
        const int n = n0 + wc * 64 + nt * 16 + lr;
        const float bn = bias[n];
        #pragma unroll
        for (int mt = 0; mt < 4; ++mt) {
            const int mbase = m0 + wr * 64 + mt * 16 + 4 * lg;
            #pragma unroll
            for (int j = 0; j < 4; ++j) {
                float v = acc[mt][nt][j] + bn;
                if constexpr (sizeof(TC) == 4)
                    C[(size_t)(mbase + j) * Ndim + n] = v;
                else
                    C[(size_t)(mbase + j) * Ndim + n] = (half_t)v;
            }
        }
    }
}

// ---------------- fp32 vector GEMM (ultimate fallback only) ----------------
template<typename TA, typename TC>
__global__ __launch_bounds__(256) void gemm_bias(const TA* __restrict__ A,
    const float* __restrict__ W, const float* __restrict__ bias,
    TC* __restrict__ C, int Mdim, int Ndim, int Kdim)
{
    constexpr int BK = 16;
    __shared__ float As[BK][68];
    __shared__ float Ws[BK][68];
    const int tx = threadIdx.x, ty = threadIdx.y;
    const int tid = ty * 16 + tx;
    const int m0 = blockIdx.y * 64, n0 = blockIdx.x * 64;
    const int lrow = tid >> 2;
    const int lc4  = (tid & 3) * 4;

    float acc[4][4] = {};
    for (int kk = 0; kk < Kdim; kk += BK) {
        {
            const TA* ap = A + (size_t)(m0 + lrow) * Kdim + kk + lc4;
            float a0, a1, a2, a3;
            if constexpr (sizeof(TA) == 4) {
                float4 v = *reinterpret_cast<const float4*>(ap);
                a0 = v.x; a1 = v.y; a2 = v.z; a3 = v.w;
            } else {
                half2v v0 = *reinterpret_cast<const half2v*>(ap);
                half2v v1 = *reinterpret_cast<const half2v*>(ap + 2);
                a0 = (float)v0[0]; a1 = (float)v0[1];
                a2 = (float)v1[0]; a3 = (float)v1[1];
            }
            As[lc4 + 0][lrow] = a0; As[lc4 + 1][lrow] = a1;
            As[lc4 + 2][lrow] = a2; As[lc4 + 3][lrow] = a3;
            const float* wp = W + (size_t)(n0 + lrow) * Kdim + kk + lc4;
            float4 wv = *reinterpret_cast<const float4*>(wp);
            Ws[lc4 + 0][lrow] = wv.x; Ws[lc4 + 1][lrow] = wv.y;
            Ws[lc4 + 2][lrow] = wv.z; Ws[lc4 + 3][lrow] = wv.w;
        }
        __syncthreads();
        #pragma unroll
        for (int k = 0; k < BK; ++k) {
            float4 av = *reinterpret_cast<const float4*>(&As[k][ty * 4]);
            float4 bv = *reinterpret_cast<const float4*>(&Ws[k][tx * 4]);
            float a[4] = {av.x, av.y, av.z, av.w};
            float b[4] = {bv.x, bv.y, bv.z, bv.w};
            #pragma unroll
            for (int i = 0; i < 4; ++i)
                #pragma unroll
                for (int j = 0; j < 4; ++j)
                    acc[i][j] = fmaf(a[i], b[j], acc[i][j]);
        }
        __syncthreads();
    }
    #pragma unroll
    for (int i = 0; i < 4; ++i) {
        const int m = m0 + ty * 4 + i;
        #pragma unroll
        for (int j = 0; j < 4; ++j) {
            const int n = n0 + tx * 4 + j;
            float v = acc[i][j] + bias[n];
            if constexpr (sizeof(TC) == 4)
                C[(size_t)m * Ndim + n] = v;
            else
                C[(size_t)m * Ndim + n] = (half_t)v;
        }
    }
}

// ---------------- MFMA attention (unchanged from round 2) ----------------
__global__ __launch_bounds__(256) void attn_mfma(const half_t* __restrict__ Q,
    const half_t* __restrict__ K, const half_t* __restrict__ V,
    half_t* __restrict__ X)
{
    __shared__ half_t Ks[64][72];
    __shared__ half_t Vt[64][72];

    const int tid = threadIdx.x;
    const int l   = tid & 63;
    const int w   = tid >> 6;
    const int lr  = l & 15;
    const int lg  = l >> 4;
    const int b = blockIdx.z, h = blockIdx.y;
    const int q0 = blockIdx.x * 64 + w * 16;
    const size_t hoff = (size_t)(b * SS) * DD + h * HDIM;

    half4v qf[4];
    {
        const half_t* qp = Q + hoff + (size_t)(q0 + lr) * DD;
        #pragma unroll
        for (int hb = 0; hb < 4; ++hb)
            qf[hb] = *reinterpret_cast<const half4v*>(qp + hb * 16 + 4 * lg);
    }

    float m = -1e30f, lsum = 0.f;

    for (int t = 0; t < SS / 64; ++t) {
        __syncthreads();
        {
            const int r = tid >> 2, c0 = (tid & 3) * 16;
            const half_t* src = K + hoff + (size_t)(t * 64 + r) * DD + c0;
            *reinterpret_cast<int4*>(&Ks[r][c0])     = *reinterpret_cast<const int4*>(src);
            *reinterpret_cast<int4*>(&Ks[r][c0 + 8]) = *reinterpret_cast<const int4*>(src + 8);
        }
        __syncthreads();

        float ef[4][4];
        float tmax = -1e30f;
        #pragma unroll
        for (int kb = 0; kb < 4; ++kb) {
            f32x4 c = {0.f, 0.f, 0.f, 0.f};
            #pragma unroll
            for (int hb = 0; hb < 4; ++hb) {
                half4v kfr = *reinterpret_cast<const half4v*>(&Ks[kb * 16 + lr][hb * 16 + 4 * lg]);
                c = __builtin_amdgcn_mfma_f32_16x16x16f16(kfr, qf[hb], c, 0, 0, 0);
            }
            #pragma unroll
            for (int j = 0; j < 4; ++j) {
                half_t e = (half_t)c[j] * (half_t)0.125f;
                float fe = (float)e;
                ef[kb][j] = fe;
                tmax = fmaxf(tmax, fe);
            }
        }
        tmax = fmaxf(tmax, __shfl_xor(tmax, 16, 64));
        tmax = fmaxf(tmax, __shfl_xor(tmax, 32, 64));
        const float mnew = fmaxf(m, tmax);
        float ps = 0.f;
        #pragma unroll
        for (int kb = 0; kb < 4; ++kb)
            #pragma unroll
            for (int j = 0; j < 4; ++j)
                ps += __expf(ef[kb][j] - mnew);
        ps += __shfl_xor(ps, 16, 64);
        ps += __shfl_xor(ps, 32, 64);
        lsum = lsum * __expf(m - mnew) + ps;
        m = mnew;
    }

    const float invl = 1.0f / lsum;

    f32x4 xacc[4] = {};
    for (int t = 0; t < SS / 64; ++t) {
        __syncthreads();
        {
            const int r = tid >> 2, c0 = (tid & 3) * 16;
            const half_t* src = K + hoff + (size_t)(t * 64 + r) * DD + c0;
            *reinterpret_cast<int4*>(&Ks[r][c0])     = *reinterpret_cast<const int4*>(src);
            *reinterpret_cast<int4*>(&Ks[r][c0 + 8]) = *reinterpret_cast<const int4*>(src + 8);
        }
        {
            const int k2 = tid & 31, dq = tid >> 5;
            const half_t* vsrc = V + hoff + (size_t)(t * 64 + 2 * k2) * DD + dq * 8;
            half_t va[8], vb[8];
            *reinterpret_cast<int4*>(va) = *reinterpret_cast<const int4*>(vsrc);
            *reinterpret_cast<int4*>(vb) = *reinterpret_cast<const int4*>(vsrc + DD);
            #pragma unroll
            for (int i = 0; i < 8; ++i) {
                half2v pk = {va[i], vb[i]};
                *reinterpret_cast<half2v*>(&Vt[dq * 8 + i][2 * k2]) = pk;
            }
        }
        __syncthreads();

        half4v af[4];
        #pragma unroll
        for (int kb = 0; kb < 4; ++kb) {
            f32x4 c = {0.f, 0.f, 0.f, 0.f};
            #pragma unroll
            for (int hb = 0; hb < 4; ++hb) {
                half4v kfr = *reinterpret_cast<const half4v*>(&Ks[kb * 16 + lr][hb * 16 + 4 * lg]);
                c = __builtin_amdgcn_mfma_f32_16x16x16f16(kfr, qf[hb], c, 0, 0, 0);
            }
            #pragma unroll
            for (int j = 0; j < 4; ++j) {
                half_t e = (half_t)c[j] * (half_t)0.125f;
                half_t p16 = (half_t)__expf((float)e - m);
                af[kb][j] = (half_t)((float)p16 * invl);
            }
        }
        #pragma unroll
        for (int db = 0; db < 4; ++db)
            #pragma unroll
            for (int kb = 0; kb < 4; ++kb) {
                half4v vf = *reinterpret_cast<const half4v*>(&Vt[db * 16 + lr][kb * 16 + 4 * lg]);
                xacc[db] = __builtin_amdgcn_mfma_f32_16x16x16f16(vf, af[kb], xacc[db], 0, 0, 0);
            }
    }

    {
        half_t* xp = X + hoff + (size_t)(q0 + lr) * DD;
        #pragma unroll
        for (int db = 0; db < 4; ++db) {
            half4v o;
            #pragma unroll
            for (int j = 0; j < 4; ++j) o[j] = (half_t)xacc[db][j];
            *reinterpret_cast<half4v*>(xp + db * 16 + 4 * lg) = o;
        }
    }
}

extern "C" void kernel_launch(void* const* d_in, const int* in_sizes, int n_in,
                              void* d_out, int out_size, void* d_ws, size_t ws_size,
                              hipStream_t stream) {
    const float* q   = (const float*)d_in[0];
    const float* k   = (const float*)d_in[1];
    const float* v   = (const float*)d_in[2];
    const float* Wq  = (const float*)d_in[3];
    const float* bq  = (const float*)d_in[4];
    const float* Wk  = (const float*)d_in[5];
    const float* bk  = (const float*)d_in[6];
    const float* Wv  = (const float*)d_in[7];
    const float* bv  = (const float*)d_in[8];
    const float* Wo  = (const float*)d_in[9];
    const float* bo  = (const float*)d_in[10];
    float* out = (float*)d_out;

    const size_t MB = 1ull << 20;
    const size_t ACT = (size_t)MTOT * DD;   // 8.39M elems
    const size_t WEL = (size_t)DD * DD;     // 1.05M elems

    half_t* q16 = (half_t*)d_ws;
    half_t* k16 = q16 + ACT;
    half_t* v16 = k16 + ACT;
    half_t* x16 = v16 + ACT;

    dim3 gblk(256);
    dim3 ggrd(DD / 128, MTOT / 128);
    dim3 ablk(256);
    dim3 agrd(SS / 64, HH, BB);

    const bool full  = ws_size >= 101 * MB;   // + ah, al, wh, wl
    const bool wonly = ws_size >= 69 * MB;    // + wh, wl only

    if (full) {
        half_t* ah = x16 + ACT;
        half_t* al = ah + ACT;
        half_t* wh = al + ACT;
        half_t* wl = wh + WEL;
        const int nact4 = (int)(ACT / 4), nw4 = (int)(WEL / 4);
        dim3 sgA((nact4 + 255) / 256), sgW((nw4 + 255) / 256);

        hipLaunchKernelGGL(split_hi_lo, sgA, gblk, 0, stream, q, ah, al, nact4);
        hipLaunchKernelGGL(split_hi_lo, sgW, gblk, 0, stream, Wq, wh, wl, nw4);
        hipLaunchKernelGGL((gemm3s<0, half_t>), ggrd, gblk, 0, stream,
                           ah, al, nullptr, wh, wl, bq, q16, DD, DD);
        hipLaunchKernelGGL(split_hi_lo, sgA, gblk, 0, stream, k, ah, al, nact4);
        hipLaunchKernelGGL(split_hi_lo, sgW, gblk, 0, stream, Wk, wh, wl, nw4);
        hipLaunchKernelGGL((gemm3s<0, half_t>), ggrd, gblk, 0, stream,
                           ah, al, nullptr, wh, wl, bk, k16, DD, DD);
        hipLaunchKernelGGL(split_hi_lo, sgA, gblk, 0, stream, v, ah, al, nact4);
        hipLaunchKernelGGL(split_hi_lo, sgW, gblk, 0, stream, Wv, wh, wl, nw4);
        hipLaunchKernelGGL((gemm3s<0, half_t>), ggrd, gblk, 0, stream,
                           ah, al, nullptr, wh, wl, bv, v16, DD, DD);

        hipLaunchKernelGGL(attn_mfma, agrd, ablk, 0, stream, q16, k16, v16, x16);

        hipLaunchKernelGGL(split_hi_lo, sgW, gblk, 0, stream, Wo, wh, wl, nw4);
        hipLaunchKernelGGL((gemm3s<2, float>), ggrd, gblk, 0, stream,
                           x16, nullptr, nullptr, wh, wl, bo, out, DD, DD);
    } else if (wonly) {
        half_t* wh = x16 + ACT;
        half_t* wl = wh + WEL;
        const int nw4 = (int)(WEL / 4);
        dim3 sgW((nw4 + 255) / 256);

        hipLaunchKernelGGL(split_hi_lo, sgW, gblk, 0, stream, Wq, wh, wl, nw4);
        hipLaunchKernelGGL((gemm3s<1, half_t>), ggrd, gblk, 0, stream,
                           nullptr, nullptr, q, wh, wl, bq, q16, DD, DD);
        hipLaunchKernelGGL(split_hi_lo, sgW, gblk, 0, stream, Wk, wh, wl, nw4);
        hipLaunchKernelGGL((gemm3s<1, half_t>), ggrd, gblk, 0, stream,
                           nullptr, nullptr, k, wh, wl, bk, k16, DD, DD);
        hipLaunchKernelGGL(split_hi_lo, sgW, gblk, 0, stream, Wv, wh, wl, nw4);
        hipLaunchKernelGGL((gemm3s<1, half_t>), ggrd, gblk, 0, stream,
                           nullptr, nullptr, v, wh, wl, bv, v16, DD, DD);

        hipLaunchKernelGGL(attn_mfma, agrd, ablk, 0, stream, q16, k16, v16, x16);

        hipLaunchKernelGGL(split_hi_lo, sgW, gblk, 0, stream, Wo, wh, wl, nw4);
        hipLaunchKernelGGL((gemm3s<2, float>), ggrd, gblk, 0, stream,
                           x16, nullptr, nullptr, wh, wl, bo, out, DD, DD);
    } else {
        dim3 blk(16, 16);
        dim3 grd(DD / 64, MTOT / 64);
        hipLaunchKernelGGL((gemm_bias<float, half_t>), grd, blk, 0, stream,
                           q, Wq, bq, q16, MTOT, DD, DD);
        hipLaunchKernelGGL((gemm_bias<float, half_t>), grd, blk, 0, stream,
                           k, Wk, bk, k16, MTOT, DD, DD);
        hipLaunchKernelGGL((gemm_bias<float, half_t>), grd, blk, 0, stream,
                           v, Wv, bv, v16, MTOT, DD, DD);
        hipLaunchKernelGGL(attn_mfma, agrd, ablk, 0, stream, q16, k16, v16, x16);
        hipLaunchKernelGGL((gemm_bias<half_t, float>), grd, blk, 0, stream,
                           x16, Wo, bo, out, MTOT, DD, DD);
    }
}

// Round 4
// 415.881 us; speedup vs baseline: 10.4240x; 1.3205x over previous
//
#include <hip/hip_runtime.h>
#include <cstdint>

#define BB 4
#define SS 2048
#define DD 1024
#define HH 16
#define HDIM 64
#define MTOT (BB*SS)

using half_t = _Float16;
typedef _Float16 half2v __attribute__((ext_vector_type(2)));
typedef _Float16 half4v __attribute__((ext_vector_type(4)));
typedef _Float16 half8v __attribute__((ext_vector_type(8)));
typedef float f32x4 __attribute__((ext_vector_type(4)));

// ---------------- fp32 -> (hi,lo) f16 split ----------------
__global__ __launch_bounds__(256) void split_hi_lo(const float* __restrict__ x,
    half_t* __restrict__ hi, half_t* __restrict__ lo, int n4)
{
    const int i = blockIdx.x * blockDim.x + threadIdx.x;
    if (i >= n4) return;
    float4 v = reinterpret_cast<const float4*>(x)[i];
    float vv[4] = {v.x, v.y, v.z, v.w};
    half4v h, l;
    #pragma unroll
    for (int j = 0; j < 4; ++j) {
        half_t hh = (half_t)vv[j];
        h[j] = hh;
        l[j] = (half_t)(vv[j] - (float)hh);
    }
    reinterpret_cast<half4v*>(hi)[i] = h;
    reinterpret_cast<half4v*>(lo)[i] = l;
}

// ---------------- MFMA split-f16 GEMM: C = A @ W^T + b ----------------
template<int MODE, typename TC>
__global__ __launch_bounds__(256) void gemm3s(
    const half_t* __restrict__ Ah, const half_t* __restrict__ Al,
    const float* __restrict__ Af,
    const half_t* __restrict__ Wh, const half_t* __restrict__ Wl,
    const float* __restrict__ bias, TC* __restrict__ C,
    int Kdim, int Ndim)
{
    constexpr int LDT = 72;   // hi: cols 0..31, lo: cols 40..71
    __shared__ __align__(16) half_t As[128 * LDT];
    __shared__ __align__(16) half_t Ws[128 * LDT];
    const int tid = threadIdx.x;
    const int l = tid & 63, w = tid >> 6;
    const int lr = l & 15, lg = l >> 4;
    const int wr = w >> 1, wc = w & 1;
    const int m0 = blockIdx.y * 128, n0 = blockIdx.x * 128;
    const int r = tid >> 1, t = tid & 1;

    f32x4 acc[4][4] = {};

    for (int kk = 0; kk < Kdim; kk += 32) {
        __syncthreads();
        if constexpr (MODE == 1) {
            const float* ap = Af + (size_t)(m0 + r) * Kdim + kk + 16 * t;
            half_t hbuf[16], lbuf[16];
            #pragma unroll
            for (int u = 0; u < 4; ++u) {
                float4 v = *reinterpret_cast<const float4*>(ap + 4 * u);
                float vv[4] = {v.x, v.y, v.z, v.w};
                #pragma unroll
                for (int j = 0; j < 4; ++j) {
                    half_t hh = (half_t)vv[j];
                    hbuf[4 * u + j] = hh;
                    lbuf[4 * u + j] = (half_t)(vv[j] - (float)hh);
                }
            }
            *reinterpret_cast<int4*>(&As[r * LDT + 16 * t])          = *reinterpret_cast<int4*>(hbuf);
            *reinterpret_cast<int4*>(&As[r * LDT + 16 * t + 8])      = *reinterpret_cast<int4*>(hbuf + 8);
            *reinterpret_cast<int4*>(&As[r * LDT + 40 + 16 * t])     = *reinterpret_cast<int4*>(lbuf);
            *reinterpret_cast<int4*>(&As[r * LDT + 40 + 16 * t + 8]) = *reinterpret_cast<int4*>(lbuf + 8);
        } else {
            const half_t* ap = Ah + (size_t)(m0 + r) * Kdim + kk + 16 * t;
            *reinterpret_cast<int4*>(&As[r * LDT + 16 * t])     = *reinterpret_cast<const int4*>(ap);
            *reinterpret_cast<int4*>(&As[r * LDT + 16 * t + 8]) = *reinterpret_cast<const int4*>(ap + 8);
            if constexpr (MODE == 0) {
                const half_t* alp = Al + (size_t)(m0 + r) * Kdim + kk + 16 * t;
                *reinterpret_cast<int4*>(&As[r * LDT + 40 + 16 * t])     = *reinterpret_cast<const int4*>(alp);
                *reinterpret_cast<int4*>(&As[r * LDT + 40 + 16 * t + 8]) = *reinterpret_cast<const int4*>(alp + 8);
            }
        }
        {
            const half_t* wp = Wh + (size_t)(n0 + r) * Kdim + kk + 16 * t;
            *reinterpret_cast<int4*>(&Ws[r * LDT + 16 * t])     = *reinterpret_cast<const int4*>(wp);
            *reinterpret_cast<int4*>(&Ws[r * LDT + 16 * t + 8]) = *reinterpret_cast<const int4*>(wp + 8);
            const half_t* wlp = Wl + (size_t)(n0 + r) * Kdim + kk + 16 * t;
            *reinterpret_cast<int4*>(&Ws[r * LDT + 40 + 16 * t])     = *reinterpret_cast<const int4*>(wlp);
            *reinterpret_cast<int4*>(&Ws[r * LDT + 40 + 16 * t + 8]) = *reinterpret_cast<const int4*>(wlp + 8);
        }
        __syncthreads();

        half8v af[4], alf[4];
        #pragma unroll
        for (int mt = 0; mt < 4; ++mt) {
            af[mt] = *reinterpret_cast<const half8v*>(&As[(wr * 64 + mt * 16 + lr) * LDT + 8 * lg]);
            if constexpr (MODE != 2)
                alf[mt] = *reinterpret_cast<const half8v*>(&As[(wr * 64 + mt * 16 + lr) * LDT + 40 + 8 * lg]);
        }
        #pragma unroll
        for (int nt = 0; nt < 4; ++nt) {
            half8v wf  = *reinterpret_cast<const half8v*>(&Ws[(wc * 64 + nt * 16 + lr) * LDT + 8 * lg]);
            half8v wlf = *reinterpret_cast<const half8v*>(&Ws[(wc * 64 + nt * 16 + lr) * LDT + 40 + 8 * lg]);
            #pragma unroll
            for (int mt = 0; mt < 4; ++mt) {
                acc[mt][nt] = __builtin_amdgcn_mfma_f32_16x16x32_f16(af[mt], wf, acc[mt][nt], 0, 0, 0);
                acc[mt][nt] = __builtin_amdgcn_mfma_f32_16x16x32_f16(af[mt], wlf, acc[mt][nt], 0, 0, 0);
                if constexpr (MODE != 2)
                    acc[mt][nt] = __builtin_amdgcn_mfma_f32_16x16x32_f16(alf[mt], wf, acc[mt][nt], 0, 0, 0);
            }
        }
    }

    #pragma unroll
    for (int nt = 0; nt < 4; ++nt) {
        const int n = n0 + wc * 64 + nt * 16 + lr;
        const float bn = bias[n];
        #pragma unroll
        for (int mt = 0; mt < 4; ++mt) {
            const int mbase = m0 + wr * 64 + mt * 16 + 4 * lg;
            #pragma unroll
            for (int j = 0; j < 4; ++j) {
                float v = acc[mt][nt][j] + bn;
                if constexpr (sizeof(TC) == 4)
                    C[(size_t)(mbase + j) * Ndim + n] = v;
                else
                    C[(size_t)(mbase + j) * Ndim + n] = (half_t)v;
            }
        }
    }
}

// ---------------- fp32 vector GEMM (ultimate fallback only) ----------------
template<typename TA, typename TC>
__global__ __launch_bounds__(256) void gemm_bias(const TA* __restrict__ A,
    const float* __restrict__ W, const float* __restrict__ bias,
    TC* __restrict__ C, int Mdim, int Ndim, int Kdim)
{
    constexpr int BK = 16;
    __shared__ float As[BK][68];
    __shared__ float Ws[BK][68];
    const int tx = threadIdx.x, ty = threadIdx.y;
    const int tid = ty * 16 + tx;
    const int m0 = blockIdx.y * 64, n0 = blockIdx.x * 64;
    const int lrow = tid >> 2;
    const int lc4  = (tid & 3) * 4;

    float acc[4][4] = {};
    for (int kk = 0; kk < Kdim; kk += BK) {
        {
            const TA* ap = A + (size_t)(m0 + lrow) * Kdim + kk + lc4;
            float a0, a1, a2, a3;
            if constexpr (sizeof(TA) == 4) {
                float4 v = *reinterpret_cast<const float4*>(ap);
                a0 = v.x; a1 = v.y; a2 = v.z; a3 = v.w;
            } else {
                half2v v0 = *reinterpret_cast<const half2v*>(ap);
                half2v v1 = *reinterpret_cast<const half2v*>(ap + 2);
                a0 = (float)v0[0]; a1 = (float)v0[1];
                a2 = (float)v1[0]; a3 = (float)v1[1];
            }
            As[lc4 + 0][lrow] = a0; As[lc4 + 1][lrow] = a1;
            As[lc4 + 2][lrow] = a2; As[lc4 + 3][lrow] = a3;
            const float* wp = W + (size_t)(n0 + lrow) * Kdim + kk + lc4;
            float4 wv = *reinterpret_cast<const float4*>(wp);
            Ws[lc4 + 0][lrow] = wv.x; Ws[lc4 + 1][lrow] = wv.y;
            Ws[lc4 + 2][lrow] = wv.z; Ws[lc4 + 3][lrow] = wv.w;
        }
        __syncthreads();
        #pragma unroll
        for (int k = 0; k < BK; ++k) {
            float4 av = *reinterpret_cast<const float4*>(&As[k][ty * 4]);
            float4 bv = *reinterpret_cast<const float4*>(&Ws[k][tx * 4]);
            float a[4] = {av.x, av.y, av.z, av.w};
            float b[4] = {bv.x, bv.y, bv.z, bv.w};
            #pragma unroll
            for (int i = 0; i < 4; ++i)
                #pragma unroll
                for (int j = 0; j < 4; ++j)
                    acc[i][j] = fmaf(a[i], b[j], acc[i][j]);
        }
        __syncthreads();
    }
    #pragma unroll
    for (int i = 0; i < 4; ++i) {
        const int m = m0 + ty * 4 + i;
        #pragma unroll
        for (int j = 0; j < 4; ++j) {
            const int n = n0 + tx * 4 + j;
            float v = acc[i][j] + bias[n];
            if constexpr (sizeof(TC) == 4)
                C[(size_t)m * Ndim + n] = v;
            else
                C[(size_t)m * Ndim + n] = (half_t)v;
        }
    }
}

// ---------------- single-pass fused attention ----------------
// Block = 4 waves x 32 q-rows (2 sets of 16) = 128 q-rows.
// Per 64-key tile: QK^T via mfma_f32_16x16x32_f16 (swapped: A=K from LDS,
// B=Q from regs -> lane owns q=l&15, keys 4*lg+j per kb). Online softmax
// with defer-max (THR=8, p <= e^8 fits f16; scales cancel in final divide).
// PV via mfma 16x16x16 (A=Vt from LDS, B=p16 in-register). Double-buffered
// LDS, one barrier/tile, loads issued before MFMA phase (T14).
__global__ __launch_bounds__(256, 4) void attn_fused(const half_t* __restrict__ Q,
    const half_t* __restrict__ K, const half_t* __restrict__ V,
    half_t* __restrict__ X)
{
    __shared__ __align__(16) half_t Ks[2][64 * 72];
    __shared__ __align__(16) half_t Vt[2][64 * 72];

    const int tid = threadIdx.x;
    const int l   = tid & 63;
    const int w   = tid >> 6;
    const int lr  = l & 15;
    const int lg  = l >> 4;

    // XCD-aware swizzle: 1024 blocks, 8 XCDs, bijective
    const int phys = blockIdx.x;
    const int virt = (phys & 7) * 128 + (phys >> 3);
    const int qb = virt & 15;
    const int h  = (virt >> 4) & 15;
    const int b  = virt >> 8;

    const int q0 = qb * 128 + w * 32;
    const size_t hoff = (size_t)(b * SS) * DD + h * HDIM;

    // Q fragments: 2 q-sets x 2 k-halves (d = hb*32 + 8*lg .. +7)
    half8v qf[2][2];
    #pragma unroll
    for (int s = 0; s < 2; ++s) {
        const half_t* qp = Q + hoff + (size_t)(q0 + s * 16 + lr) * DD;
        #pragma unroll
        for (int hb = 0; hb < 2; ++hb)
            qf[s][hb] = *reinterpret_cast<const half8v*>(qp + hb * 32 + 8 * lg);
    }

    // staging indices
    const int kr = tid >> 2, kc = (tid & 3) * 16;       // K: row, 16-col chunk
    const int vk2 = tid & 31, vdq = tid >> 5;           // V: key pair, d-block of 8

    float m[2]    = {-1e30f, -1e30f};
    float lsum[2] = {0.f, 0.f};
    f32x4 xacc[2][4] = {};

    // prologue: stage tile 0
    int4 kra, krb; half4v va0, va1, vb0, vb1;
    {
        const half_t* ksrc = K + hoff + (size_t)kr * DD + kc;
        kra = *reinterpret_cast<const int4*>(ksrc);
        krb = *reinterpret_cast<const int4*>(ksrc + 8);
        const half_t* vsrc = V + hoff + (size_t)(2 * vk2) * DD + vdq * 8;
        va0 = *reinterpret_cast<const half4v*>(vsrc);
        va1 = *reinterpret_cast<const half4v*>(vsrc + 4);
        vb0 = *reinterpret_cast<const half4v*>(vsrc + DD);
        vb1 = *reinterpret_cast<const half4v*>(vsrc + DD + 4);
        *reinterpret_cast<int4*>(&Ks[0][kr * 72 + kc])     = kra;
        *reinterpret_cast<int4*>(&Ks[0][kr * 72 + kc + 8]) = krb;
        #pragma unroll
        for (int i = 0; i < 4; ++i) {
            half2v p0 = {va0[i], vb0[i]};
            half2v p1 = {va1[i], vb1[i]};
            *reinterpret_cast<half2v*>(&Vt[0][(vdq * 8 + i) * 72 + 2 * vk2])     = p0;
            *reinterpret_cast<half2v*>(&Vt[0][(vdq * 8 + i + 4) * 72 + 2 * vk2]) = p1;
        }
    }
    __syncthreads();

    for (int t = 0; t < SS / 64; ++t) {
        const int cur = t & 1;
        if (t < SS / 64 - 1) {   // issue next-tile loads early (T14)
            const half_t* ksrc = K + hoff + (size_t)((t + 1) * 64 + kr) * DD + kc;
            kra = *reinterpret_cast<const int4*>(ksrc);
            krb = *reinterpret_cast<const int4*>(ksrc + 8);
            const half_t* vsrc = V + hoff + (size_t)((t + 1) * 64 + 2 * vk2) * DD + vdq * 8;
            va0 = *reinterpret_cast<const half4v*>(vsrc);
            va1 = *reinterpret_cast<const half4v*>(vsrc + 4);
            vb0 = *reinterpret_cast<const half4v*>(vsrc + DD);
            vb1 = *reinterpret_cast<const half4v*>(vsrc + DD + 4);
        }

        // K fragments (shared across both q-sets)
        half8v kf[4][2];
        #pragma unroll
        for (int kb = 0; kb < 4; ++kb)
            #pragma unroll
            for (int hb = 0; hb < 2; ++hb)
                kf[kb][hb] = *reinterpret_cast<const half8v*>(
                    &Ks[cur][(kb * 16 + lr) * 72 + hb * 32 + 8 * lg]);

        half4v af[2][4];
        #pragma unroll
        for (int s = 0; s < 2; ++s) {
            f32x4 c[4] = {};
            __builtin_amdgcn_s_setprio(1);
            #pragma unroll
            for (int kb = 0; kb < 4; ++kb)
                #pragma unroll
                for (int hb = 0; hb < 2; ++hb)
                    c[kb] = __builtin_amdgcn_mfma_f32_16x16x32_f16(kf[kb][hb], qf[s][hb], c[kb], 0, 0, 0);
            __builtin_amdgcn_s_setprio(0);

            // raw max (f16 RTE is monotone -> f16 of max == max of f16)
            float rmax = c[0][0];
            #pragma unroll
            for (int kb = 0; kb < 4; ++kb)
                #pragma unroll
                for (int j = 0; j < 4; ++j)
                    rmax = fmaxf(rmax, c[kb][j]);
            rmax = fmaxf(rmax, __shfl_xor(rmax, 16, 64));
            rmax = fmaxf(rmax, __shfl_xor(rmax, 32, 64));
            const float tmax = (float)(half_t)(0.125f * rmax);

            if (__any(tmax > m[s] + 8.0f)) {   // defer-max fold
                const float mn = fmaxf(m[s], tmax);
                const float sc = __expf(m[s] - mn);
                lsum[s] *= sc;
                #pragma unroll
                for (int db = 0; db < 4; ++db)
                    #pragma unroll
                    for (int j = 0; j < 4; ++j)
                        xacc[s][db][j] *= sc;
                m[s] = mn;
            }

            float ps = 0.f;
            #pragma unroll
            for (int kb = 0; kb < 4; ++kb)
                #pragma unroll
                for (int j = 0; j < 4; ++j) {
                    const half_t e16 = (half_t)(0.125f * c[kb][j]);  // f16 score (ref semantics)
                    const float p = __expf((float)e16 - m[s]);
                    ps += p;
                    af[s][kb][j] = (half_t)p;                        // p16
                }
            ps += __shfl_xor(ps, 16, 64);
            ps += __shfl_xor(ps, 32, 64);
            lsum[s] += ps;
        }

        // PV: x^T += Vt-frag * p16   (Vt frags shared across q-sets)
        __builtin_amdgcn_s_setprio(1);
        #pragma unroll
        for (int db = 0; db < 4; ++db)
            #pragma unroll
            for (int kb = 0; kb < 4; ++kb) {
                half4v vf = *reinterpret_cast<const half4v*>(
                    &Vt[cur][(db * 16 + lr) * 72 + kb * 16 + 4 * lg]);
                xacc[0][db] = __builtin_amdgcn_mfma_f32_16x16x16f16(vf, af[0][kb], xacc[0][db], 0, 0, 0);
                xacc[1][db] = __builtin_amdgcn_mfma_f32_16x16x16f16(vf, af[1][kb], xacc[1][db], 0, 0, 0);
            }
        __builtin_amdgcn_s_setprio(0);

        if (t < SS / 64 - 1) {   // write next tile into other buffer
            const int nxt = cur ^ 1;
            *reinterpret_cast<int4*>(&Ks[nxt][kr * 72 + kc])     = kra;
            *reinterpret_cast<int4*>(&Ks[nxt][kr * 72 + kc + 8]) = krb;
            #pragma unroll
            for (int i = 0; i < 4; ++i) {
                half2v p0 = {va0[i], vb0[i]};
                half2v p1 = {va1[i], vb1[i]};
                *reinterpret_cast<half2v*>(&Vt[nxt][(vdq * 8 + i) * 72 + 2 * vk2])     = p0;
                *reinterpret_cast<half2v*>(&Vt[nxt][(vdq * 8 + i + 4) * 72 + 2 * vk2]) = p1;
            }
        }
        __syncthreads();
    }

    // epilogue: normalize in f32, round to f16, store
    #pragma unroll
    for (int s = 0; s < 2; ++s) {
        const float invl = 1.0f / lsum[s];
        half_t* xp = X + hoff + (size_t)(q0 + s * 16 + lr) * DD;
        #pragma unroll
        for (int db = 0; db < 4; ++db) {
            half4v o;
            #pragma unroll
            for (int j = 0; j < 4; ++j) o[j] = (half_t)(xacc[s][db][j] * invl);
            *reinterpret_cast<half4v*>(xp + db * 16 + 4 * lg) = o;
        }
    }
}

extern "C" void kernel_launch(void* const* d_in, const int* in_sizes, int n_in,
                              void* d_out, int out_size, void* d_ws, size_t ws_size,
                              hipStream_t stream) {
    const float* q   = (const float*)d_in[0];
    const float* k   = (const float*)d_in[1];
    const float* v   = (const float*)d_in[2];
    const float* Wq  = (const float*)d_in[3];
    const float* bq  = (const float*)d_in[4];
    const float* Wk  = (const float*)d_in[5];
    const float* bk  = (const float*)d_in[6];
    const float* Wv  = (const float*)d_in[7];
    const float* bv  = (const float*)d_in[8];
    const float* Wo  = (const float*)d_in[9];
    const float* bo  = (const float*)d_in[10];
    float* out = (float*)d_out;

    const size_t MB = 1ull << 20;
    const size_t ACT = (size_t)MTOT * DD;
    const size_t WEL = (size_t)DD * DD;

    half_t* q16 = (half_t*)d_ws;
    half_t* k16 = q16 + ACT;
    half_t* v16 = k16 + ACT;
    half_t* x16 = v16 + ACT;

    dim3 gblk(256);
    dim3 ggrd(DD / 128, MTOT / 128);
    dim3 ablk(256);
    dim3 agrd(1024);   // 16 qb x 16 h x 4 b, XCD-swizzled in-kernel

    const bool full  = ws_size >= 101 * MB;
    const bool wonly = ws_size >= 69 * MB;

    if (full) {
        half_t* ah = x16 + ACT;
        half_t* al = ah + ACT;
        half_t* wh = al + ACT;
        half_t* wl = wh + WEL;
        const int nact4 = (int)(ACT / 4), nw4 = (int)(WEL / 4);
        dim3 sgA((nact4 + 255) / 256), sgW((nw4 + 255) / 256);

        hipLaunchKernelGGL(split_hi_lo, sgA, gblk, 0, stream, q, ah, al, nact4);
        hipLaunchKernelGGL(split_hi_lo, sgW, gblk, 0, stream, Wq, wh, wl, nw4);
        hipLaunchKernelGGL((gemm3s<0, half_t>), ggrd, gblk, 0, stream,
                           ah, al, nullptr, wh, wl, bq, q16, DD, DD);
        hipLaunchKernelGGL(split_hi_lo, sgA, gblk, 0, stream, k, ah, al, nact4);
        hipLaunchKernelGGL(split_hi_lo, sgW, gblk, 0, stream, Wk, wh, wl, nw4);
        hipLaunchKernelGGL((gemm3s<0, half_t>), ggrd, gblk, 0, stream,
                           ah, al, nullptr, wh, wl, bk, k16, DD, DD);
        hipLaunchKernelGGL(split_hi_lo, sgA, gblk, 0, stream, v, ah, al, nact4);
        hipLaunchKernelGGL(split_hi_lo, sgW, gblk, 0, stream, Wv, wh, wl, nw4);
        hipLaunchKernelGGL((gemm3s<0, half_t>), ggrd, gblk, 0, stream,
                           ah, al, nullptr, wh, wl, bv, v16, DD, DD);

        hipLaunchKernelGGL(attn_fused, agrd, ablk, 0, stream, q16, k16, v16, x16);

        hipLaunchKernelGGL(split_hi_lo, sgW, gblk, 0, stream, Wo, wh, wl, nw4);
        hipLaunchKernelGGL((gemm3s<2, float>), ggrd, gblk, 0, stream,
                           x16, nullptr, nullptr, wh, wl, bo, out, DD, DD);
    } else if (wonly) {
        half_t* wh = x16 + ACT;
        half_t* wl = wh + WEL;
        const int nw4 = (int)(WEL / 4);
        dim3 sgW((nw4 + 255) / 256);

        hipLaunchKernelGGL(split_hi_lo, sgW, gblk, 0, stream, Wq, wh, wl, nw4);
        hipLaunchKernelGGL((gemm3s<1, half_t>), ggrd, gblk, 0, stream,
                           nullptr, nullptr, q, wh, wl, bq, q16, DD, DD);
        hipLaunchKernelGGL(split_hi_lo, sgW, gblk, 0, stream, Wk, wh, wl, nw4);
        hipLaunchKernelGGL((gemm3s<1, half_t>), ggrd, gblk, 0, stream,
                           nullptr, nullptr, k, wh, wl, bk, k16, DD, DD);
        hipLaunchKernelGGL(split_hi_lo, sgW, gblk, 0, stream, Wv, wh, wl, nw4);
        hipLaunchKernelGGL((gemm3s<1, half_t>), ggrd, gblk, 0, stream,
                           nullptr, nullptr, v, wh, wl, bv, v16, DD, DD);

        hipLaunchKernelGGL(attn_fused, agrd, ablk, 0, stream, q16, k16, v16, x16);

        hipLaunchKernelGGL(split_hi_lo, sgW, gblk, 0, stream, Wo, wh, wl, nw4);
        hipLaunchKernelGGL((gemm3s<2, float>), ggrd, gblk, 0, stream,
                           x16, nullptr, nullptr, wh, wl, bo, out, DD, DD);
    } else {
        dim3 blk(16, 16);
        dim3 grd(DD / 64, MTOT / 64);
        hipLaunchKernelGGL((gemm_bias<float, half_t>), grd, blk, 0, stream,
                           q, Wq, bq, q16, MTOT, DD, DD);
        hipLaunchKernelGGL((gemm_bias<float, half_t>), grd, blk, 0, stream,
                           k, Wk, bk, k16, MTOT, DD, DD);
        hipLaunchKernelGGL((gemm_bias<float, half_t>), grd, blk, 0, stream,
                           v, Wv, bv, v16, MTOT, DD, DD);
        hipLaunchKernelGGL(attn_fused, agrd, ablk, 0, stream, q16, k16, v16, x16);
        hipLaunchKernelGGL((gemm_bias<half_t, float>), grd, blk, 0, stream,
                           x16, Wo, bo, out, MTOT, DD, DD);
    }
}

// Round 5
// 339.620 us; speedup vs baseline: 12.7647x; 1.2245x over previous
//
#include <hip/hip_runtime.h>
#include <cstdint>

#define BB 4
#define SS 2048
#define DD 1024
#define HH 16
#define HDIM 64
#define MTOT (BB*SS)

using half_t = _Float16;
typedef _Float16 half2v __attribute__((ext_vector_type(2)));
typedef _Float16 half4v __attribute__((ext_vector_type(4)));
typedef _Float16 half8v __attribute__((ext_vector_type(8)));
typedef float f32x4 __attribute__((ext_vector_type(4)));

// async global->LDS, 16B per lane; LDS dest = wave-uniform base + lane*16
__device__ __forceinline__ void glds16(const half_t* g, half_t* l) {
    __builtin_amdgcn_global_load_lds(g, l, 16, 0, 0);
}

// ---------------- fp32 -> (hi,lo) f16 split (fallback path) ----------------
__global__ __launch_bounds__(256) void split_hi_lo(const float* __restrict__ x,
    half_t* __restrict__ hi, half_t* __restrict__ lo, int n4)
{
    const int i = blockIdx.x * blockDim.x + threadIdx.x;
    if (i >= n4) return;
    float4 v = reinterpret_cast<const float4*>(x)[i];
    float vv[4] = {v.x, v.y, v.z, v.w};
    half4v h, l;
    #pragma unroll
    for (int j = 0; j < 4; ++j) {
        half_t hh = (half_t)vv[j];
        h[j] = hh;
        l[j] = (half_t)(vv[j] - (float)hh);
    }
    reinterpret_cast<half4v*>(hi)[i] = h;
    reinterpret_cast<half4v*>(lo)[i] = l;
}

// ---------------- split 4 weight matrices in one launch ----------------
__global__ __launch_bounds__(256) void split_w4(
    const float* __restrict__ w0, const float* __restrict__ w1,
    const float* __restrict__ w2, const float* __restrict__ w3,
    half_t* __restrict__ hi, half_t* __restrict__ lo)
{
    const int z = blockIdx.z;
    const float* src = z == 0 ? w0 : z == 1 ? w1 : z == 2 ? w2 : w3;
    const size_t base4 = (size_t)z * (DD * DD / 4);
    const size_t i = base4 + blockIdx.x * 256 + threadIdx.x;
    float4 v = reinterpret_cast<const float4*>(src)[blockIdx.x * 256 + threadIdx.x];
    float vv[4] = {v.x, v.y, v.z, v.w};
    half4v h, l;
    #pragma unroll
    for (int j = 0; j < 4; ++j) {
        half_t hh = (half_t)vv[j];
        h[j] = hh;
        l[j] = (half_t)(vv[j] - (float)hh);
    }
    reinterpret_cast<half4v*>(hi)[i] = h;
    reinterpret_cast<half4v*>(lo)[i] = l;
}

// ---------------- projection GEMM: C[z] = f16(A[z] @ W[z]^T + b[z]) ----------------
// 128x128 tile, BK=32, 4 waves. A fp32 split in-kernel (reg-prefetched),
// W-hi/lo via global_load_lds into linear [128][32] LDS (conflict-free:
// b128 reads at (row*64 + 16*lg) bytes -> slot class (4*lr+lg)%8, 8 lanes each).
// 3 MFMA products per acc: AhWh + AhWl + AlWh (Markidis split, lo*lo dropped).
__global__ __launch_bounds__(256, 3) void gemm_proj(
    const float* __restrict__ A0, const float* __restrict__ A1,
    const float* __restrict__ A2,
    const half_t* __restrict__ WH, const half_t* __restrict__ WL,
    const float* __restrict__ B0, const float* __restrict__ B1,
    const float* __restrict__ B2,
    half_t* __restrict__ C0, half_t* __restrict__ C1, half_t* __restrict__ C2)
{
    __shared__ __align__(16) half_t AhS[128 * 32];
    __shared__ __align__(16) half_t AlS[128 * 32];
    __shared__ __align__(16) half_t WhS[128 * 32];
    __shared__ __align__(16) half_t WlS[128 * 32];

    const int z = blockIdx.z;
    const float*  A    = z == 0 ? A0 : z == 1 ? A1 : A2;
    const float*  bias = z == 0 ? B0 : z == 1 ? B1 : B2;
    half_t*       C    = z == 0 ? C0 : z == 1 ? C1 : C2;
    const half_t* WHz  = WH + (size_t)z * (DD * DD);
    const half_t* WLz  = WL + (size_t)z * (DD * DD);

    const int tid = threadIdx.x;
    const int l = tid & 63, w = tid >> 6;
    const int lr = l & 15, lg = l >> 4;
    const int wr = w >> 1, wc = w & 1;
    const int m0 = blockIdx.y * 128, n0 = blockIdx.x * 128;

    const int ar = tid >> 1, at = (tid & 1) * 16;   // A staging: row, k-half
    const int wlrow = l >> 2, wlcol = (l & 3) * 8;  // W gload within an issue

    f32x4 acc[4][4] = {};

    // prologue: prefetch A(kk=0)
    float4 av[4];
    {
        const float* ap = A + (size_t)(m0 + ar) * DD + at;
        #pragma unroll
        for (int u = 0; u < 4; ++u) av[u] = *reinterpret_cast<const float4*>(ap + 4 * u);
    }

    for (int kk = 0; kk < DD; kk += 32) {
        __syncthreads();   // previous frag reads done; LDS free
        // split prefetched A -> LDS (RTE casts, same numerics as split_hi_lo)
        {
            half_t hbuf[16], lbuf[16];
            #pragma unroll
            for (int u = 0; u < 4; ++u) {
                float vv[4] = {av[u].x, av[u].y, av[u].z, av[u].w};
                #pragma unroll
                for (int j = 0; j < 4; ++j) {
                    half_t hh = (half_t)vv[j];
                    hbuf[4 * u + j] = hh;
                    lbuf[4 * u + j] = (half_t)(vv[j] - (float)hh);
                }
            }
            *reinterpret_cast<int4*>(&AhS[ar * 32 + at])     = *reinterpret_cast<int4*>(hbuf);
            *reinterpret_cast<int4*>(&AhS[ar * 32 + at + 8]) = *reinterpret_cast<int4*>(hbuf + 8);
            *reinterpret_cast<int4*>(&AlS[ar * 32 + at])     = *reinterpret_cast<int4*>(lbuf);
            *reinterpret_cast<int4*>(&AlS[ar * 32 + at + 8]) = *reinterpret_cast<int4*>(lbuf + 8);
        }
        // W hi/lo: async gload_lds, 2 issues per wave per buffer
        #pragma unroll
        for (int i = 0; i < 2; ++i) {
            const int rr = (w * 2 + i) * 16 + wlrow;
            glds16(WHz + (size_t)(n0 + rr) * DD + kk + wlcol, &WhS[(w * 2 + i) * 512]);
            glds16(WLz + (size_t)(n0 + rr) * DD + kk + wlcol, &WlS[(w * 2 + i) * 512]);
        }
        // prefetch A(next) during this K-step's MFMA phase
        if (kk + 32 < DD) {
            const float* ap = A + (size_t)(m0 + ar) * DD + kk + 32 + at;
            #pragma unroll
            for (int u = 0; u < 4; ++u) av[u] = *reinterpret_cast<const float4*>(ap + 4 * u);
        }
        __syncthreads();   // drains vmcnt (gload) + lgkm (ds_write)

        half8v af[4], alf[4];
        #pragma unroll
        for (int mt = 0; mt < 4; ++mt) {
            af[mt]  = *reinterpret_cast<const half8v*>(&AhS[(wr * 64 + mt * 16 + lr) * 32 + 8 * lg]);
            alf[mt] = *reinterpret_cast<const half8v*>(&AlS[(wr * 64 + mt * 16 + lr) * 32 + 8 * lg]);
        }
        #pragma unroll
        for (int nt = 0; nt < 4; ++nt) {
            half8v wf  = *reinterpret_cast<const half8v*>(&WhS[(wc * 64 + nt * 16 + lr) * 32 + 8 * lg]);
            half8v wlf = *reinterpret_cast<const half8v*>(&WlS[(wc * 64 + nt * 16 + lr) * 32 + 8 * lg]);
            #pragma unroll
            for (int mt = 0; mt < 4; ++mt) {
                acc[mt][nt] = __builtin_amdgcn_mfma_f32_16x16x32_f16(af[mt],  wf,  acc[mt][nt], 0, 0, 0);
                acc[mt][nt] = __builtin_amdgcn_mfma_f32_16x16x32_f16(af[mt],  wlf, acc[mt][nt], 0, 0, 0);
                acc[mt][nt] = __builtin_amdgcn_mfma_f32_16x16x32_f16(alf[mt], wf,  acc[mt][nt], 0, 0, 0);
            }
        }
    }

    #pragma unroll
    for (int nt = 0; nt < 4; ++nt) {
        const int n = n0 + wc * 64 + nt * 16 + lr;
        const float bn = bias[n];
        #pragma unroll
        for (int mt = 0; mt < 4; ++mt) {
            const int mbase = m0 + wr * 64 + mt * 16 + 4 * lg;
            #pragma unroll
            for (int j = 0; j < 4; ++j)
                C[(size_t)(mbase + j) * DD + n] = (half_t)(acc[mt][nt][j] + bn);
        }
    }
}

// ---------------- output GEMM: out = x16 @ Wo^T + bo (A exact f16, 2 products) ----------------
__global__ __launch_bounds__(256, 4) void gemm_out(
    const half_t* __restrict__ Ag,
    const half_t* __restrict__ WHz, const half_t* __restrict__ WLz,
    const float* __restrict__ bias, float* __restrict__ C)
{
    __shared__ __align__(16) half_t AhS[128 * 32];
    __shared__ __align__(16) half_t WhS[128 * 32];
    __shared__ __align__(16) half_t WlS[128 * 32];

    const int tid = threadIdx.x;
    const int l = tid & 63, w = tid >> 6;
    const int lr = l & 15, lg = l >> 4;
    const int wr = w >> 1, wc = w & 1;
    const int m0 = blockIdx.y * 128, n0 = blockIdx.x * 128;
    const int wlrow = l >> 2, wlcol = (l & 3) * 8;

    f32x4 acc[4][4] = {};

    for (int kk = 0; kk < DD; kk += 32) {
        __syncthreads();
        #pragma unroll
        for (int i = 0; i < 2; ++i) {
            const int rr = (w * 2 + i) * 16 + wlrow;
            glds16(Ag  + (size_t)(m0 + rr) * DD + kk + wlcol, &AhS[(w * 2 + i) * 512]);
            glds16(WHz + (size_t)(n0 + rr) * DD + kk + wlcol, &WhS[(w * 2 + i) * 512]);
            glds16(WLz + (size_t)(n0 + rr) * DD + kk + wlcol, &WlS[(w * 2 + i) * 512]);
        }
        __syncthreads();

        half8v af[4];
        #pragma unroll
        for (int mt = 0; mt < 4; ++mt)
            af[mt] = *reinterpret_cast<const half8v*>(&AhS[(wr * 64 + mt * 16 + lr) * 32 + 8 * lg]);
        #pragma unroll
        for (int nt = 0; nt < 4; ++nt) {
            half8v wf  = *reinterpret_cast<const half8v*>(&WhS[(wc * 64 + nt * 16 + lr) * 32 + 8 * lg]);
            half8v wlf = *reinterpret_cast<const half8v*>(&WlS[(wc * 64 + nt * 16 + lr) * 32 + 8 * lg]);
            #pragma unroll
            for (int mt = 0; mt < 4; ++mt) {
                acc[mt][nt] = __builtin_amdgcn_mfma_f32_16x16x32_f16(af[mt], wf,  acc[mt][nt], 0, 0, 0);
                acc[mt][nt] = __builtin_amdgcn_mfma_f32_16x16x32_f16(af[mt], wlf, acc[mt][nt], 0, 0, 0);
            }
        }
    }

    #pragma unroll
    for (int nt = 0; nt < 4; ++nt) {
        const int n = n0 + wc * 64 + nt * 16 + lr;
        const float bn = bias[n];
        #pragma unroll
        for (int mt = 0; mt < 4; ++mt) {
            const int mbase = m0 + wr * 64 + mt * 16 + 4 * lg;
            #pragma unroll
            for (int j = 0; j < 4; ++j)
                C[(size_t)(mbase + j) * DD + n] = acc[mt][nt][j] + bn;
        }
    }
}

// ---------------- old split GEMM (fallback path only) ----------------
template<int MODE, typename TC>
__global__ __launch_bounds__(256) void gemm3s(
    const half_t* __restrict__ Ah, const half_t* __restrict__ Al,
    const float* __restrict__ Af,
    const half_t* __restrict__ Wh, const half_t* __restrict__ Wl,
    const float* __restrict__ bias, TC* __restrict__ C,
    int Kdim, int Ndim)
{
    constexpr int LDT = 72;
    __shared__ __align__(16) half_t As[128 * LDT];
    __shared__ __align__(16) half_t Ws[128 * LDT];
    const int tid = threadIdx.x;
    const int l = tid & 63, w = tid >> 6;
    const int lr = l & 15, lg = l >> 4;
    const int wr = w >> 1, wc = w & 1;
    const int m0 = blockIdx.y * 128, n0 = blockIdx.x * 128;
    const int r = tid >> 1, t = tid & 1;

    f32x4 acc[4][4] = {};

    for (int kk = 0; kk < Kdim; kk += 32) {
        __syncthreads();
        if constexpr (MODE == 1) {
            const float* ap = Af + (size_t)(m0 + r) * Kdim + kk + 16 * t;
            half_t hbuf[16], lbuf[16];
            #pragma unroll
            for (int u = 0; u < 4; ++u) {
                float4 v = *reinterpret_cast<const float4*>(ap + 4 * u);
                float vv[4] = {v.x, v.y, v.z, v.w};
                #pragma unroll
                for (int j = 0; j < 4; ++j) {
                    half_t hh = (half_t)vv[j];
                    hbuf[4 * u + j] = hh;
                    lbuf[4 * u + j] = (half_t)(vv[j] - (float)hh);
                }
            }
            *reinterpret_cast<int4*>(&As[r * LDT + 16 * t])          = *reinterpret_cast<int4*>(hbuf);
            *reinterpret_cast<int4*>(&As[r * LDT + 16 * t + 8])      = *reinterpret_cast<int4*>(hbuf + 8);
            *reinterpret_cast<int4*>(&As[r * LDT + 40 + 16 * t])     = *reinterpret_cast<int4*>(lbuf);
            *reinterpret_cast<int4*>(&As[r * LDT + 40 + 16 * t + 8]) = *reinterpret_cast<int4*>(lbuf + 8);
        } else {
            const half_t* ap = Ah + (size_t)(m0 + r) * Kdim + kk + 16 * t;
            *reinterpret_cast<int4*>(&As[r * LDT + 16 * t])     = *reinterpret_cast<const int4*>(ap);
            *reinterpret_cast<int4*>(&As[r * LDT + 16 * t + 8]) = *reinterpret_cast<const int4*>(ap + 8);
        }
        {
            const half_t* wp = Wh + (size_t)(n0 + r) * Kdim + kk + 16 * t;
            *reinterpret_cast<int4*>(&Ws[r * LDT + 16 * t])     = *reinterpret_cast<const int4*>(wp);
            *reinterpret_cast<int4*>(&Ws[r * LDT + 16 * t + 8]) = *reinterpret_cast<const int4*>(wp + 8);
            const half_t* wlp = Wl + (size_t)(n0 + r) * Kdim + kk + 16 * t;
            *reinterpret_cast<int4*>(&Ws[r * LDT + 40 + 16 * t])     = *reinterpret_cast<const int4*>(wlp);
            *reinterpret_cast<int4*>(&Ws[r * LDT + 40 + 16 * t + 8]) = *reinterpret_cast<const int4*>(wlp + 8);
        }
        __syncthreads();

        half8v af[4], alf[4];
        #pragma unroll
        for (int mt = 0; mt < 4; ++mt) {
            af[mt] = *reinterpret_cast<const half8v*>(&As[(wr * 64 + mt * 16 + lr) * LDT + 8 * lg]);
            if constexpr (MODE != 2)
                alf[mt] = *reinterpret_cast<const half8v*>(&As[(wr * 64 + mt * 16 + lr) * LDT + 40 + 8 * lg]);
        }
        #pragma unroll
        for (int nt = 0; nt < 4; ++nt) {
            half8v wf  = *reinterpret_cast<const half8v*>(&Ws[(wc * 64 + nt * 16 + lr) * LDT + 8 * lg]);
            half8v wlf = *reinterpret_cast<const half8v*>(&Ws[(wc * 64 + nt * 16 + lr) * LDT + 40 + 8 * lg]);
            #pragma unroll
            for (int mt = 0; mt < 4; ++mt) {
                acc[mt][nt] = __builtin_amdgcn_mfma_f32_16x16x32_f16(af[mt], wf, acc[mt][nt], 0, 0, 0);
                acc[mt][nt] = __builtin_amdgcn_mfma_f32_16x16x32_f16(af[mt], wlf, acc[mt][nt], 0, 0, 0);
                if constexpr (MODE != 2)
                    acc[mt][nt] = __builtin_amdgcn_mfma_f32_16x16x32_f16(alf[mt], wf, acc[mt][nt], 0, 0, 0);
            }
        }
    }

    #pragma unroll
    for (int nt = 0; nt < 4; ++nt) {
        const int n = n0 + wc * 64 + nt * 16 + lr;
        const float bn = bias[n];
        #pragma unroll
        for (int mt = 0; mt < 4; ++mt) {
            const int mbase = m0 + wr * 64 + mt * 16 + 4 * lg;
            #pragma unroll
            for (int j = 0; j < 4; ++j) {
                float v = acc[mt][nt][j] + bn;
                if constexpr (sizeof(TC) == 4)
                    C[(size_t)(mbase + j) * Ndim + n] = v;
                else
                    C[(size_t)(mbase + j) * Ndim + n] = (half_t)v;
            }
        }
    }
}

// ---------------- fp32 vector GEMM (ultimate fallback only) ----------------
template<typename TA, typename TC>
__global__ __launch_bounds__(256) void gemm_bias(const TA* __restrict__ A,
    const float* __restrict__ W, const float* __restrict__ bias,
    TC* __restrict__ C, int Mdim, int Ndim, int Kdim)
{
    constexpr int BK = 16;
    __shared__ float As[BK][68];
    __shared__ float Ws[BK][68];
    const int tx = threadIdx.x, ty = threadIdx.y;
    const int tid = ty * 16 + tx;
    const int m0 = blockIdx.y * 64, n0 = blockIdx.x * 64;
    const int lrow = tid >> 2;
    const int lc4  = (tid & 3) * 4;

    float acc[4][4] = {};
    for (int kk = 0; kk < Kdim; kk += BK) {
        {
            const TA* ap = A + (size_t)(m0 + lrow) * Kdim + kk + lc4;
            float a0, a1, a2, a3;
            if constexpr (sizeof(TA) == 4) {
                float4 v = *reinterpret_cast<const float4*>(ap);
                a0 = v.x; a1 = v.y; a2 = v.z; a3 = v.w;
            } else {
                half2v v0 = *reinterpret_cast<const half2v*>(ap);
                half2v v1 = *reinterpret_cast<const half2v*>(ap + 2);
                a0 = (float)v0[0]; a1 = (float)v0[1];
                a2 = (float)v1[0]; a3 = (float)v1[1];
            }
            As[lc4 + 0][lrow] = a0; As[lc4 + 1][lrow] = a1;
            As[lc4 + 2][lrow] = a2; As[lc4 + 3][lrow] = a3;
            const float* wp = W + (size_t)(n0 + lrow) * Kdim + kk + lc4;
            float4 wv = *reinterpret_cast<const float4*>(wp);
            Ws[lc4 + 0][lrow] = wv.x; Ws[lc4 + 1][lrow] = wv.y;
            Ws[lc4 + 2][lrow] = wv.z; Ws[lc4 + 3][lrow] = wv.w;
        }
        __syncthreads();
        #pragma unroll
        for (int k = 0; k < BK; ++k) {
            float4 av = *reinterpret_cast<const float4*>(&As[k][ty * 4]);
            float4 bv = *reinterpret_cast<const float4*>(&Ws[k][tx * 4]);
            float a[4] = {av.x, av.y, av.z, av.w};
            float b[4] = {bv.x, bv.y, bv.z, bv.w};
            #pragma unroll
            for (int i = 0; i < 4; ++i)
                #pragma unroll
                for (int j = 0; j < 4; ++j)
                    acc[i][j] = fmaf(a[i], b[j], acc[i][j]);
        }
        __syncthreads();
    }
    #pragma unroll
    for (int i = 0; i < 4; ++i) {
        const int m = m0 + ty * 4 + i;
        #pragma unroll
        for (int j = 0; j < 4; ++j) {
            const int n = n0 + tx * 4 + j;
            float v = acc[i][j] + bias[n];
            if constexpr (sizeof(TC) == 4)
                C[(size_t)m * Ndim + n] = v;
            else
                C[(size_t)m * Ndim + n] = (half_t)v;
        }
    }
}

// ---------------- single-pass fused attention (unchanged from round 3) ----------------
__global__ __launch_bounds__(256, 4) void attn_fused(const half_t* __restrict__ Q,
    const half_t* __restrict__ K, const half_t* __restrict__ V,
    half_t* __restrict__ X)
{
    __shared__ __align__(16) half_t Ks[2][64 * 72];
    __shared__ __align__(16) half_t Vt[2][64 * 72];

    const int tid = threadIdx.x;
    const int l   = tid & 63;
    const int w   = tid >> 6;
    const int lr  = l & 15;
    const int lg  = l >> 4;

    const int phys = blockIdx.x;
    const int virt = (phys & 7) * 128 + (phys >> 3);
    const int qb = virt & 15;
    const int h  = (virt >> 4) & 15;
    const int b  = virt >> 8;

    const int q0 = qb * 128 + w * 32;
    const size_t hoff = (size_t)(b * SS) * DD + h * HDIM;

    half8v qf[2][2];
    #pragma unroll
    for (int s = 0; s < 2; ++s) {
        const half_t* qp = Q + hoff + (size_t)(q0 + s * 16 + lr) * DD;
        #pragma unroll
        for (int hb = 0; hb < 2; ++hb)
            qf[s][hb] = *reinterpret_cast<const half8v*>(qp + hb * 32 + 8 * lg);
    }

    const int kr = tid >> 2, kc = (tid & 3) * 16;
    const int vk2 = tid & 31, vdq = tid >> 5;

    float m[2]    = {-1e30f, -1e30f};
    float lsum[2] = {0.f, 0.f};
    f32x4 xacc[2][4] = {};

    int4 kra, krb; half4v va0, va1, vb0, vb1;
    {
        const half_t* ksrc = K + hoff + (size_t)kr * DD + kc;
        kra = *reinterpret_cast<const int4*>(ksrc);
        krb = *reinterpret_cast<const int4*>(ksrc + 8);
        const half_t* vsrc = V + hoff + (size_t)(2 * vk2) * DD + vdq * 8;
        va0 = *reinterpret_cast<const half4v*>(vsrc);
        va1 = *reinterpret_cast<const half4v*>(vsrc + 4);
        vb0 = *reinterpret_cast<const half4v*>(vsrc + DD);
        vb1 = *reinterpret_cast<const half4v*>(vsrc + DD + 4);
        *reinterpret_cast<int4*>(&Ks[0][kr * 72 + kc])     = kra;
        *reinterpret_cast<int4*>(&Ks[0][kr * 72 + kc + 8]) = krb;
        #pragma unroll
        for (int i = 0; i < 4; ++i) {
            half2v p0 = {va0[i], vb0[i]};
            half2v p1 = {va1[i], vb1[i]};
            *reinterpret_cast<half2v*>(&Vt[0][(vdq * 8 + i) * 72 + 2 * vk2])     = p0;
            *reinterpret_cast<half2v*>(&Vt[0][(vdq * 8 + i + 4) * 72 + 2 * vk2]) = p1;
        }
    }
    __syncthreads();

    for (int t = 0; t < SS / 64; ++t) {
        const int cur = t & 1;
        if (t < SS / 64 - 1) {
            const half_t* ksrc = K + hoff + (size_t)((t + 1) * 64 + kr) * DD + kc;
            kra = *reinterpret_cast<const int4*>(ksrc);
            krb = *reinterpret_cast<const int4*>(ksrc + 8);
            const half_t* vsrc = V + hoff + (size_t)((t + 1) * 64 + 2 * vk2) * DD + vdq * 8;
            va0 = *reinterpret_cast<const half4v*>(vsrc);
            va1 = *reinterpret_cast<const half4v*>(vsrc + 4);
            vb0 = *reinterpret_cast<const half4v*>(vsrc + DD);
            vb1 = *reinterpret_cast<const half4v*>(vsrc + DD + 4);
        }

        half8v kf[4][2];
        #pragma unroll
        for (int kb = 0; kb < 4; ++kb)
            #pragma unroll
            for (int hb = 0; hb < 2; ++hb)
                kf[kb][hb] = *reinterpret_cast<const half8v*>(
                    &Ks[cur][(kb * 16 + lr) * 72 + hb * 32 + 8 * lg]);

        half4v af[2][4];
        #pragma unroll
        for (int s = 0; s < 2; ++s) {
            f32x4 c[4] = {};
            __builtin_amdgcn_s_setprio(1);
            #pragma unroll
            for (int kb = 0; kb < 4; ++kb)
                #pragma unroll
                for (int hb = 0; hb < 2; ++hb)
                    c[kb] = __builtin_amdgcn_mfma_f32_16x16x32_f16(kf[kb][hb], qf[s][hb], c[kb], 0, 0, 0);
            __builtin_amdgcn_s_setprio(0);

            float rmax = c[0][0];
            #pragma unroll
            for (int kb = 0; kb < 4; ++kb)
                #pragma unroll
                for (int j = 0; j < 4; ++j)
                    rmax = fmaxf(rmax, c[kb][j]);
            rmax = fmaxf(rmax, __shfl_xor(rmax, 16, 64));
            rmax = fmaxf(rmax, __shfl_xor(rmax, 32, 64));
            const float tmax = (float)(half_t)(0.125f * rmax);

            if (__any(tmax > m[s] + 8.0f)) {
                const float mn = fmaxf(m[s], tmax);
                const float sc = __expf(m[s] - mn);
                lsum[s] *= sc;
                #pragma unroll
                for (int db = 0; db < 4; ++db)
                    #pragma unroll
                    for (int j = 0; j < 4; ++j)
                        xacc[s][db][j] *= sc;
                m[s] = mn;
            }

            float ps = 0.f;
            #pragma unroll
            for (int kb = 0; kb < 4; ++kb)
                #pragma unroll
                for (int j = 0; j < 4; ++j) {
                    const half_t e16 = (half_t)(0.125f * c[kb][j]);
                    const float p = __expf((float)e16 - m[s]);
                    ps += p;
                    af[s][kb][j] = (half_t)p;
                }
            ps += __shfl_xor(ps, 16, 64);
            ps += __shfl_xor(ps, 32, 64);
            lsum[s] += ps;
        }

        __builtin_amdgcn_s_setprio(1);
        #pragma unroll
        for (int db = 0; db < 4; ++db)
            #pragma unroll
            for (int kb = 0; kb < 4; ++kb) {
                half4v vf = *reinterpret_cast<const half4v*>(
                    &Vt[cur][(db * 16 + lr) * 72 + kb * 16 + 4 * lg]);
                xacc[0][db] = __builtin_amdgcn_mfma_f32_16x16x16f16(vf, af[0][kb], xacc[0][db], 0, 0, 0);
                xacc[1][db] = __builtin_amdgcn_mfma_f32_16x16x16f16(vf, af[1][kb], xacc[1][db], 0, 0, 0);
            }
        __builtin_amdgcn_s_setprio(0);

        if (t < SS / 64 - 1) {
            const int nxt = cur ^ 1;
            *reinterpret_cast<int4*>(&Ks[nxt][kr * 72 + kc])     = kra;
            *reinterpret_cast<int4*>(&Ks[nxt][kr * 72 + kc + 8]) = krb;
            #pragma unroll
            for (int i = 0; i < 4; ++i) {
                half2v p0 = {va0[i], vb0[i]};
                half2v p1 = {va1[i], vb1[i]};
                *reinterpret_cast<half2v*>(&Vt[nxt][(vdq * 8 + i) * 72 + 2 * vk2])     = p0;
                *reinterpret_cast<half2v*>(&Vt[nxt][(vdq * 8 + i + 4) * 72 + 2 * vk2]) = p1;
            }
        }
        __syncthreads();
    }

    #pragma unroll
    for (int s = 0; s < 2; ++s) {
        const float invl = 1.0f / lsum[s];
        half_t* xp = X + hoff + (size_t)(q0 + s * 16 + lr) * DD;
        #pragma unroll
        for (int db = 0; db < 4; ++db) {
            half4v o;
            #pragma unroll
            for (int j = 0; j < 4; ++j) o[j] = (half_t)(xacc[s][db][j] * invl);
            *reinterpret_cast<half4v*>(xp + db * 16 + 4 * lg) = o;
        }
    }
}

extern "C" void kernel_launch(void* const* d_in, const int* in_sizes, int n_in,
                              void* d_out, int out_size, void* d_ws, size_t ws_size,
                              hipStream_t stream) {
    const float* q   = (const float*)d_in[0];
    const float* k   = (const float*)d_in[1];
    const float* v   = (const float*)d_in[2];
    const float* Wq  = (const float*)d_in[3];
    const float* bq  = (const float*)d_in[4];
    const float* Wk  = (const float*)d_in[5];
    const float* bk  = (const float*)d_in[6];
    const float* Wv  = (const float*)d_in[7];
    const float* bv  = (const float*)d_in[8];
    const float* Wo  = (const float*)d_in[9];
    const float* bo  = (const float*)d_in[10];
    float* out = (float*)d_out;

    const size_t MB = 1ull << 20;
    const size_t ACT = (size_t)MTOT * DD;   // 8.39M elems
    const size_t WEL = (size_t)DD * DD;     // 1.05M elems

    half_t* q16 = (half_t*)d_ws;
    half_t* k16 = q16 + ACT;
    half_t* v16 = k16 + ACT;
    half_t* x16 = v16 + ACT;

    dim3 gblk(256);
    dim3 ablk(256);
    dim3 agrd(1024);

    // new path: q16..x16 (4*ACT*2B) + wh/wl (8*WEL*2B) = exactly 80 MiB
    if (ws_size >= 80 * MB) {
        half_t* wh = x16 + ACT;          // 4 * WEL
        half_t* wl = wh + 4 * WEL;       // 4 * WEL

        dim3 wsgrd(WEL / 4 / 256, 1, 4);
        hipLaunchKernelGGL(split_w4, wsgrd, gblk, 0, stream,
                           Wq, Wk, Wv, Wo, wh, wl);

        dim3 pgrd(DD / 128, MTOT / 128, 3);
        hipLaunchKernelGGL(gemm_proj, pgrd, gblk, 0, stream,
                           q, k, v, wh, wl, bq, bk, bv, q16, k16, v16);

        hipLaunchKernelGGL(attn_fused, agrd, ablk, 0, stream, q16, k16, v16, x16);

        dim3 ogrd(DD / 128, MTOT / 128);
        hipLaunchKernelGGL(gemm_out, ogrd, gblk, 0, stream,
                           x16, wh + 3 * WEL, wl + 3 * WEL, bo, out);
    } else if (ws_size >= 72 * MB) {
        half_t* wh = x16 + ACT;
        half_t* wl = wh + WEL;
        const int nw4 = (int)(WEL / 4);
        dim3 sgW((nw4 + 255) / 256);
        dim3 ggrd(DD / 128, MTOT / 128);

        hipLaunchKernelGGL(split_hi_lo, sgW, gblk, 0, stream, Wq, wh, wl, nw4);
        hipLaunchKernelGGL((gemm3s<1, half_t>), ggrd, gblk, 0, stream,
                           nullptr, nullptr, q, wh, wl, bq, q16, DD, DD);
        hipLaunchKernelGGL(split_hi_lo, sgW, gblk, 0, stream, Wk, wh, wl, nw4);
        hipLaunchKernelGGL((gemm3s<1, half_t>), ggrd, gblk, 0, stream,
                           nullptr, nullptr, k, wh, wl, bk, k16, DD, DD);
        hipLaunchKernelGGL(split_hi_lo, sgW, gblk, 0, stream, Wv, wh, wl, nw4);
        hipLaunchKernelGGL((gemm3s<1, half_t>), ggrd, gblk, 0, stream,
                           nullptr, nullptr, v, wh, wl, bv, v16, DD, DD);

        hipLaunchKernelGGL(attn_fused, agrd, ablk, 0, stream, q16, k16, v16, x16);

        hipLaunchKernelGGL(split_hi_lo, sgW, gblk, 0, stream, Wo, wh, wl, nw4);
        hipLaunchKernelGGL((gemm3s<2, float>), ggrd, gblk, 0, stream,
                           x16, nullptr, nullptr, wh, wl, bo, out, DD, DD);
    } else {
        dim3 blk(16, 16);
        dim3 grd(DD / 64, MTOT / 64);
        hipLaunchKernelGGL((gemm_bias<float, half_t>), grd, blk, 0, stream,
                           q, Wq, bq, q16, MTOT, DD, DD);
        hipLaunchKernelGGL((gemm_bias<float, half_t>), grd, blk, 0, stream,
                           k, Wk, bk, k16, MTOT, DD, DD);
        hipLaunchKernelGGL((gemm_bias<float, half_t>), grd, blk, 0, stream,
                           v, Wv, bv, v16, MTOT, DD, DD);
        hipLaunchKernelGGL(attn_fused, agrd, ablk, 0, stream, q16, k16, v16, x16);
        hipLaunchKernelGGL((gemm_bias<half_t, float>), grd, blk, 0, stream,
                           x16, Wo, bo, out, MTOT, DD, DD);
    }
}

// Round 6
// 289.606 us; speedup vs baseline: 14.9691x; 1.1727x over previous
//
#include <hip/hip_runtime.h>
#include <cstdint>

#define BB 4
#define SS 2048
#define DD 1024
#define HH 16
#define HDIM 64
#define MTOT (BB*SS)

using half_t = _Float16;
typedef _Float16 half2v __attribute__((ext_vector_type(2)));
typedef _Float16 half4v __attribute__((ext_vector_type(4)));
typedef _Float16 half8v __attribute__((ext_vector_type(8)));
typedef float f32x4 __attribute__((ext_vector_type(4)));

// async global->LDS, 16B per lane; LDS dest = wave-uniform base + lane*16
__device__ __forceinline__ void glds16(const half_t* g, half_t* l) {
    __builtin_amdgcn_global_load_lds(g, l, 16, 0, 0);
}

// ---------------- fp32 -> (hi,lo) f16 split (fallback path) ----------------
__global__ __launch_bounds__(256) void split_hi_lo(const float* __restrict__ x,
    half_t* __restrict__ hi, half_t* __restrict__ lo, int n4)
{
    const int i = blockIdx.x * blockDim.x + threadIdx.x;
    if (i >= n4) return;
    float4 v = reinterpret_cast<const float4*>(x)[i];
    float vv[4] = {v.x, v.y, v.z, v.w};
    half4v h, l;
    #pragma unroll
    for (int j = 0; j < 4; ++j) {
        half_t hh = (half_t)vv[j];
        h[j] = hh;
        l[j] = (half_t)(vv[j] - (float)hh);
    }
    reinterpret_cast<half4v*>(hi)[i] = h;
    reinterpret_cast<half4v*>(lo)[i] = l;
}

// ---------------- split 4 weight matrices in one launch ----------------
__global__ __launch_bounds__(256) void split_w4(
    const float* __restrict__ w0, const float* __restrict__ w1,
    const float* __restrict__ w2, const float* __restrict__ w3,
    half_t* __restrict__ hi, half_t* __restrict__ lo)
{
    const int z = blockIdx.z;
    const float* src = z == 0 ? w0 : z == 1 ? w1 : z == 2 ? w2 : w3;
    const size_t base4 = (size_t)z * (DD * DD / 4);
    const size_t i = base4 + blockIdx.x * 256 + threadIdx.x;
    float4 v = reinterpret_cast<const float4*>(src)[blockIdx.x * 256 + threadIdx.x];
    float vv[4] = {v.x, v.y, v.z, v.w};
    half4v h, l;
    #pragma unroll
    for (int j = 0; j < 4; ++j) {
        half_t hh = (half_t)vv[j];
        h[j] = hh;
        l[j] = (half_t)(vv[j] - (float)hh);
    }
    reinterpret_cast<half4v*>(hi)[i] = h;
    reinterpret_cast<half4v*>(lo)[i] = l;
}

// ---------------- projection GEMM: C[z] = f16(A[z] @ W[z]^T + b[z]) ----------------
// 128x128 tile, BK=32, 4 waves. 2 MFMA products: Ah*Wh + Ah*Wl (Al*Wh dropped;
// added error sigma ~2.4e-4 << 4.3e-3 budget). A fp32 hi-cast in-kernel
// (reg-prefetched). W-hi/lo via global_load_lds into linear [128][32] LDS.
// Grid (m=64, n=8, z=3): linear_id%8 == m%8 -> all n-blocks of one A panel
// land on the same XCD (A fetched ~once from HBM).
__global__ __launch_bounds__(256, 4) void gemm_proj(
    const float* __restrict__ A0, const float* __restrict__ A1,
    const float* __restrict__ A2,
    const half_t* __restrict__ WH, const half_t* __restrict__ WL,
    const float* __restrict__ B0, const float* __restrict__ B1,
    const float* __restrict__ B2,
    half_t* __restrict__ C0, half_t* __restrict__ C1, half_t* __restrict__ C2)
{
    __shared__ __align__(16) half_t AhS[128 * 32];
    __shared__ __align__(16) half_t WhS[128 * 32];
    __shared__ __align__(16) half_t WlS[128 * 32];

    const int z = blockIdx.z;
    const float*  A    = z == 0 ? A0 : z == 1 ? A1 : A2;
    const float*  bias = z == 0 ? B0 : z == 1 ? B1 : B2;
    half_t*       C    = z == 0 ? C0 : z == 1 ? C1 : C2;
    const half_t* WHz  = WH + (size_t)z * (DD * DD);
    const half_t* WLz  = WL + (size_t)z * (DD * DD);

    const int tid = threadIdx.x;
    const int l = tid & 63, w = tid >> 6;
    const int lr = l & 15, lg = l >> 4;
    const int wr = w >> 1, wc = w & 1;
    const int m0 = blockIdx.x * 128, n0 = blockIdx.y * 128;

    const int arow = tid >> 2;          // 0..63 (rows j*64+arow)
    const int acol = (tid & 3) * 8;     // 0,8,16,24
    const int wlrow = l >> 2, wlcol = (l & 3) * 8;

    f32x4 acc[4][4] = {};

    // prologue: prefetch A(kk=0) into registers
    float4 av[2][2];
    #pragma unroll
    for (int j = 0; j < 2; ++j) {
        const float* ap = A + (size_t)(m0 + j * 64 + arow) * DD + acol;
        av[j][0] = *reinterpret_cast<const float4*>(ap);
        av[j][1] = *reinterpret_cast<const float4*>(ap + 4);
    }

    for (int kk = 0; kk < DD; kk += 32) {
        __syncthreads();   // previous frag reads done; LDS free
        // hi-cast prefetched A -> LDS (even slot spread: slot%8 == tid%8)
        #pragma unroll
        for (int j = 0; j < 2; ++j) {
            half_t hb[8];
            float v0[4] = {av[j][0].x, av[j][0].y, av[j][0].z, av[j][0].w};
            float v1[4] = {av[j][1].x, av[j][1].y, av[j][1].z, av[j][1].w};
            #pragma unroll
            for (int e = 0; e < 4; ++e) { hb[e] = (half_t)v0[e]; hb[4 + e] = (half_t)v1[e]; }
            *reinterpret_cast<int4*>(&AhS[(j * 64 + arow) * 32 + acol]) = *reinterpret_cast<int4*>(hb);
        }
        // W hi/lo: async gload_lds, 2 issues per wave per buffer
        #pragma unroll
        for (int i = 0; i < 2; ++i) {
            const int rr = (w * 2 + i) * 16 + wlrow;
            glds16(WHz + (size_t)(n0 + rr) * DD + kk + wlcol, &WhS[(w * 2 + i) * 512]);
            glds16(WLz + (size_t)(n0 + rr) * DD + kk + wlcol, &WlS[(w * 2 + i) * 512]);
        }
        // prefetch A(next)
        if (kk + 32 < DD) {
            #pragma unroll
            for (int j = 0; j < 2; ++j) {
                const float* ap = A + (size_t)(m0 + j * 64 + arow) * DD + kk + 32 + acol;
                av[j][0] = *reinterpret_cast<const float4*>(ap);
                av[j][1] = *reinterpret_cast<const float4*>(ap + 4);
            }
        }
        __syncthreads();   // drains vmcnt (gload) + lgkm (ds_write)

        half8v af[4];
        #pragma unroll
        for (int mt = 0; mt < 4; ++mt)
            af[mt] = *reinterpret_cast<const half8v*>(&AhS[(wr * 64 + mt * 16 + lr) * 32 + 8 * lg]);
        #pragma unroll
        for (int nt = 0; nt < 4; ++nt) {
            half8v wf  = *reinterpret_cast<const half8v*>(&WhS[(wc * 64 + nt * 16 + lr) * 32 + 8 * lg]);
            half8v wlf = *reinterpret_cast<const half8v*>(&WlS[(wc * 64 + nt * 16 + lr) * 32 + 8 * lg]);
            #pragma unroll
            for (int mt = 0; mt < 4; ++mt) {
                acc[mt][nt] = __builtin_amdgcn_mfma_f32_16x16x32_f16(af[mt], wf,  acc[mt][nt], 0, 0, 0);
                acc[mt][nt] = __builtin_amdgcn_mfma_f32_16x16x32_f16(af[mt], wlf, acc[mt][nt], 0, 0, 0);
            }
        }
    }

    #pragma unroll
    for (int nt = 0; nt < 4; ++nt) {
        const int n = n0 + wc * 64 + nt * 16 + lr;
        const float bn = bias[n];
        #pragma unroll
        for (int mt = 0; mt < 4; ++mt) {
            const int mbase = m0 + wr * 64 + mt * 16 + 4 * lg;
            #pragma unroll
            for (int j = 0; j < 4; ++j)
                C[(size_t)(mbase + j) * DD + n] = (half_t)(acc[mt][nt][j] + bn);
        }
    }
}

// ---------------- output GEMM: out = x16 @ Wo^T + bo (A exact f16, 2 products) ----------------
// Grid (m=64, n=8), same XCD A-locality as gemm_proj.
__global__ __launch_bounds__(256, 4) void gemm_out(
    const half_t* __restrict__ Ag,
    const half_t* __restrict__ WHz, const half_t* __restrict__ WLz,
    const float* __restrict__ bias, float* __restrict__ C)
{
    __shared__ __align__(16) half_t AhS[128 * 32];
    __shared__ __align__(16) half_t WhS[128 * 32];
    __shared__ __align__(16) half_t WlS[128 * 32];

    const int tid = threadIdx.x;
    const int l = tid & 63, w = tid >> 6;
    const int lr = l & 15, lg = l >> 4;
    const int wr = w >> 1, wc = w & 1;
    const int m0 = blockIdx.x * 128, n0 = blockIdx.y * 128;
    const int wlrow = l >> 2, wlcol = (l & 3) * 8;

    f32x4 acc[4][4] = {};

    for (int kk = 0; kk < DD; kk += 32) {
        __syncthreads();
        #pragma unroll
        for (int i = 0; i < 2; ++i) {
            const int rr = (w * 2 + i) * 16 + wlrow;
            glds16(Ag  + (size_t)(m0 + rr) * DD + kk + wlcol, &AhS[(w * 2 + i) * 512]);
            glds16(WHz + (size_t)(n0 + rr) * DD + kk + wlcol, &WhS[(w * 2 + i) * 512]);
            glds16(WLz + (size_t)(n0 + rr) * DD + kk + wlcol, &WlS[(w * 2 + i) * 512]);
        }
        __syncthreads();

        half8v af[4];
        #pragma unroll
        for (int mt = 0; mt < 4; ++mt)
            af[mt] = *reinterpret_cast<const half8v*>(&AhS[(wr * 64 + mt * 16 + lr) * 32 + 8 * lg]);
        #pragma unroll
        for (int nt = 0; nt < 4; ++nt) {
            half8v wf  = *reinterpret_cast<const half8v*>(&WhS[(wc * 64 + nt * 16 + lr) * 32 + 8 * lg]);
            half8v wlf = *reinterpret_cast<const half8v*>(&WlS[(wc * 64 + nt * 16 + lr) * 32 + 8 * lg]);
            #pragma unroll
            for (int mt = 0; mt < 4; ++mt) {
                acc[mt][nt] = __builtin_amdgcn_mfma_f32_16x16x32_f16(af[mt], wf,  acc[mt][nt], 0, 0, 0);
                acc[mt][nt] = __builtin_amdgcn_mfma_f32_16x16x32_f16(af[mt], wlf, acc[mt][nt], 0, 0, 0);
            }
        }
    }

    #pragma unroll
    for (int nt = 0; nt < 4; ++nt) {
        const int n = n0 + wc * 64 + nt * 16 + lr;
        const float bn = bias[n];
        #pragma unroll
        for (int mt = 0; mt < 4; ++mt) {
            const int mbase = m0 + wr * 64 + mt * 16 + 4 * lg;
            #pragma unroll
            for (int j = 0; j < 4; ++j)
                C[(size_t)(mbase + j) * DD + n] = acc[mt][nt][j] + bn;
        }
    }
}

// ---------------- old split GEMM (fallback path only) ----------------
template<int MODE, typename TC>
__global__ __launch_bounds__(256) void gemm3s(
    const half_t* __restrict__ Ah, const half_t* __restrict__ Al,
    const float* __restrict__ Af,
    const half_t* __restrict__ Wh, const half_t* __restrict__ Wl,
    const float* __restrict__ bias, TC* __restrict__ C,
    int Kdim, int Ndim)
{
    constexpr int LDT = 72;
    __shared__ __align__(16) half_t As[128 * LDT];
    __shared__ __align__(16) half_t Ws[128 * LDT];
    const int tid = threadIdx.x;
    const int l = tid & 63, w = tid >> 6;
    const int lr = l & 15, lg = l >> 4;
    const int wr = w >> 1, wc = w & 1;
    const int m0 = blockIdx.y * 128, n0 = blockIdx.x * 128;
    const int r = tid >> 1, t = tid & 1;

    f32x4 acc[4][4] = {};

    for (int kk = 0; kk < Kdim; kk += 32) {
        __syncthreads();
        if constexpr (MODE == 1) {
            const float* ap = Af + (size_t)(m0 + r) * Kdim + kk + 16 * t;
            half_t hbuf[16], lbuf[16];
            #pragma unroll
            for (int u = 0; u < 4; ++u) {
                float4 v = *reinterpret_cast<const float4*>(ap + 4 * u);
                float vv[4] = {v.x, v.y, v.z, v.w};
                #pragma unroll
                for (int j = 0; j < 4; ++j) {
                    half_t hh = (half_t)vv[j];
                    hbuf[4 * u + j] = hh;
                    lbuf[4 * u + j] = (half_t)(vv[j] - (float)hh);
                }
            }
            *reinterpret_cast<int4*>(&As[r * LDT + 16 * t])          = *reinterpret_cast<int4*>(hbuf);
            *reinterpret_cast<int4*>(&As[r * LDT + 16 * t + 8])      = *reinterpret_cast<int4*>(hbuf + 8);
            *reinterpret_cast<int4*>(&As[r * LDT + 40 + 16 * t])     = *reinterpret_cast<int4*>(lbuf);
            *reinterpret_cast<int4*>(&As[r * LDT + 40 + 16 * t + 8]) = *reinterpret_cast<int4*>(lbuf + 8);
        } else {
            const half_t* ap = Ah + (size_t)(m0 + r) * Kdim + kk + 16 * t;
            *reinterpret_cast<int4*>(&As[r * LDT + 16 * t])     = *reinterpret_cast<const int4*>(ap);
            *reinterpret_cast<int4*>(&As[r * LDT + 16 * t + 8]) = *reinterpret_cast<const int4*>(ap + 8);
        }
        {
            const half_t* wp = Wh + (size_t)(n0 + r) * Kdim + kk + 16 * t;
            *reinterpret_cast<int4*>(&Ws[r * LDT + 16 * t])     = *reinterpret_cast<const int4*>(wp);
            *reinterpret_cast<int4*>(&Ws[r * LDT + 16 * t + 8]) = *reinterpret_cast<const int4*>(wp + 8);
            const half_t* wlp = Wl + (size_t)(n0 + r) * Kdim + kk + 16 * t;
            *reinterpret_cast<int4*>(&Ws[r * LDT + 40 + 16 * t])     = *reinterpret_cast<const int4*>(wlp);
            *reinterpret_cast<int4*>(&Ws[r * LDT + 40 + 16 * t + 8]) = *reinterpret_cast<const int4*>(wlp + 8);
        }
        __syncthreads();

        half8v af[4], alf[4];
        #pragma unroll
        for (int mt = 0; mt < 4; ++mt) {
            af[mt] = *reinterpret_cast<const half8v*>(&As[(wr * 64 + mt * 16 + lr) * LDT + 8 * lg]);
            if constexpr (MODE != 2)
                alf[mt] = *reinterpret_cast<const half8v*>(&As[(wr * 64 + mt * 16 + lr) * LDT + 40 + 8 * lg]);
        }
        #pragma unroll
        for (int nt = 0; nt < 4; ++nt) {
            half8v wf  = *reinterpret_cast<const half8v*>(&Ws[(wc * 64 + nt * 16 + lr) * LDT + 8 * lg]);
            half8v wlf = *reinterpret_cast<const half8v*>(&Ws[(wc * 64 + nt * 16 + lr) * LDT + 40 + 8 * lg]);
            #pragma unroll
            for (int mt = 0; mt < 4; ++mt) {
                acc[mt][nt] = __builtin_amdgcn_mfma_f32_16x16x32_f16(af[mt], wf, acc[mt][nt], 0, 0, 0);
                acc[mt][nt] = __builtin_amdgcn_mfma_f32_16x16x32_f16(af[mt], wlf, acc[mt][nt], 0, 0, 0);
                if constexpr (MODE != 2)
                    acc[mt][nt] = __builtin_amdgcn_mfma_f32_16x16x32_f16(alf[mt], wf, acc[mt][nt], 0, 0, 0);
            }
        }
    }

    #pragma unroll
    for (int nt = 0; nt < 4; ++nt) {
        const int n = n0 + wc * 64 + nt * 16 + lr;
        const float bn = bias[n];
        #pragma unroll
        for (int mt = 0; mt < 4; ++mt) {
            const int mbase = m0 + wr * 64 + mt * 16 + 4 * lg;
            #pragma unroll
            for (int j = 0; j < 4; ++j) {
                float v = acc[mt][nt][j] + bn;
                if constexpr (sizeof(TC) == 4)
                    C[(size_t)(mbase + j) * Ndim + n] = v;
                else
                    C[(size_t)(mbase + j) * Ndim + n] = (half_t)v;
            }
        }
    }
}

// ---------------- fp32 vector GEMM (ultimate fallback only) ----------------
template<typename TA, typename TC>
__global__ __launch_bounds__(256) void gemm_bias(const TA* __restrict__ A,
    const float* __restrict__ W, const float* __restrict__ bias,
    TC* __restrict__ C, int Mdim, int Ndim, int Kdim)
{
    constexpr int BK = 16;
    __shared__ float As[BK][68];
    __shared__ float Ws[BK][68];
    const int tx = threadIdx.x, ty = threadIdx.y;
    const int tid = ty * 16 + tx;
    const int m0 = blockIdx.y * 64, n0 = blockIdx.x * 64;
    const int lrow = tid >> 2;
    const int lc4  = (tid & 3) * 4;

    float acc[4][4] = {};
    for (int kk = 0; kk < Kdim; kk += BK) {
        {
            const TA* ap = A + (size_t)(m0 + lrow) * Kdim + kk + lc4;
            float a0, a1, a2, a3;
            if constexpr (sizeof(TA) == 4) {
                float4 v = *reinterpret_cast<const float4*>(ap);
                a0 = v.x; a1 = v.y; a2 = v.z; a3 = v.w;
            } else {
                half2v v0 = *reinterpret_cast<const half2v*>(ap);
                half2v v1 = *reinterpret_cast<const half2v*>(ap + 2);
                a0 = (float)v0[0]; a1 = (float)v0[1];
                a2 = (float)v1[0]; a3 = (float)v1[1];
            }
            As[lc4 + 0][lrow] = a0; As[lc4 + 1][lrow] = a1;
            As[lc4 + 2][lrow] = a2; As[lc4 + 3][lrow] = a3;
            const float* wp = W + (size_t)(n0 + lrow) * Kdim + kk + lc4;
            float4 wv = *reinterpret_cast<const float4*>(wp);
            Ws[lc4 + 0][lrow] = wv.x; Ws[lc4 + 1][lrow] = wv.y;
            Ws[lc4 + 2][lrow] = wv.z; Ws[lc4 + 3][lrow] = wv.w;
        }
        __syncthreads();
        #pragma unroll
        for (int k = 0; k < BK; ++k) {
            float4 av = *reinterpret_cast<const float4*>(&As[k][ty * 4]);
            float4 bv = *reinterpret_cast<const float4*>(&Ws[k][tx * 4]);
            float a[4] = {av.x, av.y, av.z, av.w};
            float b[4] = {bv.x, bv.y, bv.z, bv.w};
            #pragma unroll
            for (int i = 0; i < 4; ++i)
                #pragma unroll
                for (int j = 0; j < 4; ++j)
                    acc[i][j] = fmaf(a[i], b[j], acc[i][j]);
        }
        __syncthreads();
    }
    #pragma unroll
    for (int i = 0; i < 4; ++i) {
        const int m = m0 + ty * 4 + i;
        #pragma unroll
        for (int j = 0; j < 4; ++j) {
            const int n = n0 + tx * 4 + j;
            float v = acc[i][j] + bias[n];
            if constexpr (sizeof(TC) == 4)
                C[(size_t)m * Ndim + n] = v;
            else
                C[(size_t)m * Ndim + n] = (half_t)v;
        }
    }
}

// ---------------- single-pass fused attention (unchanged) ----------------
__global__ __launch_bounds__(256, 4) void attn_fused(const half_t* __restrict__ Q,
    const half_t* __restrict__ K, const half_t* __restrict__ V,
    half_t* __restrict__ X)
{
    __shared__ __align__(16) half_t Ks[2][64 * 72];
    __shared__ __align__(16) half_t Vt[2][64 * 72];

    const int tid = threadIdx.x;
    const int l   = tid & 63;
    const int w   = tid >> 6;
    const int lr  = l & 15;
    const int lg  = l >> 4;

    const int phys = blockIdx.x;
    const int virt = (phys & 7) * 128 + (phys >> 3);
    const int qb = virt & 15;
    const int h  = (virt >> 4) & 15;
    const int b  = virt >> 8;

    const int q0 = qb * 128 + w * 32;
    const size_t hoff = (size_t)(b * SS) * DD + h * HDIM;

    half8v qf[2][2];
    #pragma unroll
    for (int s = 0; s < 2; ++s) {
        const half_t* qp = Q + hoff + (size_t)(q0 + s * 16 + lr) * DD;
        #pragma unroll
        for (int hb = 0; hb < 2; ++hb)
            qf[s][hb] = *reinterpret_cast<const half8v*>(qp + hb * 32 + 8 * lg);
    }

    const int kr = tid >> 2, kc = (tid & 3) * 16;
    const int vk2 = tid & 31, vdq = tid >> 5;

    float m[2]    = {-1e30f, -1e30f};
    float lsum[2] = {0.f, 0.f};
    f32x4 xacc[2][4] = {};

    int4 kra, krb; half4v va0, va1, vb0, vb1;
    {
        const half_t* ksrc = K + hoff + (size_t)kr * DD + kc;
        kra = *reinterpret_cast<const int4*>(ksrc);
        krb = *reinterpret_cast<const int4*>(ksrc + 8);
        const half_t* vsrc = V + hoff + (size_t)(2 * vk2) * DD + vdq * 8;
        va0 = *reinterpret_cast<const half4v*>(vsrc);
        va1 = *reinterpret_cast<const half4v*>(vsrc + 4);
        vb0 = *reinterpret_cast<const half4v*>(vsrc + DD);
        vb1 = *reinterpret_cast<const half4v*>(vsrc + DD + 4);
        *reinterpret_cast<int4*>(&Ks[0][kr * 72 + kc])     = kra;
        *reinterpret_cast<int4*>(&Ks[0][kr * 72 + kc + 8]) = krb;
        #pragma unroll
        for (int i = 0; i < 4; ++i) {
            half2v p0 = {va0[i], vb0[i]};
            half2v p1 = {va1[i], vb1[i]};
            *reinterpret_cast<half2v*>(&Vt[0][(vdq * 8 + i) * 72 + 2 * vk2])     = p0;
            *reinterpret_cast<half2v*>(&Vt[0][(vdq * 8 + i + 4) * 72 + 2 * vk2]) = p1;
        }
    }
    __syncthreads();

    for (int t = 0; t < SS / 64; ++t) {
        const int cur = t & 1;
        if (t < SS / 64 - 1) {
            const half_t* ksrc = K + hoff + (size_t)((t + 1) * 64 + kr) * DD + kc;
            kra = *reinterpret_cast<const int4*>(ksrc);
            krb = *reinterpret_cast<const int4*>(ksrc + 8);
            const half_t* vsrc = V + hoff + (size_t)((t + 1) * 64 + 2 * vk2) * DD + vdq * 8;
            va0 = *reinterpret_cast<const half4v*>(vsrc);
            va1 = *reinterpret_cast<const half4v*>(vsrc + 4);
            vb0 = *reinterpret_cast<const half4v*>(vsrc + DD);
            vb1 = *reinterpret_cast<const half4v*>(vsrc + DD + 4);
        }

        half8v kf[4][2];
        #pragma unroll
        for (int kb = 0; kb < 4; ++kb)
            #pragma unroll
            for (int hb = 0; hb < 2; ++hb)
                kf[kb][hb] = *reinterpret_cast<const half8v*>(
                    &Ks[cur][(kb * 16 + lr) * 72 + hb * 32 + 8 * lg]);

        half4v af[2][4];
        #pragma unroll
        for (int s = 0; s < 2; ++s) {
            f32x4 c[4] = {};
            __builtin_amdgcn_s_setprio(1);
            #pragma unroll
            for (int kb = 0; kb < 4; ++kb)
                #pragma unroll
                for (int hb = 0; hb < 2; ++hb)
                    c[kb] = __builtin_amdgcn_mfma_f32_16x16x32_f16(kf[kb][hb], qf[s][hb], c[kb], 0, 0, 0);
            __builtin_amdgcn_s_setprio(0);

            float rmax = c[0][0];
            #pragma unroll
            for (int kb = 0; kb < 4; ++kb)
                #pragma unroll
                for (int j = 0; j < 4; ++j)
                    rmax = fmaxf(rmax, c[kb][j]);
            rmax = fmaxf(rmax, __shfl_xor(rmax, 16, 64));
            rmax = fmaxf(rmax, __shfl_xor(rmax, 32, 64));
            const float tmax = (float)(half_t)(0.125f * rmax);

            if (__any(tmax > m[s] + 8.0f)) {
                const float mn = fmaxf(m[s], tmax);
                const float sc = __expf(m[s] - mn);
                lsum[s] *= sc;
                #pragma unroll
                for (int db = 0; db < 4; ++db)
                    #pragma unroll
                    for (int j = 0; j < 4; ++j)
                        xacc[s][db][j] *= sc;
                m[s] = mn;
            }

            float ps = 0.f;
            #pragma unroll
            for (int kb = 0; kb < 4; ++kb)
                #pragma unroll
                for (int j = 0; j < 4; ++j) {
                    const half_t e16 = (half_t)(0.125f * c[kb][j]);
                    const float p = __expf((float)e16 - m[s]);
                    ps += p;
                    af[s][kb][j] = (half_t)p;
                }
            ps += __shfl_xor(ps, 16, 64);
            ps += __shfl_xor(ps, 32, 64);
            lsum[s] += ps;
        }

        __builtin_amdgcn_s_setprio(1);
        #pragma unroll
        for (int db = 0; db < 4; ++db)
            #pragma unroll
            for (int kb = 0; kb < 4; ++kb) {
                half4v vf = *reinterpret_cast<const half4v*>(
                    &Vt[cur][(db * 16 + lr) * 72 + kb * 16 + 4 * lg]);
                xacc[0][db] = __builtin_amdgcn_mfma_f32_16x16x16f16(vf, af[0][kb], xacc[0][db], 0, 0, 0);
                xacc[1][db] = __builtin_amdgcn_mfma_f32_16x16x16f16(vf, af[1][kb], xacc[1][db], 0, 0, 0);
            }
        __builtin_amdgcn_s_setprio(0);

        if (t < SS / 64 - 1) {
            const int nxt = cur ^ 1;
            *reinterpret_cast<int4*>(&Ks[nxt][kr * 72 + kc])     = kra;
            *reinterpret_cast<int4*>(&Ks[nxt][kr * 72 + kc + 8]) = krb;
            #pragma unroll
            for (int i = 0; i < 4; ++i) {
                half2v p0 = {va0[i], vb0[i]};
                half2v p1 = {va1[i], vb1[i]};
                *reinterpret_cast<half2v*>(&Vt[nxt][(vdq * 8 + i) * 72 + 2 * vk2])     = p0;
                *reinterpret_cast<half2v*>(&Vt[nxt][(vdq * 8 + i + 4) * 72 + 2 * vk2]) = p1;
            }
        }
        __syncthreads();
    }

    #pragma unroll
    for (int s = 0; s < 2; ++s) {
        const float invl = 1.0f / lsum[s];
        half_t* xp = X + hoff + (size_t)(q0 + s * 16 + lr) * DD;
        #pragma unroll
        for (int db = 0; db < 4; ++db) {
            half4v o;
            #pragma unroll
            for (int j = 0; j < 4; ++j) o[j] = (half_t)(xacc[s][db][j] * invl);
            *reinterpret_cast<half4v*>(xp + db * 16 + 4 * lg) = o;
        }
    }
}

extern "C" void kernel_launch(void* const* d_in, const int* in_sizes, int n_in,
                              void* d_out, int out_size, void* d_ws, size_t ws_size,
                              hipStream_t stream) {
    const float* q   = (const float*)d_in[0];
    const float* k   = (const float*)d_in[1];
    const float* v   = (const float*)d_in[2];
    const float* Wq  = (const float*)d_in[3];
    const float* bq  = (const float*)d_in[4];
    const float* Wk  = (const float*)d_in[5];
    const float* bk  = (const float*)d_in[6];
    const float* Wv  = (const float*)d_in[7];
    const float* bv  = (const float*)d_in[8];
    const float* Wo  = (const float*)d_in[9];
    const float* bo  = (const float*)d_in[10];
    float* out = (float*)d_out;

    const size_t MB = 1ull << 20;
    const size_t ACT = (size_t)MTOT * DD;   // 8.39M elems
    const size_t WEL = (size_t)DD * DD;     // 1.05M elems

    half_t* q16 = (half_t*)d_ws;
    half_t* k16 = q16 + ACT;
    half_t* v16 = k16 + ACT;
    half_t* x16 = v16 + ACT;

    dim3 gblk(256);
    dim3 ablk(256);
    dim3 agrd(1024);

    if (ws_size >= 80 * MB) {
        half_t* wh = x16 + ACT;          // 4 * WEL
        half_t* wl = wh + 4 * WEL;       // 4 * WEL

        dim3 wsgrd(WEL / 4 / 256, 1, 4);
        hipLaunchKernelGGL(split_w4, wsgrd, gblk, 0, stream,
                           Wq, Wk, Wv, Wo, wh, wl);

        dim3 pgrd(MTOT / 128, DD / 128, 3);   // (m=64, n=8, z=3)
        hipLaunchKernelGGL(gemm_proj, pgrd, gblk, 0, stream,
                           q, k, v, wh, wl, bq, bk, bv, q16, k16, v16);

        hipLaunchKernelGGL(attn_fused, agrd, ablk, 0, stream, q16, k16, v16, x16);

        dim3 ogrd(MTOT / 128, DD / 128);      // (m=64, n=8)
        hipLaunchKernelGGL(gemm_out, ogrd, gblk, 0, stream,
                           x16, wh + 3 * WEL, wl + 3 * WEL, bo, out);
    } else if (ws_size >= 72 * MB) {
        half_t* wh = x16 + ACT;
        half_t* wl = wh + WEL;
        const int nw4 = (int)(WEL / 4);
        dim3 sgW((nw4 + 255) / 256);
        dim3 ggrd(DD / 128, MTOT / 128);

        hipLaunchKernelGGL(split_hi_lo, sgW, gblk, 0, stream, Wq, wh, wl, nw4);
        hipLaunchKernelGGL((gemm3s<1, half_t>), ggrd, gblk, 0, stream,
                           nullptr, nullptr, q, wh, wl, bq, q16, DD, DD);
        hipLaunchKernelGGL(split_hi_lo, sgW, gblk, 0, stream, Wk, wh, wl, nw4);
        hipLaunchKernelGGL((gemm3s<1, half_t>), ggrd, gblk, 0, stream,
                           nullptr, nullptr, k, wh, wl, bk, k16, DD, DD);
        hipLaunchKernelGGL(split_hi_lo, sgW, gblk, 0, stream, Wv, wh, wl, nw4);
        hipLaunchKernelGGL((gemm3s<1, half_t>), ggrd, gblk, 0, stream,
                           nullptr, nullptr, v, wh, wl, bv, v16, DD, DD);

        hipLaunchKernelGGL(attn_fused, agrd, ablk, 0, stream, q16, k16, v16, x16);

        hipLaunchKernelGGL(split_hi_lo, sgW, gblk, 0, stream, Wo, wh, wl, nw4);
        hipLaunchKernelGGL((gemm3s<2, float>), ggrd, gblk, 0, stream,
                           x16, nullptr, nullptr, wh, wl, bo, out, DD, DD);
    } else {
        dim3 blk(16, 16);
        dim3 grd(DD / 64, MTOT / 64);
        hipLaunchKernelGGL((gemm_bias<float, half_t>), grd, blk, 0, stream,
                           q, Wq, bq, q16, MTOT, DD, DD);
        hipLaunchKernelGGL((gemm_bias<float, half_t>), grd, blk, 0, stream,
                           k, Wk, bk, k16, MTOT, DD, DD);
        hipLaunchKernelGGL((gemm_bias<float, half_t>), grd, blk, 0, stream,
                           v, Wv, bv, v16, MTOT, DD, DD);
        hipLaunchKernelGGL(attn_fused, agrd, ablk, 0, stream, q16, k16, v16, x16);
        hipLaunchKernelGGL((gemm_bias<half_t, float>), grd, blk, 0, stream,
                           x16, Wo, bo, out, MTOT, DD, DD);
    }
}

// Round 7
// 272.678 us; speedup vs baseline: 15.8984x; 1.0621x over previous
//
#include <hip/hip_runtime.h>
#include <cstdint>

#define BB 4
#define SS 2048
#define DD 1024
#define HH 16
#define HDIM 64
#define MTOT (BB*SS)

using half_t = _Float16;
typedef _Float16 half2v __attribute__((ext_vector_type(2)));
typedef _Float16 half4v __attribute__((ext_vector_type(4)));
typedef _Float16 half8v __attribute__((ext_vector_type(8)));
typedef float f32x4 __attribute__((ext_vector_type(4)));

#if defined(__has_builtin)
#if __has_builtin(__builtin_amdgcn_exp2f)
#define ATTN_EXP2(x) __builtin_amdgcn_exp2f(x)
#endif
#endif

// async global->LDS, 16B per lane; LDS dest = wave-uniform base + lane*16
__device__ __forceinline__ void glds16(const half_t* g, half_t* l) {
    __builtin_amdgcn_global_load_lds(g, l, 16, 0, 0);
}

// ---------------- fp32 -> (hi,lo) f16 split (fallback path) ----------------
__global__ __launch_bounds__(256) void split_hi_lo(const float* __restrict__ x,
    half_t* __restrict__ hi, half_t* __restrict__ lo, int n4)
{
    const int i = blockIdx.x * blockDim.x + threadIdx.x;
    if (i >= n4) return;
    float4 v = reinterpret_cast<const float4*>(x)[i];
    float vv[4] = {v.x, v.y, v.z, v.w};
    half4v h, l;
    #pragma unroll
    for (int j = 0; j < 4; ++j) {
        half_t hh = (half_t)vv[j];
        h[j] = hh;
        l[j] = (half_t)(vv[j] - (float)hh);
    }
    reinterpret_cast<half4v*>(hi)[i] = h;
    reinterpret_cast<half4v*>(lo)[i] = l;
}

// ---------------- split 4 weight matrices in one launch ----------------
__global__ __launch_bounds__(256) void split_w4(
    const float* __restrict__ w0, const float* __restrict__ w1,
    const float* __restrict__ w2, const float* __restrict__ w3,
    half_t* __restrict__ hi, half_t* __restrict__ lo)
{
    const int z = blockIdx.z;
    const float* src = z == 0 ? w0 : z == 1 ? w1 : z == 2 ? w2 : w3;
    const size_t base4 = (size_t)z * (DD * DD / 4);
    const size_t i = base4 + blockIdx.x * 256 + threadIdx.x;
    float4 v = reinterpret_cast<const float4*>(src)[blockIdx.x * 256 + threadIdx.x];
    float vv[4] = {v.x, v.y, v.z, v.w};
    half4v h, l;
    #pragma unroll
    for (int j = 0; j < 4; ++j) {
        half_t hh = (half_t)vv[j];
        h[j] = hh;
        l[j] = (half_t)(vv[j] - (float)hh);
    }
    reinterpret_cast<half4v*>(hi)[i] = h;
    reinterpret_cast<half4v*>(lo)[i] = l;
}

// ---------------- projection GEMM: C[z] = f16(A[z] @ W[z]^T + b[z]) ----------------
__global__ __launch_bounds__(256, 4) void gemm_proj(
    const float* __restrict__ A0, const float* __restrict__ A1,
    const float* __restrict__ A2,
    const half_t* __restrict__ WH, const half_t* __restrict__ WL,
    const float* __restrict__ B0, const float* __restrict__ B1,
    const float* __restrict__ B2,
    half_t* __restrict__ C0, half_t* __restrict__ C1, half_t* __restrict__ C2)
{
    __shared__ __align__(16) half_t AhS[128 * 32];
    __shared__ __align__(16) half_t WhS[128 * 32];
    __shared__ __align__(16) half_t WlS[128 * 32];

    const int z = blockIdx.z;
    const float*  A    = z == 0 ? A0 : z == 1 ? A1 : A2;
    const float*  bias = z == 0 ? B0 : z == 1 ? B1 : B2;
    half_t*       C    = z == 0 ? C0 : z == 1 ? C1 : C2;
    const half_t* WHz  = WH + (size_t)z * (DD * DD);
    const half_t* WLz  = WL + (size_t)z * (DD * DD);

    const int tid = threadIdx.x;
    const int l = tid & 63, w = tid >> 6;
    const int lr = l & 15, lg = l >> 4;
    const int wr = w >> 1, wc = w & 1;
    const int m0 = blockIdx.x * 128, n0 = blockIdx.y * 128;

    const int arow = tid >> 2;
    const int acol = (tid & 3) * 8;
    const int wlrow = l >> 2, wlcol = (l & 3) * 8;

    f32x4 acc[4][4] = {};

    float4 av[2][2];
    #pragma unroll
    for (int j = 0; j < 2; ++j) {
        const float* ap = A + (size_t)(m0 + j * 64 + arow) * DD + acol;
        av[j][0] = *reinterpret_cast<const float4*>(ap);
        av[j][1] = *reinterpret_cast<const float4*>(ap + 4);
    }

    for (int kk = 0; kk < DD; kk += 32) {
        __syncthreads();
        #pragma unroll
        for (int j = 0; j < 2; ++j) {
            half_t hb[8];
            float v0[4] = {av[j][0].x, av[j][0].y, av[j][0].z, av[j][0].w};
            float v1[4] = {av[j][1].x, av[j][1].y, av[j][1].z, av[j][1].w};
            #pragma unroll
            for (int e = 0; e < 4; ++e) { hb[e] = (half_t)v0[e]; hb[4 + e] = (half_t)v1[e]; }
            *reinterpret_cast<int4*>(&AhS[(j * 64 + arow) * 32 + acol]) = *reinterpret_cast<int4*>(hb);
        }
        #pragma unroll
        for (int i = 0; i < 2; ++i) {
            const int rr = (w * 2 + i) * 16 + wlrow;
            glds16(WHz + (size_t)(n0 + rr) * DD + kk + wlcol, &WhS[(w * 2 + i) * 512]);
            glds16(WLz + (size_t)(n0 + rr) * DD + kk + wlcol, &WlS[(w * 2 + i) * 512]);
        }
        if (kk + 32 < DD) {
            #pragma unroll
            for (int j = 0; j < 2; ++j) {
                const float* ap = A + (size_t)(m0 + j * 64 + arow) * DD + kk + 32 + acol;
                av[j][0] = *reinterpret_cast<const float4*>(ap);
                av[j][1] = *reinterpret_cast<const float4*>(ap + 4);
            }
        }
        __syncthreads();

        half8v af[4];
        #pragma unroll
        for (int mt = 0; mt < 4; ++mt)
            af[mt] = *reinterpret_cast<const half8v*>(&AhS[(wr * 64 + mt * 16 + lr) * 32 + 8 * lg]);
        #pragma unroll
        for (int nt = 0; nt < 4; ++nt) {
            half8v wf  = *reinterpret_cast<const half8v*>(&WhS[(wc * 64 + nt * 16 + lr) * 32 + 8 * lg]);
            half8v wlf = *reinterpret_cast<const half8v*>(&WlS[(wc * 64 + nt * 16 + lr) * 32 + 8 * lg]);
            #pragma unroll
            for (int mt = 0; mt < 4; ++mt) {
                acc[mt][nt] = __builtin_amdgcn_mfma_f32_16x16x32_f16(af[mt], wf,  acc[mt][nt], 0, 0, 0);
                acc[mt][nt] = __builtin_amdgcn_mfma_f32_16x16x32_f16(af[mt], wlf, acc[mt][nt], 0, 0, 0);
            }
        }
    }

    #pragma unroll
    for (int nt = 0; nt < 4; ++nt) {
        const int n = n0 + wc * 64 + nt * 16 + lr;
        const float bn = bias[n];
        #pragma unroll
        for (int mt = 0; mt < 4; ++mt) {
            const int mbase = m0 + wr * 64 + mt * 16 + 4 * lg;
            #pragma unroll
            for (int j = 0; j < 4; ++j)
                C[(size_t)(mbase + j) * DD + n] = (half_t)(acc[mt][nt][j] + bn);
        }
    }
}

// ---------------- output GEMM: out = x16 @ Wo^T + bo ----------------
__global__ __launch_bounds__(256, 4) void gemm_out(
    const half_t* __restrict__ Ag,
    const half_t* __restrict__ WHz, const half_t* __restrict__ WLz,
    const float* __restrict__ bias, float* __restrict__ C)
{
    __shared__ __align__(16) half_t AhS[128 * 32];
    __shared__ __align__(16) half_t WhS[128 * 32];
    __shared__ __align__(16) half_t WlS[128 * 32];

    const int tid = threadIdx.x;
    const int l = tid & 63, w = tid >> 6;
    const int lr = l & 15, lg = l >> 4;
    const int wr = w >> 1, wc = w & 1;
    const int m0 = blockIdx.x * 128, n0 = blockIdx.y * 128;
    const int wlrow = l >> 2, wlcol = (l & 3) * 8;

    f32x4 acc[4][4] = {};

    for (int kk = 0; kk < DD; kk += 32) {
        __syncthreads();
        #pragma unroll
        for (int i = 0; i < 2; ++i) {
            const int rr = (w * 2 + i) * 16 + wlrow;
            glds16(Ag  + (size_t)(m0 + rr) * DD + kk + wlcol, &AhS[(w * 2 + i) * 512]);
            glds16(WHz + (size_t)(n0 + rr) * DD + kk + wlcol, &WhS[(w * 2 + i) * 512]);
            glds16(WLz + (size_t)(n0 + rr) * DD + kk + wlcol, &WlS[(w * 2 + i) * 512]);
        }
        __syncthreads();

        half8v af[4];
        #pragma unroll
        for (int mt = 0; mt < 4; ++mt)
            af[mt] = *reinterpret_cast<const half8v*>(&AhS[(wr * 64 + mt * 16 + lr) * 32 + 8 * lg]);
        #pragma unroll
        for (int nt = 0; nt < 4; ++nt) {
            half8v wf  = *reinterpret_cast<const half8v*>(&WhS[(wc * 64 + nt * 16 + lr) * 32 + 8 * lg]);
            half8v wlf = *reinterpret_cast<const half8v*>(&WlS[(wc * 64 + nt * 16 + lr) * 32 + 8 * lg]);
            #pragma unroll
            for (int mt = 0; mt < 4; ++mt) {
                acc[mt][nt] = __builtin_amdgcn_mfma_f32_16x16x32_f16(af[mt], wf,  acc[mt][nt], 0, 0, 0);
                acc[mt][nt] = __builtin_amdgcn_mfma_f32_16x16x32_f16(af[mt], wlf, acc[mt][nt], 0, 0, 0);
            }
        }
    }

    #pragma unroll
    for (int nt = 0; nt < 4; ++nt) {
        const int n = n0 + wc * 64 + nt * 16 + lr;
        const float bn = bias[n];
        #pragma unroll
        for (int mt = 0; mt < 4; ++mt) {
            const int mbase = m0 + wr * 64 + mt * 16 + 4 * lg;
            #pragma unroll
            for (int j = 0; j < 4; ++j)
                C[(size_t)(mbase + j) * DD + n] = acc[mt][nt][j] + bn;
        }
    }
}

// ---------------- old split GEMM (fallback path only) ----------------
template<int MODE, typename TC>
__global__ __launch_bounds__(256) void gemm3s(
    const half_t* __restrict__ Ah, const half_t* __restrict__ Al,
    const float* __restrict__ Af,
    const half_t* __restrict__ Wh, const half_t* __restrict__ Wl,
    const float* __restrict__ bias, TC* __restrict__ C,
    int Kdim, int Ndim)
{
    constexpr int LDT = 72;
    __shared__ __align__(16) half_t As[128 * LDT];
    __shared__ __align__(16) half_t Ws[128 * LDT];
    const int tid = threadIdx.x;
    const int l = tid & 63, w = tid >> 6;
    const int lr = l & 15, lg = l >> 4;
    const int wr = w >> 1, wc = w & 1;
    const int m0 = blockIdx.y * 128, n0 = blockIdx.x * 128;
    const int r = tid >> 1, t = tid & 1;

    f32x4 acc[4][4] = {};

    for (int kk = 0; kk < Kdim; kk += 32) {
        __syncthreads();
        if constexpr (MODE == 1) {
            const float* ap = Af + (size_t)(m0 + r) * Kdim + kk + 16 * t;
            half_t hbuf[16], lbuf[16];
            #pragma unroll
            for (int u = 0; u < 4; ++u) {
                float4 v = *reinterpret_cast<const float4*>(ap + 4 * u);
                float vv[4] = {v.x, v.y, v.z, v.w};
                #pragma unroll
                for (int j = 0; j < 4; ++j) {
                    half_t hh = (half_t)vv[j];
                    hbuf[4 * u + j] = hh;
                    lbuf[4 * u + j] = (half_t)(vv[j] - (float)hh);
                }
            }
            *reinterpret_cast<int4*>(&As[r * LDT + 16 * t])          = *reinterpret_cast<int4*>(hbuf);
            *reinterpret_cast<int4*>(&As[r * LDT + 16 * t + 8])      = *reinterpret_cast<int4*>(hbuf + 8);
            *reinterpret_cast<int4*>(&As[r * LDT + 40 + 16 * t])     = *reinterpret_cast<int4*>(lbuf);
            *reinterpret_cast<int4*>(&As[r * LDT + 40 + 16 * t + 8]) = *reinterpret_cast<int4*>(lbuf + 8);
        } else {
            const half_t* ap = Ah + (size_t)(m0 + r) * Kdim + kk + 16 * t;
            *reinterpret_cast<int4*>(&As[r * LDT + 16 * t])     = *reinterpret_cast<const int4*>(ap);
            *reinterpret_cast<int4*>(&As[r * LDT + 16 * t + 8]) = *reinterpret_cast<const int4*>(ap + 8);
        }
        {
            const half_t* wp = Wh + (size_t)(n0 + r) * Kdim + kk + 16 * t;
            *reinterpret_cast<int4*>(&Ws[r * LDT + 16 * t])     = *reinterpret_cast<const int4*>(wp);
            *reinterpret_cast<int4*>(&Ws[r * LDT + 16 * t + 8]) = *reinterpret_cast<const int4*>(wp + 8);
            const half_t* wlp = Wl + (size_t)(n0 + r) * Kdim + kk + 16 * t;
            *reinterpret_cast<int4*>(&Ws[r * LDT + 40 + 16 * t])     = *reinterpret_cast<const int4*>(wlp);
            *reinterpret_cast<int4*>(&Ws[r * LDT + 40 + 16 * t + 8]) = *reinterpret_cast<const int4*>(wlp + 8);
        }
        __syncthreads();

        half8v af[4], alf[4];
        #pragma unroll
        for (int mt = 0; mt < 4; ++mt) {
            af[mt] = *reinterpret_cast<const half8v*>(&As[(wr * 64 + mt * 16 + lr) * LDT + 8 * lg]);
            if constexpr (MODE != 2)
                alf[mt] = *reinterpret_cast<const half8v*>(&As[(wr * 64 + mt * 16 + lr) * LDT + 40 + 8 * lg]);
        }
        #pragma unroll
        for (int nt = 0; nt < 4; ++nt) {
            half8v wf  = *reinterpret_cast<const half8v*>(&Ws[(wc * 64 + nt * 16 + lr) * LDT + 8 * lg]);
            half8v wlf = *reinterpret_cast<const half8v*>(&Ws[(wc * 64 + nt * 16 + lr) * LDT + 40 + 8 * lg]);
            #pragma unroll
            for (int mt = 0; mt < 4; ++mt) {
                acc[mt][nt] = __builtin_amdgcn_mfma_f32_16x16x32_f16(af[mt], wf, acc[mt][nt], 0, 0, 0);
                acc[mt][nt] = __builtin_amdgcn_mfma_f32_16x16x32_f16(af[mt], wlf, acc[mt][nt], 0, 0, 0);
                if constexpr (MODE != 2)
                    acc[mt][nt] = __builtin_amdgcn_mfma_f32_16x16x32_f16(alf[mt], wf, acc[mt][nt], 0, 0, 0);
            }
        }
    }

    #pragma unroll
    for (int nt = 0; nt < 4; ++nt) {
        const int n = n0 + wc * 64 + nt * 16 + lr;
        const float bn = bias[n];
        #pragma unroll
        for (int mt = 0; mt < 4; ++mt) {
            const int mbase = m0 + wr * 64 + mt * 16 + 4 * lg;
            #pragma unroll
            for (int j = 0; j < 4; ++j) {
                float v = acc[mt][nt][j] + bn;
                if constexpr (sizeof(TC) == 4)
                    C[(size_t)(mbase + j) * Ndim + n] = v;
                else
                    C[(size_t)(mbase + j) * Ndim + n] = (half_t)v;
            }
        }
    }
}

// ---------------- fp32 vector GEMM (ultimate fallback only) ----------------
template<typename TA, typename TC>
__global__ __launch_bounds__(256) void gemm_bias(const TA* __restrict__ A,
    const float* __restrict__ W, const float* __restrict__ bias,
    TC* __restrict__ C, int Mdim, int Ndim, int Kdim)
{
    constexpr int BK = 16;
    __shared__ float As[BK][68];
    __shared__ float Ws[BK][68];
    const int tx = threadIdx.x, ty = threadIdx.y;
    const int tid = ty * 16 + tx;
    const int m0 = blockIdx.y * 64, n0 = blockIdx.x * 64;
    const int lrow = tid >> 2;
    const int lc4  = (tid & 3) * 4;

    float acc[4][4] = {};
    for (int kk = 0; kk < Kdim; kk += BK) {
        {
            const TA* ap = A + (size_t)(m0 + lrow) * Kdim + kk + lc4;
            float a0, a1, a2, a3;
            if constexpr (sizeof(TA) == 4) {
                float4 v = *reinterpret_cast<const float4*>(ap);
                a0 = v.x; a1 = v.y; a2 = v.z; a3 = v.w;
            } else {
                half2v v0 = *reinterpret_cast<const half2v*>(ap);
                half2v v1 = *reinterpret_cast<const half2v*>(ap + 2);
                a0 = (float)v0[0]; a1 = (float)v0[1];
                a2 = (float)v1[0]; a3 = (float)v1[1];
            }
            As[lc4 + 0][lrow] = a0; As[lc4 + 1][lrow] = a1;
            As[lc4 + 2][lrow] = a2; As[lc4 + 3][lrow] = a3;
            const float* wp = W + (size_t)(n0 + lrow) * Kdim + kk + lc4;
            float4 wv = *reinterpret_cast<const float4*>(wp);
            Ws[lc4 + 0][lrow] = wv.x; Ws[lc4 + 1][lrow] = wv.y;
            Ws[lc4 + 2][lrow] = wv.z; Ws[lc4 + 3][lrow] = wv.w;
        }
        __syncthreads();
        #pragma unroll
        for (int k = 0; k < BK; ++k) {
            float4 av = *reinterpret_cast<const float4*>(&As[k][ty * 4]);
            float4 bv = *reinterpret_cast<const float4*>(&Ws[k][tx * 4]);
            float a[4] = {av.x, av.y, av.z, av.w};
            float b[4] = {bv.x, bv.y, bv.z, bv.w};
            #pragma unroll
            for (int i = 0; i < 4; ++i)
                #pragma unroll
                for (int j = 0; j < 4; ++j)
                    acc[i][j] = fmaf(a[i], b[j], acc[i][j]);
        }
        __syncthreads();
    }
    #pragma unroll
    for (int i = 0; i < 4; ++i) {
        const int m = m0 + ty * 4 + i;
        #pragma unroll
        for (int j = 0; j < 4; ++j) {
            const int n = n0 + tx * 4 + j;
            float v = acc[i][j] + bias[n];
            if constexpr (sizeof(TC) == 4)
                C[(size_t)m * Ndim + n] = v;
            else
                C[(size_t)m * Ndim + n] = (half_t)v;
        }
    }
}

// ---------------- single-pass fused attention ----------------
// K via global_load_lds into linear [64][64] LDS, XOR-pre-swizzled global
// source (chunk c at row r holds global chunk c^(r&7)) -> conflict-free
// b128 frag reads, zero VALU staging. Q pre-scaled by 1/8 (exact pow2,
// commutes with f32 accum + f16 RTE -> e16 bit-identical to prior rounds).
// Softmax in exp2 domain: p = exp2(fma(e16, log2e, -m*log2e)).
__global__ __launch_bounds__(256, 4) void attn_fused(const half_t* __restrict__ Q,
    const half_t* __restrict__ K, const half_t* __restrict__ V,
    half_t* __restrict__ X)
{
    __shared__ __align__(16) half_t KsL[2][64 * 64];   // linear, swizzled content
    __shared__ __align__(16) half_t Vt[2][64 * 72];    // transposed V

    const int tid = threadIdx.x;
    const int l   = tid & 63;
    const int w   = tid >> 6;
    const int lr  = l & 15;
    const int lg  = l >> 4;

    const int phys = blockIdx.x;
    const int virt = (phys & 7) * 128 + (phys >> 3);
    const int qb = virt & 15;
    const int h  = (virt >> 4) & 15;
    const int b  = virt >> 8;

    const int q0 = qb * 128 + w * 32;
    const size_t hoff = (size_t)(b * SS) * DD + h * HDIM;

    // Q fragments, pre-scaled by 1/8
    half8v qf[2][2];
    #pragma unroll
    for (int s = 0; s < 2; ++s) {
        const half_t* qp = Q + hoff + (size_t)(q0 + s * 16 + lr) * DD;
        #pragma unroll
        for (int hb = 0; hb < 2; ++hb) {
            half8v v = *reinterpret_cast<const half8v*>(qp + hb * 32 + 8 * lg);
            #pragma unroll
            for (int e = 0; e < 8; ++e) v[e] *= (half_t)0.125f;
            qf[s][hb] = v;
        }
    }

    // K staging: per-lane swizzled global source offsets (halves)
    int koffH[2];
    #pragma unroll
    for (int i = 0; i < 2; ++i) {
        const int row = (w * 2 + i) * 8 + (l >> 3);
        const int gc  = (l & 7) ^ (row & 7);
        koffH[i] = row * DD + gc * 8;
    }
    // swizzled frag-read indices (halves within a kb-block)
    const int kidx0 = lr * 64 + ((lg ^ (lr & 7)) * 8);
    const int kidx1 = lr * 64 + (((4 + lg) ^ (lr & 7)) * 8);

    const int vk2 = tid & 31, vdq = tid >> 5;

    float m[2]    = {-1e30f, -1e30f};
    float lsum[2] = {0.f, 0.f};
    f32x4 xacc[2][4] = {};

    half4v va0, va1, vb0, vb1;
    {   // prologue: stage tile 0
        const half_t* kbase = K + hoff;
        glds16(kbase + koffH[0], &KsL[0][(w * 2 + 0) * 512]);
        glds16(kbase + koffH[1], &KsL[0][(w * 2 + 1) * 512]);
        const half_t* vsrc = V + hoff + (size_t)(2 * vk2) * DD + vdq * 8;
        va0 = *reinterpret_cast<const half4v*>(vsrc);
        va1 = *reinterpret_cast<const half4v*>(vsrc + 4);
        vb0 = *reinterpret_cast<const half4v*>(vsrc + DD);
        vb1 = *reinterpret_cast<const half4v*>(vsrc + DD + 4);
        #pragma unroll
        for (int i = 0; i < 4; ++i) {
            half2v p0 = {va0[i], vb0[i]};
            half2v p1 = {va1[i], vb1[i]};
            *reinterpret_cast<half2v*>(&Vt[0][(vdq * 8 + i) * 72 + 2 * vk2])     = p0;
            *reinterpret_cast<half2v*>(&Vt[0][(vdq * 8 + i + 4) * 72 + 2 * vk2]) = p1;
        }
    }
    __syncthreads();

    for (int t = 0; t < SS / 64; ++t) {
        const int cur = t & 1, nxt = cur ^ 1;
        if (t < SS / 64 - 1) {   // issue next-tile loads early (T14)
            const half_t* kbase = K + hoff + (size_t)(t + 1) * 64 * DD;
            glds16(kbase + koffH[0], &KsL[nxt][(w * 2 + 0) * 512]);
            glds16(kbase + koffH[1], &KsL[nxt][(w * 2 + 1) * 512]);
            const half_t* vsrc = V + hoff + (size_t)((t + 1) * 64 + 2 * vk2) * DD + vdq * 8;
            va0 = *reinterpret_cast<const half4v*>(vsrc);
            va1 = *reinterpret_cast<const half4v*>(vsrc + 4);
            vb0 = *reinterpret_cast<const half4v*>(vsrc + DD);
            vb1 = *reinterpret_cast<const half4v*>(vsrc + DD + 4);
        }

        half8v kf[4][2];
        #pragma unroll
        for (int kb = 0; kb < 4; ++kb) {
            kf[kb][0] = *reinterpret_cast<const half8v*>(&KsL[cur][kb * 1024 + kidx0]);
            kf[kb][1] = *reinterpret_cast<const half8v*>(&KsL[cur][kb * 1024 + kidx1]);
        }

        half4v af[2][4];
        #pragma unroll
        for (int s = 0; s < 2; ++s) {
            f32x4 c[4] = {};
            __builtin_amdgcn_s_setprio(1);
            #pragma unroll
            for (int kb = 0; kb < 4; ++kb)
                #pragma unroll
                for (int hb = 0; hb < 2; ++hb)
                    c[kb] = __builtin_amdgcn_mfma_f32_16x16x32_f16(kf[kb][hb], qf[s][hb], c[kb], 0, 0, 0);
            __builtin_amdgcn_s_setprio(0);

            // max tree (max3-friendly); c is already the f16-domain score
            float r0 = fmaxf(fmaxf(c[0][0], c[0][1]), fmaxf(c[0][2], c[0][3]));
            float r1 = fmaxf(fmaxf(c[1][0], c[1][1]), fmaxf(c[1][2], c[1][3]));
            float r2 = fmaxf(fmaxf(c[2][0], c[2][1]), fmaxf(c[2][2], c[2][3]));
            float r3 = fmaxf(fmaxf(c[3][0], c[3][1]), fmaxf(c[3][2], c[3][3]));
            float rmax = fmaxf(fmaxf(r0, r1), fmaxf(r2, r3));
            rmax = fmaxf(rmax, __shfl_xor(rmax, 16, 64));
            rmax = fmaxf(rmax, __shfl_xor(rmax, 32, 64));
            const float tmax = (float)(half_t)rmax;   // f16 RTE monotone

            if (__any(tmax > m[s] + 8.0f)) {   // defer-max fold
                const float mn = fmaxf(m[s], tmax);
                const float sc = __expf(m[s] - mn);
                lsum[s] *= sc;
                #pragma unroll
                for (int db = 0; db < 4; ++db)
                    #pragma unroll
                    for (int j = 0; j < 4; ++j)
                        xacc[s][db][j] *= sc;
                m[s] = mn;
            }

            const float nm2 = m[s] * -1.4426950408889634f;
            (void)nm2;
            float ps = 0.f;
            #pragma unroll
            for (int kb = 0; kb < 4; ++kb)
                #pragma unroll
                for (int j = 0; j < 4; ++j) {
                    const half_t e16 = (half_t)c[kb][j];   // f16 score (ref semantics)
                    const float ef = (float)e16;
#ifdef ATTN_EXP2
                    const float p = ATTN_EXP2(__builtin_fmaf(ef, 1.4426950408889634f, nm2));
#else
                    const float p = __expf(ef - m[s]);
#endif
                    ps += p;
                    af[s][kb][j] = (half_t)p;              // p16
                }
            ps += __shfl_xor(ps, 16, 64);
            ps += __shfl_xor(ps, 32, 64);
            lsum[s] += ps;
        }

        // PV: x^T += Vt-frag * p16
        __builtin_amdgcn_s_setprio(1);
        #pragma unroll
        for (int db = 0; db < 4; ++db)
            #pragma unroll
            for (int kb = 0; kb < 4; ++kb) {
                half4v vf = *reinterpret_cast<const half4v*>(
                    &Vt[cur][(db * 16 + lr) * 72 + kb * 16 + 4 * lg]);
                xacc[0][db] = __builtin_amdgcn_mfma_f32_16x16x16f16(vf, af[0][kb], xacc[0][db], 0, 0, 0);
                xacc[1][db] = __builtin_amdgcn_mfma_f32_16x16x16f16(vf, af[1][kb], xacc[1][db], 0, 0, 0);
            }
        __builtin_amdgcn_s_setprio(0);

        if (t < SS / 64 - 1) {   // write V-transpose into other buffer
            #pragma unroll
            for (int i = 0; i < 4; ++i) {
                half2v p0 = {va0[i], vb0[i]};
                half2v p1 = {va1[i], vb1[i]};
                *reinterpret_cast<half2v*>(&Vt[nxt][(vdq * 8 + i) * 72 + 2 * vk2])     = p0;
                *reinterpret_cast<half2v*>(&Vt[nxt][(vdq * 8 + i + 4) * 72 + 2 * vk2]) = p1;
            }
        }
        __syncthreads();   // drains vmcnt (gload) + lgkm; buffers swap
    }

    // epilogue: normalize in f32, round to f16, store
    #pragma unroll
    for (int s = 0; s < 2; ++s) {
        const float invl = 1.0f / lsum[s];
        half_t* xp = X + hoff + (size_t)(q0 + s * 16 + lr) * DD;
        #pragma unroll
        for (int db = 0; db < 4; ++db) {
            half4v o;
            #pragma unroll
            for (int j = 0; j < 4; ++j) o[j] = (half_t)(xacc[s][db][j] * invl);
            *reinterpret_cast<half4v*>(xp + db * 16 + 4 * lg) = o;
        }
    }
}

extern "C" void kernel_launch(void* const* d_in, const int* in_sizes, int n_in,
                              void* d_out, int out_size, void* d_ws, size_t ws_size,
                              hipStream_t stream) {
    const float* q   = (const float*)d_in[0];
    const float* k   = (const float*)d_in[1];
    const float* v   = (const float*)d_in[2];
    const float* Wq  = (const float*)d_in[3];
    const float* bq  = (const float*)d_in[4];
    const float* Wk  = (const float*)d_in[5];
    const float* bk  = (const float*)d_in[6];
    const float* Wv  = (const float*)d_in[7];
    const float* bv  = (const float*)d_in[8];
    const float* Wo  = (const float*)d_in[9];
    const float* bo  = (const float*)d_in[10];
    float* out = (float*)d_out;

    const size_t MB = 1ull << 20;
    const size_t ACT = (size_t)MTOT * DD;   // 8.39M elems
    const size_t WEL = (size_t)DD * DD;     // 1.05M elems

    half_t* q16 = (half_t*)d_ws;
    half_t* k16 = q16 + ACT;
    half_t* v16 = k16 + ACT;
    half_t* x16 = v16 + ACT;

    dim3 gblk(256);
    dim3 ablk(256);
    dim3 agrd(1024);

    if (ws_size >= 80 * MB) {
        half_t* wh = x16 + ACT;          // 4 * WEL
        half_t* wl = wh + 4 * WEL;       // 4 * WEL

        dim3 wsgrd(WEL / 4 / 256, 1, 4);
        hipLaunchKernelGGL(split_w4, wsgrd, gblk, 0, stream,
                           Wq, Wk, Wv, Wo, wh, wl);

        dim3 pgrd(MTOT / 128, DD / 128, 3);   // (m=64, n=8, z=3)
        hipLaunchKernelGGL(gemm_proj, pgrd, gblk, 0, stream,
                           q, k, v, wh, wl, bq, bk, bv, q16, k16, v16);

        hipLaunchKernelGGL(attn_fused, agrd, ablk, 0, stream, q16, k16, v16, x16);

        dim3 ogrd(MTOT / 128, DD / 128);      // (m=64, n=8)
        hipLaunchKernelGGL(gemm_out, ogrd, gblk, 0, stream,
                           x16, wh + 3 * WEL, wl + 3 * WEL, bo, out);
    } else if (ws_size >= 72 * MB) {
        half_t* wh = x16 + ACT;
        half_t* wl = wh + WEL;
        const int nw4 = (int)(WEL / 4);
        dim3 sgW((nw4 + 255) / 256);
        dim3 ggrd(DD / 128, MTOT / 128);

        hipLaunchKernelGGL(split_hi_lo, sgW, gblk, 0, stream, Wq, wh, wl, nw4);
        hipLaunchKernelGGL((gemm3s<1, half_t>), ggrd, gblk, 0, stream,
                           nullptr, nullptr, q, wh, wl, bq, q16, DD, DD);
        hipLaunchKernelGGL(split_hi_lo, sgW, gblk, 0, stream, Wk, wh, wl, nw4);
        hipLaunchKernelGGL((gemm3s<1, half_t>), ggrd, gblk, 0, stream,
                           nullptr, nullptr, k, wh, wl, bk, k16, DD, DD);
        hipLaunchKernelGGL(split_hi_lo, sgW, gblk, 0, stream, Wv, wh, wl, nw4);
        hipLaunchKernelGGL((gemm3s<1, half_t>), ggrd, gblk, 0, stream,
                           nullptr, nullptr, v, wh, wl, bv, v16, DD, DD);

        hipLaunchKernelGGL(attn_fused, agrd, ablk, 0, stream, q16, k16, v16, x16);

        hipLaunchKernelGGL(split_hi_lo, sgW, gblk, 0, stream, Wo, wh, wl, nw4);
        hipLaunchKernelGGL((gemm3s<2, float>), ggrd, gblk, 0, stream,
                           x16, nullptr, nullptr, wh, wl, bo, out, DD, DD);
    } else {
        dim3 blk(16, 16);
        dim3 grd(DD / 64, MTOT / 64);
        hipLaunchKernelGGL((gemm_bias<float, half_t>), grd, blk, 0, stream,
                           q, Wq, bq, q16, MTOT, DD, DD);
        hipLaunchKernelGGL((gemm_bias<float, half_t>), grd, blk, 0, stream,
                           k, Wk, bk, k16, MTOT, DD, DD);
        hipLaunchKernelGGL((gemm_bias<float, half_t>), grd, blk, 0, stream,
                           v, Wv, bv, v16, MTOT, DD, DD);
        hipLaunchKernelGGL(attn_fused, agrd, ablk, 0, stream, q16, k16, v16, x16);
        hipLaunchKernelGGL((gemm_bias<half_t, float>), grd, blk, 0, stream,
                           x16, Wo, bo, out, MTOT, DD, DD);
    }
}

// Round 8
// 268.616 us; speedup vs baseline: 16.1388x; 1.0151x over previous
//
#include <hip/hip_runtime.h>
#include <cstdint>

#define BB 4
#define SS 2048
#define DD 1024
#define HH 16
#define HDIM 64
#define MTOT (BB*SS)

using half_t = _Float16;
typedef _Float16 half2v __attribute__((ext_vector_type(2)));
typedef _Float16 half4v __attribute__((ext_vector_type(4)));
typedef _Float16 half8v __attribute__((ext_vector_type(8)));
typedef float f32x4 __attribute__((ext_vector_type(4)));

#if defined(__has_builtin)
#if __has_builtin(__builtin_amdgcn_exp2f)
#define ATTN_EXP2(x) __builtin_amdgcn_exp2f(x)
#endif
#endif

// async global->LDS, 16B per lane; LDS dest = wave-uniform base + lane*16
__device__ __forceinline__ void glds16(const half_t* g, half_t* l) {
    __builtin_amdgcn_global_load_lds(g, l, 16, 0, 0);
}

// ---------------- fp32 -> (hi,lo) f16 split (fallback path) ----------------
__global__ __launch_bounds__(256) void split_hi_lo(const float* __restrict__ x,
    half_t* __restrict__ hi, half_t* __restrict__ lo, int n4)
{
    const int i = blockIdx.x * blockDim.x + threadIdx.x;
    if (i >= n4) return;
    float4 v = reinterpret_cast<const float4*>(x)[i];
    float vv[4] = {v.x, v.y, v.z, v.w};
    half4v h, l;
    #pragma unroll
    for (int j = 0; j < 4; ++j) {
        half_t hh = (half_t)vv[j];
        h[j] = hh;
        l[j] = (half_t)(vv[j] - (float)hh);
    }
    reinterpret_cast<half4v*>(hi)[i] = h;
    reinterpret_cast<half4v*>(lo)[i] = l;
}

// ---------------- split 4 weight matrices in one launch ----------------
__global__ __launch_bounds__(256) void split_w4(
    const float* __restrict__ w0, const float* __restrict__ w1,
    const float* __restrict__ w2, const float* __restrict__ w3,
    half_t* __restrict__ hi, half_t* __restrict__ lo)
{
    const int z = blockIdx.z;
    const float* src = z == 0 ? w0 : z == 1 ? w1 : z == 2 ? w2 : w3;
    const size_t base4 = (size_t)z * (DD * DD / 4);
    const size_t i = base4 + blockIdx.x * 256 + threadIdx.x;
    float4 v = reinterpret_cast<const float4*>(src)[blockIdx.x * 256 + threadIdx.x];
    float vv[4] = {v.x, v.y, v.z, v.w};
    half4v h, l;
    #pragma unroll
    for (int j = 0; j < 4; ++j) {
        half_t hh = (half_t)vv[j];
        h[j] = hh;
        l[j] = (half_t)(vv[j] - (float)hh);
    }
    reinterpret_cast<half4v*>(hi)[i] = h;
    reinterpret_cast<half4v*>(lo)[i] = l;
}

// ---------------- projection GEMM: C[z] = f16(A[z] @ W[z]^T + b[z]) ----------------
// 2-deep pipelined: double-buffered LDS; tile t+1 staging (W gload_lds +
// A hi-split ds_write from prefetched regs) issued BEFORE tile t's MFMAs,
// one vmcnt(0)+barrier per tile -> global latency hides under compute.
__global__ __launch_bounds__(256, 3) void gemm_proj(
    const float* __restrict__ A0, const float* __restrict__ A1,
    const float* __restrict__ A2,
    const half_t* __restrict__ WH, const half_t* __restrict__ WL,
    const float* __restrict__ B0, const float* __restrict__ B1,
    const float* __restrict__ B2,
    half_t* __restrict__ C0, half_t* __restrict__ C1, half_t* __restrict__ C2)
{
    __shared__ __align__(16) half_t AhS[2][128 * 32];
    __shared__ __align__(16) half_t WhS[2][128 * 32];
    __shared__ __align__(16) half_t WlS[2][128 * 32];

    const int z = blockIdx.z;
    const float*  A    = z == 0 ? A0 : z == 1 ? A1 : A2;
    const float*  bias = z == 0 ? B0 : z == 1 ? B1 : B2;
    half_t*       C    = z == 0 ? C0 : z == 1 ? C1 : C2;
    const half_t* WHz  = WH + (size_t)z * (DD * DD);
    const half_t* WLz  = WL + (size_t)z * (DD * DD);

    const int tid = threadIdx.x;
    const int l = tid & 63, w = tid >> 6;
    const int lr = l & 15, lg = l >> 4;
    const int wr = w >> 1, wc = w & 1;
    const int m0 = blockIdx.x * 128, n0 = blockIdx.y * 128;

    const int arow = tid >> 2;          // 0..63 (rows j*64+arow)
    const int acol = (tid & 3) * 8;     // 0,8,16,24
    const int wlrow = l >> 2, wlcol = (l & 3) * 8;

    f32x4 acc[4][4] = {};
    float4 av[2][2];

    // --- prologue: stage tile 0, prefetch A(tile 1) regs ---
    #pragma unroll
    for (int j = 0; j < 2; ++j) {
        const float* ap = A + (size_t)(m0 + j * 64 + arow) * DD + acol;
        av[j][0] = *reinterpret_cast<const float4*>(ap);
        av[j][1] = *reinterpret_cast<const float4*>(ap + 4);
    }
    #pragma unroll
    for (int j = 0; j < 2; ++j) {
        half_t hb[8];
        float v0[4] = {av[j][0].x, av[j][0].y, av[j][0].z, av[j][0].w};
        float v1[4] = {av[j][1].x, av[j][1].y, av[j][1].z, av[j][1].w};
        #pragma unroll
        for (int e = 0; e < 4; ++e) { hb[e] = (half_t)v0[e]; hb[4 + e] = (half_t)v1[e]; }
        *reinterpret_cast<int4*>(&AhS[0][(j * 64 + arow) * 32 + acol]) = *reinterpret_cast<int4*>(hb);
    }
    #pragma unroll
    for (int i = 0; i < 2; ++i) {
        const int rr = (w * 2 + i) * 16 + wlrow;
        glds16(WHz + (size_t)(n0 + rr) * DD + wlcol, &WhS[0][(w * 2 + i) * 512]);
        glds16(WLz + (size_t)(n0 + rr) * DD + wlcol, &WlS[0][(w * 2 + i) * 512]);
    }
    #pragma unroll
    for (int j = 0; j < 2; ++j) {
        const float* ap = A + (size_t)(m0 + j * 64 + arow) * DD + 32 + acol;
        av[j][0] = *reinterpret_cast<const float4*>(ap);
        av[j][1] = *reinterpret_cast<const float4*>(ap + 4);
    }
    __syncthreads();

    for (int t = 0; t < 32; ++t) {
        const int cur = t & 1, nxt = cur ^ 1;
        if (t < 31) {
            // issue next-tile W loads FIRST (async, hide under MFMAs)
            const int kk1 = (t + 1) * 32;
            #pragma unroll
            for (int i = 0; i < 2; ++i) {
                const int rr = (w * 2 + i) * 16 + wlrow;
                glds16(WHz + (size_t)(n0 + rr) * DD + kk1 + wlcol, &WhS[nxt][(w * 2 + i) * 512]);
                glds16(WLz + (size_t)(n0 + rr) * DD + kk1 + wlcol, &WlS[nxt][(w * 2 + i) * 512]);
            }
            // hi-cast prefetched A(t+1) -> LDS
            #pragma unroll
            for (int j = 0; j < 2; ++j) {
                half_t hb[8];
                float v0[4] = {av[j][0].x, av[j][0].y, av[j][0].z, av[j][0].w};
                float v1[4] = {av[j][1].x, av[j][1].y, av[j][1].z, av[j][1].w};
                #pragma unroll
                for (int e = 0; e < 4; ++e) { hb[e] = (half_t)v0[e]; hb[4 + e] = (half_t)v1[e]; }
                *reinterpret_cast<int4*>(&AhS[nxt][(j * 64 + arow) * 32 + acol]) = *reinterpret_cast<int4*>(hb);
            }
        }

        half8v af[4];
        #pragma unroll
        for (int mt = 0; mt < 4; ++mt)
            af[mt] = *reinterpret_cast<const half8v*>(&AhS[cur][(wr * 64 + mt * 16 + lr) * 32 + 8 * lg]);
        #pragma unroll
        for (int nt = 0; nt < 4; ++nt) {
            half8v wf  = *reinterpret_cast<const half8v*>(&WhS[cur][(wc * 64 + nt * 16 + lr) * 32 + 8 * lg]);
            half8v wlf = *reinterpret_cast<const half8v*>(&WlS[cur][(wc * 64 + nt * 16 + lr) * 32 + 8 * lg]);
            #pragma unroll
            for (int mt = 0; mt < 4; ++mt) {
                acc[mt][nt] = __builtin_amdgcn_mfma_f32_16x16x32_f16(af[mt], wf,  acc[mt][nt], 0, 0, 0);
                acc[mt][nt] = __builtin_amdgcn_mfma_f32_16x16x32_f16(af[mt], wlf, acc[mt][nt], 0, 0, 0);
            }
        }

        if (t < 30) {   // prefetch A(t+2) regs during MFMA phase
            const int kk2 = (t + 2) * 32;
            #pragma unroll
            for (int j = 0; j < 2; ++j) {
                const float* ap = A + (size_t)(m0 + j * 64 + arow) * DD + kk2 + acol;
                av[j][0] = *reinterpret_cast<const float4*>(ap);
                av[j][1] = *reinterpret_cast<const float4*>(ap + 4);
            }
        }
        __syncthreads();   // one drain per tile; next-tile loads had full MFMA phase
    }

    #pragma unroll
    for (int nt = 0; nt < 4; ++nt) {
        const int n = n0 + wc * 64 + nt * 16 + lr;
        const float bn = bias[n];
        #pragma unroll
        for (int mt = 0; mt < 4; ++mt) {
            const int mbase = m0 + wr * 64 + mt * 16 + 4 * lg;
            #pragma unroll
            for (int j = 0; j < 4; ++j)
                C[(size_t)(mbase + j) * DD + n] = (half_t)(acc[mt][nt][j] + bn);
        }
    }
}

// ---------------- output GEMM: out = x16 @ Wo^T + bo (2-deep pipelined) ----------------
__global__ __launch_bounds__(256, 3) void gemm_out(
    const half_t* __restrict__ Ag,
    const half_t* __restrict__ WHz, const half_t* __restrict__ WLz,
    const float* __restrict__ bias, float* __restrict__ C)
{
    __shared__ __align__(16) half_t AhS[2][128 * 32];
    __shared__ __align__(16) half_t WhS[2][128 * 32];
    __shared__ __align__(16) half_t WlS[2][128 * 32];

    const int tid = threadIdx.x;
    const int l = tid & 63, w = tid >> 6;
    const int lr = l & 15, lg = l >> 4;
    const int wr = w >> 1, wc = w & 1;
    const int m0 = blockIdx.x * 128, n0 = blockIdx.y * 128;
    const int wlrow = l >> 2, wlcol = (l & 3) * 8;

    f32x4 acc[4][4] = {};

    // prologue: stage tile 0
    #pragma unroll
    for (int i = 0; i < 2; ++i) {
        const int rr = (w * 2 + i) * 16 + wlrow;
        glds16(Ag  + (size_t)(m0 + rr) * DD + wlcol, &AhS[0][(w * 2 + i) * 512]);
        glds16(WHz + (size_t)(n0 + rr) * DD + wlcol, &WhS[0][(w * 2 + i) * 512]);
        glds16(WLz + (size_t)(n0 + rr) * DD + wlcol, &WlS[0][(w * 2 + i) * 512]);
    }
    __syncthreads();

    for (int t = 0; t < 32; ++t) {
        const int cur = t & 1, nxt = cur ^ 1;
        if (t < 31) {
            const int kk1 = (t + 1) * 32;
            #pragma unroll
            for (int i = 0; i < 2; ++i) {
                const int rr = (w * 2 + i) * 16 + wlrow;
                glds16(Ag  + (size_t)(m0 + rr) * DD + kk1 + wlcol, &AhS[nxt][(w * 2 + i) * 512]);
                glds16(WHz + (size_t)(n0 + rr) * DD + kk1 + wlcol, &WhS[nxt][(w * 2 + i) * 512]);
                glds16(WLz + (size_t)(n0 + rr) * DD + kk1 + wlcol, &WlS[nxt][(w * 2 + i) * 512]);
            }
        }

        half8v af[4];
        #pragma unroll
        for (int mt = 0; mt < 4; ++mt)
            af[mt] = *reinterpret_cast<const half8v*>(&AhS[cur][(wr * 64 + mt * 16 + lr) * 32 + 8 * lg]);
        #pragma unroll
        for (int nt = 0; nt < 4; ++nt) {
            half8v wf  = *reinterpret_cast<const half8v*>(&WhS[cur][(wc * 64 + nt * 16 + lr) * 32 + 8 * lg]);
            half8v wlf = *reinterpret_cast<const half8v*>(&WlS[cur][(wc * 64 + nt * 16 + lr) * 32 + 8 * lg]);
            #pragma unroll
            for (int mt = 0; mt < 4; ++mt) {
                acc[mt][nt] = __builtin_amdgcn_mfma_f32_16x16x32_f16(af[mt], wf,  acc[mt][nt], 0, 0, 0);
                acc[mt][nt] = __builtin_amdgcn_mfma_f32_16x16x32_f16(af[mt], wlf, acc[mt][nt], 0, 0, 0);
            }
        }
        __syncthreads();
    }

    #pragma unroll
    for (int nt = 0; nt < 4; ++nt) {
        const int n = n0 + wc * 64 + nt * 16 + lr;
        const float bn = bias[n];
        #pragma unroll
        for (int mt = 0; mt < 4; ++mt) {
            const int mbase = m0 + wr * 64 + mt * 16 + 4 * lg;
            #pragma unroll
            for (int j = 0; j < 4; ++j)
                C[(size_t)(mbase + j) * DD + n] = acc[mt][nt][j] + bn;
        }
    }
}

// ---------------- old split GEMM (fallback path only) ----------------
template<int MODE, typename TC>
__global__ __launch_bounds__(256) void gemm3s(
    const half_t* __restrict__ Ah, const half_t* __restrict__ Al,
    const float* __restrict__ Af,
    const half_t* __restrict__ Wh, const half_t* __restrict__ Wl,
    const float* __restrict__ bias, TC* __restrict__ C,
    int Kdim, int Ndim)
{
    constexpr int LDT = 72;
    __shared__ __align__(16) half_t As[128 * LDT];
    __shared__ __align__(16) half_t Ws[128 * LDT];
    const int tid = threadIdx.x;
    const int l = tid & 63, w = tid >> 6;
    const int lr = l & 15, lg = l >> 4;
    const int wr = w >> 1, wc = w & 1;
    const int m0 = blockIdx.y * 128, n0 = blockIdx.x * 128;
    const int r = tid >> 1, t = tid & 1;

    f32x4 acc[4][4] = {};

    for (int kk = 0; kk < Kdim; kk += 32) {
        __syncthreads();
        if constexpr (MODE == 1) {
            const float* ap = Af + (size_t)(m0 + r) * Kdim + kk + 16 * t;
            half_t hbuf[16], lbuf[16];
            #pragma unroll
            for (int u = 0; u < 4; ++u) {
                float4 v = *reinterpret_cast<const float4*>(ap + 4 * u);
                float vv[4] = {v.x, v.y, v.z, v.w};
                #pragma unroll
                for (int j = 0; j < 4; ++j) {
                    half_t hh = (half_t)vv[j];
                    hbuf[4 * u + j] = hh;
                    lbuf[4 * u + j] = (half_t)(vv[j] - (float)hh);
                }
            }
            *reinterpret_cast<int4*>(&As[r * LDT + 16 * t])          = *reinterpret_cast<int4*>(hbuf);
            *reinterpret_cast<int4*>(&As[r * LDT + 16 * t + 8])      = *reinterpret_cast<int4*>(hbuf + 8);
            *reinterpret_cast<int4*>(&As[r * LDT + 40 + 16 * t])     = *reinterpret_cast<int4*>(lbuf);
            *reinterpret_cast<int4*>(&As[r * LDT + 40 + 16 * t + 8]) = *reinterpret_cast<int4*>(lbuf + 8);
        } else {
            const half_t* ap = Ah + (size_t)(m0 + r) * Kdim + kk + 16 * t;
            *reinterpret_cast<int4*>(&As[r * LDT + 16 * t])     = *reinterpret_cast<const int4*>(ap);
            *reinterpret_cast<int4*>(&As[r * LDT + 16 * t + 8]) = *reinterpret_cast<const int4*>(ap + 8);
        }
        {
            const half_t* wp = Wh + (size_t)(n0 + r) * Kdim + kk + 16 * t;
            *reinterpret_cast<int4*>(&Ws[r * LDT + 16 * t])     = *reinterpret_cast<const int4*>(wp);
            *reinterpret_cast<int4*>(&Ws[r * LDT + 16 * t + 8]) = *reinterpret_cast<const int4*>(wp + 8);
            const half_t* wlp = Wl + (size_t)(n0 + r) * Kdim + kk + 16 * t;
            *reinterpret_cast<int4*>(&Ws[r * LDT + 40 + 16 * t])     = *reinterpret_cast<const int4*>(wlp);
            *reinterpret_cast<int4*>(&Ws[r * LDT + 40 + 16 * t + 8]) = *reinterpret_cast<const int4*>(wlp + 8);
        }
        __syncthreads();

        half8v af[4], alf[4];
        #pragma unroll
        for (int mt = 0; mt < 4; ++mt) {
            af[mt] = *reinterpret_cast<const half8v*>(&As[(wr * 64 + mt * 16 + lr) * LDT + 8 * lg]);
            if constexpr (MODE != 2)
                alf[mt] = *reinterpret_cast<const half8v*>(&As[(wr * 64 + mt * 16 + lr) * LDT + 40 + 8 * lg]);
        }
        #pragma unroll
        for (int nt = 0; nt < 4; ++nt) {
            half8v wf  = *reinterpret_cast<const half8v*>(&Ws[(wc * 64 + nt * 16 + lr) * LDT + 8 * lg]);
            half8v wlf = *reinterpret_cast<const half8v*>(&Ws[(wc * 64 + nt * 16 + lr) * LDT + 40 + 8 * lg]);
            #pragma unroll
            for (int mt = 0; mt < 4; ++mt) {
                acc[mt][nt] = __builtin_amdgcn_mfma_f32_16x16x32_f16(af[mt], wf, acc[mt][nt], 0, 0, 0);
                acc[mt][nt] = __builtin_amdgcn_mfma_f32_16x16x32_f16(af[mt], wlf, acc[mt][nt], 0, 0, 0);
                if constexpr (MODE != 2)
                    acc[mt][nt] = __builtin_amdgcn_mfma_f32_16x16x32_f16(alf[mt], wf, acc[mt][nt], 0, 0, 0);
            }
        }
    }

    #pragma unroll
    for (int nt = 0; nt < 4; ++nt) {
        const int n = n0 + wc * 64 + nt * 16 + lr;
        const float bn = bias[n];
        #pragma unroll
        for (int mt = 0; mt < 4; ++mt) {
            const int mbase = m0 + wr * 64 + mt * 16 + 4 * lg;
            #pragma unroll
            for (int j = 0; j < 4; ++j) {
                float v = acc[mt][nt][j] + bn;
                if constexpr (sizeof(TC) == 4)
                    C[(size_t)(mbase + j) * Ndim + n] = v;
                else
                    C[(size_t)(mbase + j) * Ndim + n] = (half_t)v;
            }
        }
    }
}

// ---------------- fp32 vector GEMM (ultimate fallback only) ----------------
template<typename TA, typename TC>
__global__ __launch_bounds__(256) void gemm_bias(const TA* __restrict__ A,
    const float* __restrict__ W, const float* __restrict__ bias,
    TC* __restrict__ C, int Mdim, int Ndim, int Kdim)
{
    constexpr int BK = 16;
    __shared__ float As[BK][68];
    __shared__ float Ws[BK][68];
    const int tx = threadIdx.x, ty = threadIdx.y;
    const int tid = ty * 16 + tx;
    const int m0 = blockIdx.y * 64, n0 = blockIdx.x * 64;
    const int lrow = tid >> 2;
    const int lc4  = (tid & 3) * 4;

    float acc[4][4] = {};
    for (int kk = 0; kk < Kdim; kk += BK) {
        {
            const TA* ap = A + (size_t)(m0 + lrow) * Kdim + kk + lc4;
            float a0, a1, a2, a3;
            if constexpr (sizeof(TA) == 4) {
                float4 v = *reinterpret_cast<const float4*>(ap);
                a0 = v.x; a1 = v.y; a2 = v.z; a3 = v.w;
            } else {
                half2v v0 = *reinterpret_cast<const half2v*>(ap);
                half2v v1 = *reinterpret_cast<const half2v*>(ap + 2);
                a0 = (float)v0[0]; a1 = (float)v0[1];
                a2 = (float)v1[0]; a3 = (float)v1[1];
            }
            As[lc4 + 0][lrow] = a0; As[lc4 + 1][lrow] = a1;
            As[lc4 + 2][lrow] = a2; As[lc4 + 3][lrow] = a3;
            const float* wp = W + (size_t)(n0 + lrow) * Kdim + kk + lc4;
            float4 wv = *reinterpret_cast<const float4*>(wp);
            Ws[lc4 + 0][lrow] = wv.x; Ws[lc4 + 1][lrow] = wv.y;
            Ws[lc4 + 2][lrow] = wv.z; Ws[lc4 + 3][lrow] = wv.w;
        }
        __syncthreads();
        #pragma unroll
        for (int k = 0; k < BK; ++k) {
            float4 av = *reinterpret_cast<const float4*>(&As[k][ty * 4]);
            float4 bv = *reinterpret_cast<const float4*>(&Ws[k][tx * 4]);
            float a[4] = {av.x, av.y, av.z, av.w};
            float b[4] = {bv.x, bv.y, bv.z, bv.w};
            #pragma unroll
            for (int i = 0; i < 4; ++i)
                #pragma unroll
                for (int j = 0; j < 4; ++j)
                    acc[i][j] = fmaf(a[i], b[j], acc[i][j]);
        }
        __syncthreads();
    }
    #pragma unroll
    for (int i = 0; i < 4; ++i) {
        const int m = m0 + ty * 4 + i;
        #pragma unroll
        for (int j = 0; j < 4; ++j) {
            const int n = n0 + tx * 4 + j;
            float v = acc[i][j] + bias[n];
            if constexpr (sizeof(TC) == 4)
                C[(size_t)m * Ndim + n] = v;
            else
                C[(size_t)m * Ndim + n] = (half_t)v;
        }
    }
}

// ---------------- single-pass fused attention (unchanged from round 6) ----------------
__global__ __launch_bounds__(256, 4) void attn_fused(const half_t* __restrict__ Q,
    const half_t* __restrict__ K, const half_t* __restrict__ V,
    half_t* __restrict__ X)
{
    __shared__ __align__(16) half_t KsL[2][64 * 64];   // linear, swizzled content
    __shared__ __align__(16) half_t Vt[2][64 * 72];    // transposed V

    const int tid = threadIdx.x;
    const int l   = tid & 63;
    const int w   = tid >> 6;
    const int lr  = l & 15;
    const int lg  = l >> 4;

    const int phys = blockIdx.x;
    const int virt = (phys & 7) * 128 + (phys >> 3);
    const int qb = virt & 15;
    const int h  = (virt >> 4) & 15;
    const int b  = virt >> 8;

    const int q0 = qb * 128 + w * 32;
    const size_t hoff = (size_t)(b * SS) * DD + h * HDIM;

    // Q fragments, pre-scaled by 1/8
    half8v qf[2][2];
    #pragma unroll
    for (int s = 0; s < 2; ++s) {
        const half_t* qp = Q + hoff + (size_t)(q0 + s * 16 + lr) * DD;
        #pragma unroll
        for (int hb = 0; hb < 2; ++hb) {
            half8v v = *reinterpret_cast<const half8v*>(qp + hb * 32 + 8 * lg);
            #pragma unroll
            for (int e = 0; e < 8; ++e) v[e] *= (half_t)0.125f;
            qf[s][hb] = v;
        }
    }

    // K staging: per-lane swizzled global source offsets (halves)
    int koffH[2];
    #pragma unroll
    for (int i = 0; i < 2; ++i) {
        const int row = (w * 2 + i) * 8 + (l >> 3);
        const int gc  = (l & 7) ^ (row & 7);
        koffH[i] = row * DD + gc * 8;
    }
    // swizzled frag-read indices (halves within a kb-block)
    const int kidx0 = lr * 64 + ((lg ^ (lr & 7)) * 8);
    const int kidx1 = lr * 64 + (((4 + lg) ^ (lr & 7)) * 8);

    const int vk2 = tid & 31, vdq = tid >> 5;

    float m[2]    = {-1e30f, -1e30f};
    float lsum[2] = {0.f, 0.f};
    f32x4 xacc[2][4] = {};

    half4v va0, va1, vb0, vb1;
    {   // prologue: stage tile 0
        const half_t* kbase = K + hoff;
        glds16(kbase + koffH[0], &KsL[0][(w * 2 + 0) * 512]);
        glds16(kbase + koffH[1], &KsL[0][(w * 2 + 1) * 512]);
        const half_t* vsrc = V + hoff + (size_t)(2 * vk2) * DD + vdq * 8;
        va0 = *reinterpret_cast<const half4v*>(vsrc);
        va1 = *reinterpret_cast<const half4v*>(vsrc + 4);
        vb0 = *reinterpret_cast<const half4v*>(vsrc + DD);
        vb1 = *reinterpret_cast<const half4v*>(vsrc + DD + 4);
        #pragma unroll
        for (int i = 0; i < 4; ++i) {
            half2v p0 = {va0[i], vb0[i]};
            half2v p1 = {va1[i], vb1[i]};
            *reinterpret_cast<half2v*>(&Vt[0][(vdq * 8 + i) * 72 + 2 * vk2])     = p0;
            *reinterpret_cast<half2v*>(&Vt[0][(vdq * 8 + i + 4) * 72 + 2 * vk2]) = p1;
        }
    }
    __syncthreads();

    for (int t = 0; t < SS / 64; ++t) {
        const int cur = t & 1, nxt = cur ^ 1;
        if (t < SS / 64 - 1) {   // issue next-tile loads early (T14)
            const half_t* kbase = K + hoff + (size_t)(t + 1) * 64 * DD;
            glds16(kbase + koffH[0], &KsL[nxt][(w * 2 + 0) * 512]);
            glds16(kbase + koffH[1], &KsL[nxt][(w * 2 + 1) * 512]);
            const half_t* vsrc = V + hoff + (size_t)((t + 1) * 64 + 2 * vk2) * DD + vdq * 8;
            va0 = *reinterpret_cast<const half4v*>(vsrc);
            va1 = *reinterpret_cast<const half4v*>(vsrc + 4);
            vb0 = *reinterpret_cast<const half4v*>(vsrc + DD);
            vb1 = *reinterpret_cast<const half4v*>(vsrc + DD + 4);
        }

        half8v kf[4][2];
        #pragma unroll
        for (int kb = 0; kb < 4; ++kb) {
            kf[kb][0] = *reinterpret_cast<const half8v*>(&KsL[cur][kb * 1024 + kidx0]);
            kf[kb][1] = *reinterpret_cast<const half8v*>(&KsL[cur][kb * 1024 + kidx1]);
        }

        half4v af[2][4];
        #pragma unroll
        for (int s = 0; s < 2; ++s) {
            f32x4 c[4] = {};
            __builtin_amdgcn_s_setprio(1);
            #pragma unroll
            for (int kb = 0; kb < 4; ++kb)
                #pragma unroll
                for (int hb = 0; hb < 2; ++hb)
                    c[kb] = __builtin_amdgcn_mfma_f32_16x16x32_f16(kf[kb][hb], qf[s][hb], c[kb], 0, 0, 0);
            __builtin_amdgcn_s_setprio(0);

            float r0 = fmaxf(fmaxf(c[0][0], c[0][1]), fmaxf(c[0][2], c[0][3]));
            float r1 = fmaxf(fmaxf(c[1][0], c[1][1]), fmaxf(c[1][2], c[1][3]));
            float r2 = fmaxf(fmaxf(c[2][0], c[2][1]), fmaxf(c[2][2], c[2][3]));
            float r3 = fmaxf(fmaxf(c[3][0], c[3][1]), fmaxf(c[3][2], c[3][3]));
            float rmax = fmaxf(fmaxf(r0, r1), fmaxf(r2, r3));
            rmax = fmaxf(rmax, __shfl_xor(rmax, 16, 64));
            rmax = fmaxf(rmax, __shfl_xor(rmax, 32, 64));
            const float tmax = (float)(half_t)rmax;   // f16 RTE monotone

            if (__any(tmax > m[s] + 8.0f)) {   // defer-max fold
                const float mn = fmaxf(m[s], tmax);
                const float sc = __expf(m[s] - mn);
                lsum[s] *= sc;
                #pragma unroll
                for (int db = 0; db < 4; ++db)
                    #pragma unroll
                    for (int j = 0; j < 4; ++j)
                        xacc[s][db][j] *= sc;
                m[s] = mn;
            }

            const float nm2 = m[s] * -1.4426950408889634f;
            (void)nm2;
            float ps = 0.f;
            #pragma unroll
            for (int kb = 0; kb < 4; ++kb)
                #pragma unroll
                for (int j = 0; j < 4; ++j) {
                    const half_t e16 = (half_t)c[kb][j];   // f16 score (ref semantics)
                    const float ef = (float)e16;
#ifdef ATTN_EXP2
                    const float p = ATTN_EXP2(__builtin_fmaf(ef, 1.4426950408889634f, nm2));
#else
                    const float p = __expf(ef - m[s]);
#endif
                    ps += p;
                    af[s][kb][j] = (half_t)p;              // p16
                }
            ps += __shfl_xor(ps, 16, 64);
            ps += __shfl_xor(ps, 32, 64);
            lsum[s] += ps;
        }

        __builtin_amdgcn_s_setprio(1);
        #pragma unroll
        for (int db = 0; db < 4; ++db)
            #pragma unroll
            for (int kb = 0; kb < 4; ++kb) {
                half4v vf = *reinterpret_cast<const half4v*>(
                    &Vt[cur][(db * 16 + lr) * 72 + kb * 16 + 4 * lg]);
                xacc[0][db] = __builtin_amdgcn_mfma_f32_16x16x16f16(vf, af[0][kb], xacc[0][db], 0, 0, 0);
                xacc[1][db] = __builtin_amdgcn_mfma_f32_16x16x16f16(vf, af[1][kb], xacc[1][db], 0, 0, 0);
            }
        __builtin_amdgcn_s_setprio(0);

        if (t < SS / 64 - 1) {   // write V-transpose into other buffer
            #pragma unroll
            for (int i = 0; i < 4; ++i) {
                half2v p0 = {va0[i], vb0[i]};
                half2v p1 = {va1[i], vb1[i]};
                *reinterpret_cast<half2v*>(&Vt[nxt][(vdq * 8 + i) * 72 + 2 * vk2])     = p0;
                *reinterpret_cast<half2v*>(&Vt[nxt][(vdq * 8 + i + 4) * 72 + 2 * vk2]) = p1;
            }
        }
        __syncthreads();
    }

    #pragma unroll
    for (int s = 0; s < 2; ++s) {
        const float invl = 1.0f / lsum[s];
        half_t* xp = X + hoff + (size_t)(q0 + s * 16 + lr) * DD;
        #pragma unroll
        for (int db = 0; db < 4; ++db) {
            half4v o;
            #pragma unroll
            for (int j = 0; j < 4; ++j) o[j] = (half_t)(xacc[s][db][j] * invl);
            *reinterpret_cast<half4v*>(xp + db * 16 + 4 * lg) = o;
        }
    }
}

extern "C" void kernel_launch(void* const* d_in, const int* in_sizes, int n_in,
                              void* d_out, int out_size, void* d_ws, size_t ws_size,
                              hipStream_t stream) {
    const float* q   = (const float*)d_in[0];
    const float* k   = (const float*)d_in[1];
    const float* v   = (const float*)d_in[2];
    const float* Wq  = (const float*)d_in[3];
    const float* bq  = (const float*)d_in[4];
    const float* Wk  = (const float*)d_in[5];
    const float* bk  = (const float*)d_in[6];
    const float* Wv  = (const float*)d_in[7];
    const float* bv  = (const float*)d_in[8];
    const float* Wo  = (const float*)d_in[9];
    const float* bo  = (const float*)d_in[10];
    float* out = (float*)d_out;

    const size_t MB = 1ull << 20;
    const size_t ACT = (size_t)MTOT * DD;   // 8.39M elems
    const size_t WEL = (size_t)DD * DD;     // 1.05M elems

    half_t* q16 = (half_t*)d_ws;
    half_t* k16 = q16 + ACT;
    half_t* v16 = k16 + ACT;
    half_t* x16 = v16 + ACT;

    dim3 gblk(256);
    dim3 ablk(256);
    dim3 agrd(1024);

    if (ws_size >= 80 * MB) {
        half_t* wh = x16 + ACT;          // 4 * WEL
        half_t* wl = wh + 4 * WEL;       // 4 * WEL

        dim3 wsgrd(WEL / 4 / 256, 1, 4);
        hipLaunchKernelGGL(split_w4, wsgrd, gblk, 0, stream,
                           Wq, Wk, Wv, Wo, wh, wl);

        dim3 pgrd(MTOT / 128, DD / 128, 3);   // (m=64, n=8, z=3)
        hipLaunchKernelGGL(gemm_proj, pgrd, gblk, 0, stream,
                           q, k, v, wh, wl, bq, bk, bv, q16, k16, v16);

        hipLaunchKernelGGL(attn_fused, agrd, ablk, 0, stream, q16, k16, v16, x16);

        dim3 ogrd(MTOT / 128, DD / 128);      // (m=64, n=8)
        hipLaunchKernelGGL(gemm_out, ogrd, gblk, 0, stream,
                           x16, wh + 3 * WEL, wl + 3 * WEL, bo, out);
    } else if (ws_size >= 72 * MB) {
        half_t* wh = x16 + ACT;
        half_t* wl = wh + WEL;
        const int nw4 = (int)(WEL / 4);
        dim3 sgW((nw4 + 255) / 256);
        dim3 ggrd(DD / 128, MTOT / 128);

        hipLaunchKernelGGL(split_hi_lo, sgW, gblk, 0, stream, Wq, wh, wl, nw4);
        hipLaunchKernelGGL((gemm3s<1, half_t>), ggrd, gblk, 0, stream,
                           nullptr, nullptr, q, wh, wl, bq, q16, DD, DD);
        hipLaunchKernelGGL(split_hi_lo, sgW, gblk, 0, stream, Wk, wh, wl, nw4);
        hipLaunchKernelGGL((gemm3s<1, half_t>), ggrd, gblk, 0, stream,
                           nullptr, nullptr, k, wh, wl, bk, k16, DD, DD);
        hipLaunchKernelGGL(split_hi_lo, sgW, gblk, 0, stream, Wv, wh, wl, nw4);
        hipLaunchKernelGGL((gemm3s<1, half_t>), ggrd, gblk, 0, stream,
                           nullptr, nullptr, v, wh, wl, bv, v16, DD, DD);

        hipLaunchKernelGGL(attn_fused, agrd, ablk, 0, stream, q16, k16, v16, x16);

        hipLaunchKernelGGL(split_hi_lo, sgW, gblk, 0, stream, Wo, wh, wl, nw4);
        hipLaunchKernelGGL((gemm3s<2, float>), ggrd, gblk, 0, stream,
                           x16, nullptr, nullptr, wh, wl, bo, out, DD, DD);
    } else {
        dim3 blk(16, 16);
        dim3 grd(DD / 64, MTOT / 64);
        hipLaunchKernelGGL((gemm_bias<float, half_t>), grd, blk, 0, stream,
                           q, Wq, bq, q16, MTOT, DD, DD);
        hipLaunchKernelGGL((gemm_bias<float, half_t>), grd, blk, 0, stream,
                           k, Wk, bk, k16, MTOT, DD, DD);
        hipLaunchKernelGGL((gemm_bias<float, half_t>), grd, blk, 0, stream,
                           v, Wv, bv, v16, MTOT, DD, DD);
        hipLaunchKernelGGL(attn_fused, agrd, ablk, 0, stream, q16, k16, v16, x16);
        hipLaunchKernelGGL((gemm_bias<half_t, float>), grd, blk, 0, stream,
                           x16, Wo, bo, out, MTOT, DD, DD);
    }
}